// Round 1
// baseline (4281.163 us; speedup 1.0000x reference)
//
#include <hip/hip_runtime.h>
#include <math.h>

// ---------------- problem constants ----------------
// T=16, NC=NQ=32, DW=256, DR=256, DZ=128, NH=8, F=1419
#define F_FEAT 1419
static constexpr float RATIO = 0.026546563287556634f; // 1419^-0.5
static constexpr float DN    = 0.25f;                 // 256^-0.25

// ---------------- workspace layout (float offsets) ----------------
static constexpr long OFF_POOL = 0;                  // [1024][48][16][16] = 12,582,912 (stage A)
static constexpr long OFF_XDQ  = 0;                  // alias (stage B): [4096][1419]
static constexpr long OFF_XDK  = 5812224;            // [4096][1419]
static constexpr long OFF_C3   = 12582912;           // [1024][4096]
static constexpr long BASE     = 16777216;
static constexpr long OFF_XCTX = BASE + 0;           // [512][256]
static constexpr long OFF_XQRY = BASE + 131072;      // [512][256] (contiguous after XCTX)
static constexpr long OFF_XCAT = BASE + 262144;      // [512][320]
static constexpr long OFF_H1   = BASE + 425984;      // [512][256]
static constexpr long OFF_H2   = BASE + 557056;      // [512][256]
static constexpr long OFF_RS   = BASE + 688128;      // [512][256]
static constexpr long OFF_QA   = BASE + 819200;      // [8][512][256]
static constexpr long OFF_KA   = BASE + 1867776;     // [8][512][256]
static constexpr long OFF_VA   = BASE + 2916352;     // [8][512][256]
static constexpr long OFF_DQ   = BASE + 3964928;     // [4096]
static constexpr long OFF_DK   = BASE + 3969024;     // [4096]
static constexpr long OFF_MQ   = BASE + 3973120;     // [4096]
static constexpr long OFF_MK   = BASE + 3977216;     // [128]
static constexpr long OFF_REPIN= BASE + 3977344;     // [512][2048]
static constexpr long OFF_REP  = BASE + 5025920;     // [512][256]
static constexpr long OFF_XZ   = BASE + 5156992;     // [512][384]
static constexpr long OFF_DH1  = BASE + 5353600;     // [512][100]
static constexpr long OFF_DH2  = BASE + 5404800;     // [512][100]
// total ≈ 22,233,216 floats = ~85 MiB of d_ws

// ============================================================
// Fused conv1 (1->32, s2) -> relu -> conv2 (32->48, s2) -> relu -> maxpool2
// One block per (image, oc-half). Rolling LDS rings for input rows & conv1 rows.
// ============================================================
__launch_bounds__(256)
__global__ void k_conv12(const float* __restrict__ train, const float* __restrict__ test,
                         const float* __restrict__ w1, const float* __restrict__ b1,
                         const float* __restrict__ w2, const float* __restrict__ b2,
                         float* __restrict__ pool_out)
{
    const int img = blockIdx.x >> 1;
    const int oh  = blockIdx.x & 1;            // oc base = oh*24
    const float* in = (img < 512) ? (train + (long)img * 16384)
                                  : (test  + (long)(img - 512) * 16384);

    __shared__ float s_w1[32][12];
    __shared__ float s_b1[32];
    __shared__ float s_w2[24][32][12];
    __shared__ float s_b2[24];
    __shared__ float s_c1[3][32][64];

    const int t = threadIdx.x;
    for (int i = t; i < 32 * 9; i += 256) { int ic = i / 9, j = i % 9; s_w1[ic][j] = w1[i]; }
    for (int i = t; i < 24 * 32 * 9; i += 256) {
        int oc = i / 288, r = i % 288, ic = r / 9, j = r % 9;
        s_w2[oc][ic][j] = w2[(oh * 24 + oc) * 288 + ic * 9 + j];
    }
    if (t < 32) s_b1[t] = b1[t];
    if (t < 24) s_b2[t] = b2[oh * 24 + t];
    __syncthreads();

    const int x64 = t & 63;    // conv1 x
    const int wid = t >> 6;    // 0..3 (ic base)
    const int g   = t >> 5;    // 0..7 conv2 oc-trio
    const int x32 = t & 31;    // conv2 x

    float pmax[3];

    for (int y = 0; y < 32; y++) {
        // ---- conv1: produce rows 2y, 2y+1 into the ring ----
        for (int rr = 0; rr < 2; rr++) {
            int r = 2 * y + rr;
            int slot = r % 3;
            float v[3][3];
            #pragma unroll
            for (int dy = 0; dy < 3; dy++) {
                int row = 2 * r - 1 + dy;
                #pragma unroll
                for (int dx = 0; dx < 3; dx++) {
                    int col = 2 * x64 - 1 + dx;
                    v[dy][dx] = (row >= 0 && col >= 0) ? in[row * 128 + col] : 0.f;
                }
            }
            #pragma unroll
            for (int k = 0; k < 8; k++) {
                int ic = wid + k * 4;
                float a = s_b1[ic];
                #pragma unroll
                for (int dy = 0; dy < 3; dy++)
                    #pragma unroll
                    for (int dx = 0; dx < 3; dx++)
                        a += v[dy][dx] * s_w1[ic][dy * 3 + dx];
                s_c1[slot][ic][x64] = fmaxf(a, 0.f);
            }
        }
        __syncthreads();

        // ---- conv2 row y ----
        float acc[3];
        #pragma unroll
        for (int j = 0; j < 3; j++) acc[j] = s_b2[g * 3 + j];

        for (int ic = 0; ic < 32; ic++) {
            float wA[3][9];
            #pragma unroll
            for (int j = 0; j < 3; j++)
                #pragma unroll
                for (int q = 0; q < 9; q++) wA[j][q] = s_w2[g * 3 + j][ic][q];
            #pragma unroll
            for (int dy = 0; dy < 3; dy++) {
                int row = 2 * y - 1 + dy;
                if (row < 0) continue;
                int slot = row % 3;
                float c0 = (x32 > 0) ? s_c1[slot][ic][2 * x32 - 1] : 0.f;
                float c1 = s_c1[slot][ic][2 * x32];
                float c2 = s_c1[slot][ic][2 * x32 + 1];
                #pragma unroll
                for (int j = 0; j < 3; j++)
                    acc[j] += c0 * wA[j][dy * 3 + 0] + c1 * wA[j][dy * 3 + 1] + c2 * wA[j][dy * 3 + 2];
            }
        }

        // relu + 2x2 maxpool (horizontal via shfl, vertical in regs)
        #pragma unroll
        for (int j = 0; j < 3; j++) {
            float r = fmaxf(acc[j], 0.f);
            float mm = fmaxf(r, __shfl_xor(r, 1));
            if ((y & 1) == 0) pmax[j] = mm;
            else {
                mm = fmaxf(mm, pmax[j]);
                if ((x32 & 1) == 0) {
                    int oc = oh * 24 + g * 3 + j;
                    pool_out[(((long)img * 48 + oc) * 16 + (y >> 1)) * 16 + (x32 >> 1)] = mm;
                }
            }
        }
        __syncthreads();
    }
}

// ============================================================
// conv3 (48->64, s2, 16->8) + relu, flattened NCHW output [img][4096]
// block = (oc-group of 8, image); split-K over ic with shuffle reduce
// ============================================================
__launch_bounds__(256)
__global__ void k_conv3(const float* __restrict__ pool, const float* __restrict__ w3,
                        const float* __restrict__ b3, float* __restrict__ c3out)
{
    const int ocg = blockIdx.x;   // 0..7
    const int img = blockIdx.y;
    __shared__ float s_pool[48 * 16 * 16];
    __shared__ float s_w3[8 * 48 * 9];
    const int t = threadIdx.x;
    const float* pb = pool + (long)img * 12288;
    for (int i = t; i < 12288; i += 256) s_pool[i] = pb[i];
    for (int i = t; i < 3456; i += 256)  s_w3[i] = w3[ocg * 3456 + i];
    __syncthreads();

    const int unit = t >> 2;   // 0..63
    const int oc = unit >> 3;  // 0..7
    const int y  = unit & 7;
    const int icq = t & 3;

    float acc[8] = {0,0,0,0,0,0,0,0};
    for (int ic = icq * 12; ic < icq * 12 + 12; ic++) {
        #pragma unroll
        for (int dy = 0; dy < 3; dy++) {
            int row = 2 * y - 1 + dy;
            if (row < 0) continue;
            const float* pr = &s_pool[(ic * 16 + row) * 16];
            float p[16];
            #pragma unroll
            for (int q = 0; q < 16; q += 4) {
                float4 f4 = *(const float4*)(pr + q);
                p[q] = f4.x; p[q + 1] = f4.y; p[q + 2] = f4.z; p[q + 3] = f4.w;
            }
            const float* wr = &s_w3[(oc * 48 + ic) * 9 + dy * 3];
            float w0 = wr[0], w1v = wr[1], w2v = wr[2];
            #pragma unroll
            for (int xx = 0; xx < 8; xx++) {
                int c = 2 * xx - 1;
                float s = p[c + 1] * w1v + p[c + 2] * w2v;
                if (c >= 0) s += p[c] * w0;
                acc[xx] += s;
            }
        }
    }
    #pragma unroll
    for (int xx = 0; xx < 8; xx++) {
        acc[xx] += __shfl_xor(acc[xx], 1);
        acc[xx] += __shfl_xor(acc[xx], 2);
    }
    if (icq == 0) {
        float bias = b3[ocg * 8 + oc];
        float o[8];
        #pragma unroll
        for (int xx = 0; xx < 8; xx++) o[xx] = fmaxf(acc[xx] + bias, 0.f);
        float4* dst = (float4*)&c3out[(long)img * 4096 + (ocg * 8 + oc) * 64 + y * 8];
        dst[0] = make_float4(o[0], o[1], o[2], o[3]);
        dst[1] = make_float4(o[4], o[5], o[6], o[7]);
    }
}

// ============================================================
// Generic fp32 GEMM: Y = act(scale*(X @ W^T) + bias)
// X[M,K], W[N,K] row-major. Batched via gridDim.z (strides) OR split-K (atomics).
// ============================================================
template<int BM, int BN, int BK, int TM, int TN, int ACT, bool SPLITK>
__launch_bounds__(256)
__global__ void gemm_k(const float* __restrict__ Xb, const float* __restrict__ Wb,
                       const float* __restrict__ Bb, float* __restrict__ Yb,
                       int M, int N, int K, int ldY, float scale,
                       long sX, long sW, long sB, long sY, int kChunk)
{
    const int z = blockIdx.z;
    const float* X = Xb + (SPLITK ? 0 : (long)z * sX);
    const float* W = Wb + (SPLITK ? 0 : (long)z * sW);
    const float* B = Bb ? (Bb + (SPLITK ? 0 : (long)z * sB)) : nullptr;
    float* Y = Yb + (SPLITK ? 0 : (long)z * sY);
    int k0 = 0, k1 = K;
    if (SPLITK) { k0 = z * kChunk; k1 = min(K, k0 + kChunk); }

    __shared__ float As[BK][BM + 4];
    __shared__ float Bs[BK][BN + 4];
    const int t = threadIdx.x;
    const int tx = t & 15, ty = t >> 4;
    const int m0 = blockIdx.y * BM, n0 = blockIdx.x * BN;
    float acc[TM][TN];
    #pragma unroll
    for (int i = 0; i < TM; i++)
        #pragma unroll
        for (int j = 0; j < TN; j++) acc[i][j] = 0.f;

    for (int kb = k0; kb < k1; kb += BK) {
        for (int i = t; i < BM * BK; i += 256) {
            int r = i / BK, c = i % BK;
            int mm = m0 + r, kk = kb + c;
            As[c][r] = (mm < M && kk < k1) ? X[(long)mm * K + kk] : 0.f;
        }
        for (int i = t; i < BN * BK; i += 256) {
            int r = i / BK, c = i % BK;
            int nn = n0 + r, kk = kb + c;
            Bs[c][r] = (nn < N && kk < k1) ? W[(long)nn * K + kk] : 0.f;
        }
        __syncthreads();
        #pragma unroll
        for (int kk = 0; kk < BK; kk++) {
            float a[TM], b[TN];
            #pragma unroll
            for (int i = 0; i < TM; i++) a[i] = As[kk][ty * TM + i];
            #pragma unroll
            for (int j = 0; j < TN; j++) b[j] = Bs[kk][tx * TN + j];
            #pragma unroll
            for (int i = 0; i < TM; i++)
                #pragma unroll
                for (int j = 0; j < TN; j++) acc[i][j] += a[i] * b[j];
        }
        __syncthreads();
    }

    #pragma unroll
    for (int i = 0; i < TM; i++) {
        int mm = m0 + ty * TM + i;
        if (mm >= M) continue;
        #pragma unroll
        for (int j = 0; j < TN; j++) {
            int nn = n0 + tx * TN + j;
            if (nn >= N) continue;
            float v = acc[i][j] * scale;
            if (SPLITK) {
                if (z == 0 && B) v += B[nn];
                atomicAdd(&Y[(long)mm * ldY + nn], v);
            } else {
                if (B) v += B[nn];
                if (ACT == 1) v = fmaxf(v, 0.f);
                if (ACT == 2) v = tanhf(v);
                Y[(long)mm * ldY + nn] = v;
            }
        }
    }
}

// ============================================================
// xcat = [x_ctx | label @ ty_w^T + ty_b]   -> [512][320]
// ============================================================
__global__ void k_xcat(const float* __restrict__ x_ctx, const float* __restrict__ label,
                       const float* __restrict__ tyw, const float* __restrict__ tyb,
                       float* __restrict__ xcat)
{
    int idx = blockIdx.x * 256 + threadIdx.x;
    if (idx >= 512 * 320) return;
    int r = idx / 320, c = idx % 320;
    float v;
    if (c < 256) v = x_ctx[r * 256 + c];
    else {
        int e = c - 256;
        v = tyb[e] + label[r * 2] * tyw[e * 2] + label[r * 2 + 1] * tyw[e * 2 + 1];
    }
    xcat[idx] = v;
}

// diag[tok] = 0.5 * dn^2 * sum(x^2) = sum(x^2)/32 ; tok<4096 -> q, else k
__global__ void k_diag(const float* __restrict__ qa, const float* __restrict__ ka,
                       float* __restrict__ dq, float* __restrict__ dk)
{
    int tok = blockIdx.x * 4 + (threadIdx.x >> 6);
    int l = threadIdx.x & 63;
    const float* src = (tok < 4096) ? qa + (long)tok * 256 : ka + (long)(tok - 4096) * 256;
    float4 f = *(const float4*)(src + l * 4);
    float s = f.x * f.x + f.y * f.y + f.z * f.z + f.w * f.w;
    for (int d = 1; d < 64; d <<= 1) s += __shfl_xor(s, d);
    if (l == 0) {
        float v = s * (1.f / 32.f);
        if (tok < 4096) dq[tok] = v; else dk[tok - 4096] = v;
    }
}

// per-row max over F (queries)
__global__ void k_rowmax(const float* __restrict__ xd, float* __restrict__ mq)
{
    int tok = blockIdx.x;
    const float* row = xd + (long)tok * F_FEAT;
    int t = threadIdx.x;
    float m = -1e30f;
    for (int f = t; f < F_FEAT; f += 256) m = fmaxf(m, row[f]);
    for (int d = 1; d < 64; d <<= 1) m = fmaxf(m, __shfl_xor(m, d));
    __shared__ float sm[4];
    if ((t & 63) == 0) sm[t >> 6] = m;
    __syncthreads();
    if (t == 0) mq[tok] = fmaxf(fmaxf(sm[0], sm[1]), fmaxf(sm[2], sm[3]));
}

// per-(h,t) max over 32 x F (keys)
__global__ void k_blkmax(const float* __restrict__ xd, float* __restrict__ mk)
{
    int b = blockIdx.x;
    const float* base = xd + (long)b * 32 * F_FEAT;
    int t = threadIdx.x;
    float m = -1e30f;
    for (int i = t; i < 32 * F_FEAT; i += 256) m = fmaxf(m, base[i]);
    for (int d = 1; d < 64; d <<= 1) m = fmaxf(m, __shfl_xor(m, d));
    __shared__ float sm[4];
    if ((t & 63) == 0) sm[t >> 6] = m;
    __syncthreads();
    if (t == 0) mk[b] = fmaxf(fmaxf(sm[0], sm[1]), fmaxf(sm[2], sm[3]));
}

// in-place: xd <- ratio * (exp(xd - diag[tok] - m) + 1e-4)
__global__ void k_exp(float* __restrict__ xd, const float* __restrict__ diag,
                      const float* __restrict__ mrow, int per_row)
{
    int tok = blockIdx.y;
    int f = blockIdx.x * 256 + threadIdx.x;
    if (f >= F_FEAT) return;
    long i = (long)tok * F_FEAT + f;
    float m = per_row ? mrow[tok] : mrow[tok >> 5];
    xd[i] = RATIO * (expf(xd[i] - diag[tok] - m) + 1e-4f);
}

// ============================================================
// Attention core per (h, t): A = qp@kp^T [32,32]; d_inv = 1/rowsum(A);
// outs = (A @ v) * d_inv; write permuted into rep_in[t*32+n][e*8+h]
// ============================================================
__launch_bounds__(256)
__global__ void k_attn(const float* __restrict__ qp, const float* __restrict__ kp,
                       const float* __restrict__ va, float* __restrict__ rep_in)
{
    const int tt = blockIdx.x;  // 0..15
    const int h  = blockIdx.y;  // 0..7
    const long row0 = ((long)h * 16 + tt) * 32;

    __shared__ float s_q[32][68];
    __shared__ float s_k[32][68];
    __shared__ float s_A[32][33];
    __shared__ float s_di[32];
    __shared__ float s_v[32 * 256];

    const int t = threadIdx.x;
    const int n = t >> 3;          // 0..31
    const int mq = (t & 7) * 4;    // A column group

    float acc[4] = {0, 0, 0, 0};
    for (int fc = 0; fc < F_FEAT; fc += 64) {
        for (int i = t; i < 2048; i += 256) {
            int rr = i >> 6, ff = i & 63;
            int fg = fc + ff;
            s_q[rr][ff] = (fg < F_FEAT) ? qp[(row0 + rr) * F_FEAT + fg] : 0.f;
            s_k[rr][ff] = (fg < F_FEAT) ? kp[(row0 + rr) * F_FEAT + fg] : 0.f;
        }
        __syncthreads();
        #pragma unroll 8
        for (int ff = 0; ff < 64; ff++) {
            float a = s_q[n][ff];
            #pragma unroll
            for (int j = 0; j < 4; j++) acc[j] += a * s_k[mq + j][ff];
        }
        __syncthreads();
    }

    float rsum = acc[0] + acc[1] + acc[2] + acc[3];
    rsum += __shfl_xor(rsum, 1);
    rsum += __shfl_xor(rsum, 2);
    rsum += __shfl_xor(rsum, 4);
    #pragma unroll
    for (int j = 0; j < 4; j++) s_A[n][mq + j] = acc[j];
    if ((t & 7) == 0) s_di[n] = 1.f / rsum;
    for (int i = t; i < 8192; i += 256) s_v[i] = va[row0 * 256 + i];
    __syncthreads();

    const int e0 = t & 7;
    float out[32];
    #pragma unroll
    for (int j = 0; j < 32; j++) out[j] = 0.f;
    for (int m = 0; m < 32; m++) {
        float a = s_A[n][m];
        #pragma unroll
        for (int j = 0; j < 32; j++) out[j] += a * s_v[m * 256 + e0 + 8 * j];
    }
    float di = s_di[n];
    float* dst = rep_in + ((long)tt * 32 + n) * 2048;
    #pragma unroll
    for (int j = 0; j < 32; j++) {
        int e = e0 + 8 * j;
        dst[e * 8 + h] = out[j] * di;
    }
}

// copy x_qry into xz[:, 0:256]
__global__ void k_xzcopy(const float* __restrict__ xq, float* __restrict__ xz)
{
    int idx = blockIdx.x * 256 + threadIdx.x;
    if (idx >= 512 * 256) return;
    int r = idx >> 8, c = idx & 255;
    xz[r * 384 + c] = xq[idx];
}

__global__ void k_fin(float* __restrict__ out) { if (threadIdx.x == 0) out[1024] = 0.f; }

// ============================================================
extern "C" void kernel_launch(void* const* d_in, const int* in_sizes, int n_in,
                              void* d_out, int out_size, void* d_ws, size_t ws_size,
                              hipStream_t stream)
{
    const float* train  = (const float*)d_in[0];
    const float* label  = (const float*)d_in[1];
    const float* test   = (const float*)d_in[2];
    const float* c1w = (const float*)d_in[3];  const float* c1b = (const float*)d_in[4];
    const float* c2w = (const float*)d_in[5];  const float* c2b = (const float*)d_in[6];
    const float* c3w = (const float*)d_in[7];  const float* c3b = (const float*)d_in[8];
    const float* elw = (const float*)d_in[9];  const float* elb = (const float*)d_in[10];
    const float* tyw = (const float*)d_in[11]; const float* tyb = (const float*)d_in[12];
    const float* ew1 = (const float*)d_in[13]; const float* eb1 = (const float*)d_in[14];
    const float* ew2 = (const float*)d_in[15]; const float* eb2 = (const float*)d_in[16];
    const float* ew3 = (const float*)d_in[17]; const float* eb3 = (const float*)d_in[18];
    const float* wq  = (const float*)d_in[19]; const float* wqb = (const float*)d_in[20];
    const float* wk  = (const float*)d_in[21]; const float* wkb = (const float*)d_in[22];
    const float* wv  = (const float*)d_in[23]; const float* wvb = (const float*)d_in[24];
    const float* wow = (const float*)d_in[25]; const float* wob = (const float*)d_in[26];
    const float* rzw = (const float*)d_in[27]; const float* rzb = (const float*)d_in[28];
    const float* dw1 = (const float*)d_in[29]; const float* db1 = (const float*)d_in[30];
    const float* dw2 = (const float*)d_in[31]; const float* db2 = (const float*)d_in[32];
    const float* dw3 = (const float*)d_in[33]; const float* db3 = (const float*)d_in[34];
    const float* proj= (const float*)d_in[35];

    float* wsf = (float*)d_ws;
    float* out = (float*)d_out;

    float* A_pool = wsf + OFF_POOL;
    float* A_c3   = wsf + OFF_C3;
    float* x_ctx  = wsf + OFF_XCTX;
    float* x_qry  = wsf + OFF_XQRY;
    float* xcat   = wsf + OFF_XCAT;
    float* h1     = wsf + OFF_H1;
    float* h2     = wsf + OFF_H2;
    float* rs     = wsf + OFF_RS;
    float* q_all  = wsf + OFF_QA;
    float* k_all  = wsf + OFF_KA;
    float* v_all  = wsf + OFF_VA;
    float* dq     = wsf + OFF_DQ;
    float* dk     = wsf + OFF_DK;
    float* m_q    = wsf + OFF_MQ;
    float* m_k    = wsf + OFF_MK;
    float* rep_in = wsf + OFF_REPIN;
    float* rep    = wsf + OFF_REP;
    float* xz     = wsf + OFF_XZ;
    float* dh1    = wsf + OFF_DH1;
    float* dh2    = wsf + OFF_DH2;
    float* xd_q   = wsf + OFF_XDQ;
    float* xd_k   = wsf + OFF_XDK;

    // ---- encoder ----
    k_conv12<<<2048, 256, 0, stream>>>(train, test, c1w, c1b, c2w, c2b, A_pool);
    k_conv3<<<dim3(8, 1024), 256, 0, stream>>>(A_pool, c3w, c3b, A_c3);

    hipMemsetAsync(x_ctx, 0, 1024 * 256 * sizeof(float), stream);   // x_ctx + x_qry
    gemm_k<64,64,16,4,4,0,true><<<dim3(4, 16, 8), 256, 0, stream>>>(
        A_c3, elw, elb, x_ctx, 1024, 256, 4096, 256, 1.f, 0, 0, 0, 0, 512);

    // ---- xcat + er MLP -> rs ----
    k_xcat<<<640, 256, 0, stream>>>(x_ctx, label, tyw, tyb, xcat);
    gemm_k<32,32,32,2,2,1,false><<<dim3(8, 16, 1), 256, 0, stream>>>(
        xcat, ew1, eb1, h1, 512, 256, 320, 256, 1.f, 0, 0, 0, 0, 0);
    gemm_k<32,32,32,2,2,1,false><<<dim3(8, 16, 1), 256, 0, stream>>>(
        h1, ew2, eb2, h2, 512, 256, 256, 256, 1.f, 0, 0, 0, 0, 0);
    gemm_k<32,32,32,2,2,0,false><<<dim3(8, 16, 1), 256, 0, stream>>>(
        h2, ew3, eb3, rs, 512, 256, 256, 256, 1.f, 0, 0, 0, 0, 0);

    // ---- q/k/v per-head projections (batched over heads via grid.z) ----
    gemm_k<64,64,16,4,4,0,false><<<dim3(4, 8, 8), 256, 0, stream>>>(
        x_qry, wq, wqb, q_all, 512, 256, 256, 256, 1.f, 0, 65536, 256, 131072, 0);
    gemm_k<64,64,16,4,4,0,false><<<dim3(4, 8, 8), 256, 0, stream>>>(
        x_ctx, wk, wkb, k_all, 512, 256, 256, 256, 1.f, 0, 65536, 256, 131072, 0);
    gemm_k<64,64,16,4,4,0,false><<<dim3(4, 8, 8), 256, 0, stream>>>(
        rs, wv, wvb, v_all, 512, 256, 256, 256, 1.f, 0, 65536, 256, 131072, 0);

    // ---- performer features: xd = dn * (x @ proj^T) ----
    gemm_k<64,64,16,4,4,0,false><<<dim3(23, 64, 1), 256, 0, stream>>>(
        q_all, proj, nullptr, xd_q, 4096, F_FEAT, 256, F_FEAT, DN, 0, 0, 0, 0, 0);
    gemm_k<64,64,16,4,4,0,false><<<dim3(23, 64, 1), 256, 0, stream>>>(
        k_all, proj, nullptr, xd_k, 4096, F_FEAT, 256, F_FEAT, DN, 0, 0, 0, 0, 0);

    k_diag<<<2048, 256, 0, stream>>>(q_all, k_all, dq, dk);
    k_rowmax<<<4096, 256, 0, stream>>>(xd_q, m_q);
    k_blkmax<<<128, 256, 0, stream>>>(xd_k, m_k);
    k_exp<<<dim3(6, 4096), 256, 0, stream>>>(xd_q, dq, m_q, 1);
    k_exp<<<dim3(6, 4096), 256, 0, stream>>>(xd_k, dk, m_k, 0);

    // ---- attention + permuted concat ----
    k_attn<<<dim3(16, 8), 256, 0, stream>>>(xd_q, xd_k, v_all, rep_in);

    // ---- rep = rep_in @ wo^T + b (split-K) ----
    hipMemsetAsync(rep, 0, 512 * 256 * sizeof(float), stream);
    gemm_k<64,64,16,4,4,0,true><<<dim3(4, 8, 8), 256, 0, stream>>>(
        rep_in, wow, wob, rep, 512, 256, 2048, 256, 1.f, 0, 0, 0, 0, 256);

    // ---- xz = [x_qry | rep @ rz^T + b] ----
    k_xzcopy<<<512, 256, 0, stream>>>(x_qry, xz);
    gemm_k<32,32,32,2,2,0,false><<<dim3(4, 16, 1), 256, 0, stream>>>(
        rep, rzw, rzb, xz + 256, 512, 128, 256, 384, 1.f, 0, 0, 0, 0, 0);

    // ---- decoder ----
    gemm_k<32,32,32,2,2,1,false><<<dim3(4, 16, 1), 256, 0, stream>>>(
        xz, dw1, db1, dh1, 512, 100, 384, 100, 1.f, 0, 0, 0, 0, 0);
    gemm_k<32,32,32,2,2,1,false><<<dim3(4, 16, 1), 256, 0, stream>>>(
        dh1, dw2, db2, dh2, 512, 100, 100, 100, 1.f, 0, 0, 0, 0, 0);
    gemm_k<32,32,32,2,2,2,false><<<dim3(1, 16, 1), 256, 0, stream>>>(
        dh2, dw3, db3, out, 512, 2, 100, 2, 1.f, 0, 0, 0, 0, 0);

    k_fin<<<1, 64, 0, stream>>>(out);
}

// Round 2
// 2824.494 us; speedup vs baseline: 1.5157x; 1.5157x over previous
//
#include <hip/hip_runtime.h>
#include <math.h>

// ---------------- problem constants ----------------
// T=16, NC=NQ=32, DW=256, DR=256, DZ=128, NH=8, F=1419
#define F_FEAT 1419
static constexpr float RATIO = 0.026546563287556634f; // 1419^-0.5
static constexpr float DN    = 0.25f;                 // 256^-0.25

typedef short short8 __attribute__((ext_vector_type(8)));
typedef float f32x4  __attribute__((ext_vector_type(4)));

// ---------------- workspace layout (float offsets) ----------------
static constexpr long OFF_POOL = 0;                  // [1024][48][16][16] (stage A)
static constexpr long OFF_XDQ  = 0;                  // alias (stage B): [4096][1419]
static constexpr long OFF_XDK  = 5812224;            // [4096][1419]
static constexpr long OFF_C3   = 12582912;           // [1024][4096]
static constexpr long BASE     = 16777216;
static constexpr long OFF_XCTX = BASE + 0;           // [512][256]
static constexpr long OFF_XQRY = BASE + 131072;      // [512][256]
static constexpr long OFF_XCAT = BASE + 262144;      // [512][320]
static constexpr long OFF_H1   = BASE + 425984;      // [512][256]
static constexpr long OFF_H2   = BASE + 557056;      // [512][256]
static constexpr long OFF_RS   = BASE + 688128;      // [512][256]
static constexpr long OFF_QA   = BASE + 819200;      // [8][512][256]
static constexpr long OFF_KA   = BASE + 1867776;     // [8][512][256]
static constexpr long OFF_VA   = BASE + 2916352;     // [8][512][256]
static constexpr long OFF_DQ   = BASE + 3964928;     // [4096]
static constexpr long OFF_DK   = BASE + 3969024;     // [4096]
static constexpr long OFF_MQ   = BASE + 3973120;     // [4096]
static constexpr long OFF_MK   = BASE + 3977216;     // [128]
static constexpr long OFF_REPIN= BASE + 3977344;     // [512][2048]
static constexpr long OFF_REP  = BASE + 5025920;     // [512][256]
static constexpr long OFF_XZ   = BASE + 5156992;     // [512][384]
static constexpr long OFF_DH1  = BASE + 5353600;     // [512][100]
static constexpr long OFF_DH2  = BASE + 5404800;     // [512][100]
static constexpr long OFF_AW   = 22233216;           // [9][3][16][32] bf16 (13824 ushort)

__device__ inline unsigned short f2bf(float f) {
    unsigned int x = __float_as_uint(f);
    unsigned int r = x + 0x7fffu + ((x >> 16) & 1u);
    return (unsigned short)(r >> 16);
}

// ============================================================
// w2 [48][32][3][3] fp32 -> Aw [tap e=dy*3+dx][mt 3][m 16][ic 32] bf16
// (A-fragment friendly: lane m reads 8 contiguous ic -> global b128)
// ============================================================
__global__ void k_wprep(const float* __restrict__ w2, unsigned short* __restrict__ Aw)
{
    int i = blockIdx.x * 256 + threadIdx.x;   // 13824 total
    if (i >= 13824) return;
    int ic  = i & 31;
    int m16 = (i >> 5) & 15;
    int emt = i >> 9;          // e*3 + mt
    int mt  = emt % 3;
    int e   = emt / 3;
    int oc  = mt * 16 + m16;
    Aw[i] = f2bf(w2[(oc * 32 + ic) * 9 + e]);
}

// ============================================================
// Fused conv1(fp32 VALU) -> bf16 ring -> conv2 via MFMA (9 shifted GEMMs,
// 16x16x32 bf16, K=32=ic per tap) -> +bias, relu, 2x2 maxpool.
// Block = (rowgroup g: 4 conv2 rows, image). 256 threads = 4 waves,
// wave w owns conv2 local row r=w (2 x-tiles of 16).
// Ring: [slot 9][col 66][icpitch 40] bf16 (col c = input col + 1; c=0 is the
// zero pad for input col -1). B-frag = ds_read_b128 of 8 contiguous ic.
// ============================================================
__launch_bounds__(256)
__global__ void k_conv12m(const float* __restrict__ train, const float* __restrict__ test,
                          const float* __restrict__ w1, const float* __restrict__ b1,
                          const unsigned short* __restrict__ Aw, const float* __restrict__ b2,
                          float* __restrict__ pool_out)
{
    const int g   = blockIdx.x;    // 0..7 (conv2 rows 4g..4g+3)
    const int img = blockIdx.y;
    const float* in = (img < 512) ? (train + (long)img * 16384)
                                  : (test  + (long)(img - 512) * 16384);

    __shared__ unsigned short ring[9 * 66 * 40];   // 47520 B
    float* scratch = (float*)ring;                 // alias after MFMA: [4][48][32] fp32

    const int t = threadIdx.x;

    // zero pad column c=0 of every slot
    for (int i = t; i < 9 * 40; i += 256) {
        int s = i / 40, icp = i % 40;
        ring[(s * 66 + 0) * 40 + icp] = 0;
    }
    // g==0: conv1 row -1 -> whole slot 0 zero
    if (g == 0)
        for (int i = t; i < 66 * 40; i += 256) ring[i] = 0;

    // ---- conv1 phase: thread = (col 0..63, icq 0..3 -> ics icq*8..icq*8+7) ----
    const int col = t & 63;
    const int icq = t >> 6;
    float wr[8][9], bb[8];
    #pragma unroll
    for (int j = 0; j < 8; j++) {
        int ic = icq * 8 + j;
        bb[j] = b1[ic];
        #pragma unroll
        for (int q = 0; q < 9; q++) wr[j][q] = w1[ic * 9 + q];
    }

    for (int s = (g == 0 ? 1 : 0); s < 9; s++) {
        int row = 8 * g - 1 + s;                  // conv1 row (>=0 here)
        float v[3][3];
        #pragma unroll
        for (int dyy = 0; dyy < 3; dyy++) {
            int r2 = 2 * row - 1 + dyy;
            #pragma unroll
            for (int dxx = 0; dxx < 3; dxx++) {
                int c2 = 2 * col - 1 + dxx;
                v[dyy][dxx] = (r2 >= 0 && c2 >= 0) ? in[r2 * 128 + c2] : 0.f;
            }
        }
        unsigned short o[8];
        #pragma unroll
        for (int j = 0; j < 8; j++) {
            float a = bb[j];
            #pragma unroll
            for (int q = 0; q < 9; q++) a += v[q / 3][q % 3] * wr[j][q];
            o[j] = f2bf(fmaxf(a, 0.f));
        }
        *(uint4*)&ring[(s * 66 + col + 1) * 40 + icq * 8] = *(const uint4*)o;
    }
    __syncthreads();

    // ---- MFMA phase ----
    const int w    = t >> 6;       // wave = conv2 local row r
    const int lane = t & 63;
    const int n    = lane & 15;
    const int quad = lane >> 4;

    f32x4 acc[3][2];
    #pragma unroll
    for (int mt = 0; mt < 3; mt++)
        #pragma unroll
        for (int xh = 0; xh < 2; xh++) acc[mt][xh] = (f32x4){0.f, 0.f, 0.f, 0.f};

    for (int e = 0; e < 9; e++) {
        int dy = e / 3, dx = e - 3 * dy;
        // A-frags: lane m=n reads 8 contiguous ic (global b128, L1-hot)
        short8 a0 = *(const short8*)&Aw[((e * 3 + 0) * 16 + n) * 32 + quad * 8];
        short8 a1 = *(const short8*)&Aw[((e * 3 + 1) * 16 + n) * 32 + quad * 8];
        short8 a2 = *(const short8*)&Aw[((e * 3 + 2) * 16 + n) * 32 + quad * 8];
        int s = 2 * w + dy;        // ring slot for this row/tap
        #pragma unroll
        for (int xh = 0; xh < 2; xh++) {
            int c = 2 * (xh * 16 + n) + dx;   // = input col (2x-1+dx) + 1
            short8 bfr = *(const short8*)&ring[(s * 66 + c) * 40 + quad * 8];
            acc[0][xh] = __builtin_amdgcn_mfma_f32_16x16x32_bf16(a0, bfr, acc[0][xh], 0, 0, 0);
            acc[1][xh] = __builtin_amdgcn_mfma_f32_16x16x32_bf16(a1, bfr, acc[1][xh], 0, 0, 0);
            acc[2][xh] = __builtin_amdgcn_mfma_f32_16x16x32_bf16(a2, bfr, acc[2][xh], 0, 0, 0);
        }
    }
    __syncthreads();   // all ring reads done before scratch overwrite

    // C/D layout: col = lane&15 (=x within 16), row = quad*4+reg (=oc within mtile)
    #pragma unroll
    for (int mt = 0; mt < 3; mt++) {
        #pragma unroll
        for (int reg = 0; reg < 4; reg++) {
            int oc = mt * 16 + quad * 4 + reg;
            float bias = b2[oc];
            #pragma unroll
            for (int xh = 0; xh < 2; xh++) {
                int x = xh * 16 + n;
                scratch[(w * 48 + oc) * 32 + x] = fmaxf(acc[mt][xh][reg] + bias, 0.f);
            }
        }
    }
    __syncthreads();

    // 2x2 maxpool -> pool rows 2g, 2g+1
    for (int i = t; i < 1536; i += 256) {
        int px = i & 15, pr = (i >> 4) & 1, oc = i >> 5;
        const float* s0 = &scratch[((2 * pr) * 48 + oc) * 32 + 2 * px];
        const float* s1 = &scratch[((2 * pr + 1) * 48 + oc) * 32 + 2 * px];
        float m = fmaxf(fmaxf(s0[0], s0[1]), fmaxf(s1[0], s1[1]));
        pool_out[(((long)img * 48 + oc) * 16 + (2 * g + pr)) * 16 + px] = m;
    }
}

// ============================================================
// conv3 (48->64, s2, 16->8) + relu, flattened NCHW output [img][4096]
// ============================================================
__launch_bounds__(256)
__global__ void k_conv3(const float* __restrict__ pool, const float* __restrict__ w3,
                        const float* __restrict__ b3, float* __restrict__ c3out)
{
    const int ocg = blockIdx.x;   // 0..7
    const int img = blockIdx.y;
    __shared__ float s_pool[48 * 16 * 16];
    __shared__ float s_w3[8 * 48 * 9];
    const int t = threadIdx.x;
    const float* pb = pool + (long)img * 12288;
    for (int i = t; i < 12288; i += 256) s_pool[i] = pb[i];
    for (int i = t; i < 3456; i += 256)  s_w3[i] = w3[ocg * 3456 + i];
    __syncthreads();

    const int unit = t >> 2;   // 0..63
    const int oc = unit >> 3;  // 0..7
    const int y  = unit & 7;
    const int icq = t & 3;

    float acc[8] = {0,0,0,0,0,0,0,0};
    for (int ic = icq * 12; ic < icq * 12 + 12; ic++) {
        #pragma unroll
        for (int dy = 0; dy < 3; dy++) {
            int row = 2 * y - 1 + dy;
            if (row < 0) continue;
            const float* pr = &s_pool[(ic * 16 + row) * 16];
            float p[16];
            #pragma unroll
            for (int q = 0; q < 16; q += 4) {
                float4 f4 = *(const float4*)(pr + q);
                p[q] = f4.x; p[q + 1] = f4.y; p[q + 2] = f4.z; p[q + 3] = f4.w;
            }
            const float* wr = &s_w3[(oc * 48 + ic) * 9 + dy * 3];
            float w0 = wr[0], w1v = wr[1], w2v = wr[2];
            #pragma unroll
            for (int xx = 0; xx < 8; xx++) {
                int c = 2 * xx - 1;
                float s = p[c + 1] * w1v + p[c + 2] * w2v;
                if (c >= 0) s += p[c] * w0;
                acc[xx] += s;
            }
        }
    }
    #pragma unroll
    for (int xx = 0; xx < 8; xx++) {
        acc[xx] += __shfl_xor(acc[xx], 1);
        acc[xx] += __shfl_xor(acc[xx], 2);
    }
    if (icq == 0) {
        float bias = b3[ocg * 8 + oc];
        float o[8];
        #pragma unroll
        for (int xx = 0; xx < 8; xx++) o[xx] = fmaxf(acc[xx] + bias, 0.f);
        float4* dst = (float4*)&c3out[(long)img * 4096 + (ocg * 8 + oc) * 64 + y * 8];
        dst[0] = make_float4(o[0], o[1], o[2], o[3]);
        dst[1] = make_float4(o[4], o[5], o[6], o[7]);
    }
}

// ============================================================
// Generic fp32 GEMM: Y = act(scale*(X @ W^T) + bias)
// ============================================================
template<int BM, int BN, int BK, int TM, int TN, int ACT, bool SPLITK>
__launch_bounds__(256)
__global__ void gemm_k(const float* __restrict__ Xb, const float* __restrict__ Wb,
                       const float* __restrict__ Bb, float* __restrict__ Yb,
                       int M, int N, int K, int ldY, float scale,
                       long sX, long sW, long sB, long sY, int kChunk)
{
    const int z = blockIdx.z;
    const float* X = Xb + (SPLITK ? 0 : (long)z * sX);
    const float* W = Wb + (SPLITK ? 0 : (long)z * sW);
    const float* B = Bb ? (Bb + (SPLITK ? 0 : (long)z * sB)) : nullptr;
    float* Y = Yb + (SPLITK ? 0 : (long)z * sY);
    int k0 = 0, k1 = K;
    if (SPLITK) { k0 = z * kChunk; k1 = min(K, k0 + kChunk); }

    __shared__ float As[BK][BM + 4];
    __shared__ float Bs[BK][BN + 4];
    const int t = threadIdx.x;
    const int tx = t & 15, ty = t >> 4;
    const int m0 = blockIdx.y * BM, n0 = blockIdx.x * BN;
    float acc[TM][TN];
    #pragma unroll
    for (int i = 0; i < TM; i++)
        #pragma unroll
        for (int j = 0; j < TN; j++) acc[i][j] = 0.f;

    for (int kb = k0; kb < k1; kb += BK) {
        for (int i = t; i < BM * BK; i += 256) {
            int r = i / BK, c = i % BK;
            int mm = m0 + r, kk = kb + c;
            As[c][r] = (mm < M && kk < k1) ? X[(long)mm * K + kk] : 0.f;
        }
        for (int i = t; i < BN * BK; i += 256) {
            int r = i / BK, c = i % BK;
            int nn = n0 + r, kk = kb + c;
            Bs[c][r] = (nn < N && kk < k1) ? W[(long)nn * K + kk] : 0.f;
        }
        __syncthreads();
        #pragma unroll
        for (int kk = 0; kk < BK; kk++) {
            float a[TM], b[TN];
            #pragma unroll
            for (int i = 0; i < TM; i++) a[i] = As[kk][ty * TM + i];
            #pragma unroll
            for (int j = 0; j < TN; j++) b[j] = Bs[kk][tx * TN + j];
            #pragma unroll
            for (int i = 0; i < TM; i++)
                #pragma unroll
                for (int j = 0; j < TN; j++) acc[i][j] += a[i] * b[j];
        }
        __syncthreads();
    }

    #pragma unroll
    for (int i = 0; i < TM; i++) {
        int mm = m0 + ty * TM + i;
        if (mm >= M) continue;
        #pragma unroll
        for (int j = 0; j < TN; j++) {
            int nn = n0 + tx * TN + j;
            if (nn >= N) continue;
            float v = acc[i][j] * scale;
            if (SPLITK) {
                if (z == 0 && B) v += B[nn];
                atomicAdd(&Y[(long)mm * ldY + nn], v);
            } else {
                if (B) v += B[nn];
                if (ACT == 1) v = fmaxf(v, 0.f);
                if (ACT == 2) v = tanhf(v);
                Y[(long)mm * ldY + nn] = v;
            }
        }
    }
}

// ============================================================
__global__ void k_xcat(const float* __restrict__ x_ctx, const float* __restrict__ label,
                       const float* __restrict__ tyw, const float* __restrict__ tyb,
                       float* __restrict__ xcat)
{
    int idx = blockIdx.x * 256 + threadIdx.x;
    if (idx >= 512 * 320) return;
    int r = idx / 320, c = idx % 320;
    float v;
    if (c < 256) v = x_ctx[r * 256 + c];
    else {
        int e = c - 256;
        v = tyb[e] + label[r * 2] * tyw[e * 2] + label[r * 2 + 1] * tyw[e * 2 + 1];
    }
    xcat[idx] = v;
}

__global__ void k_diag(const float* __restrict__ qa, const float* __restrict__ ka,
                       float* __restrict__ dq, float* __restrict__ dk)
{
    int tok = blockIdx.x * 4 + (threadIdx.x >> 6);
    int l = threadIdx.x & 63;
    const float* src = (tok < 4096) ? qa + (long)tok * 256 : ka + (long)(tok - 4096) * 256;
    float4 f = *(const float4*)(src + l * 4);
    float s = f.x * f.x + f.y * f.y + f.z * f.z + f.w * f.w;
    for (int d = 1; d < 64; d <<= 1) s += __shfl_xor(s, d);
    if (l == 0) {
        float v = s * (1.f / 32.f);
        if (tok < 4096) dq[tok] = v; else dk[tok - 4096] = v;
    }
}

__global__ void k_rowmax(const float* __restrict__ xd, float* __restrict__ mq)
{
    int tok = blockIdx.x;
    const float* row = xd + (long)tok * F_FEAT;
    int t = threadIdx.x;
    float m = -1e30f;
    for (int f = t; f < F_FEAT; f += 256) m = fmaxf(m, row[f]);
    for (int d = 1; d < 64; d <<= 1) m = fmaxf(m, __shfl_xor(m, d));
    __shared__ float sm[4];
    if ((t & 63) == 0) sm[t >> 6] = m;
    __syncthreads();
    if (t == 0) mq[tok] = fmaxf(fmaxf(sm[0], sm[1]), fmaxf(sm[2], sm[3]));
}

__global__ void k_blkmax(const float* __restrict__ xd, float* __restrict__ mk)
{
    int b = blockIdx.x;
    const float* base = xd + (long)b * 32 * F_FEAT;
    int t = threadIdx.x;
    float m = -1e30f;
    for (int i = t; i < 32 * F_FEAT; i += 256) m = fmaxf(m, base[i]);
    for (int d = 1; d < 64; d <<= 1) m = fmaxf(m, __shfl_xor(m, d));
    __shared__ float sm[4];
    if ((t & 63) == 0) sm[t >> 6] = m;
    __syncthreads();
    if (t == 0) mk[b] = fmaxf(fmaxf(sm[0], sm[1]), fmaxf(sm[2], sm[3]));
}

__global__ void k_exp(float* __restrict__ xd, const float* __restrict__ diag,
                      const float* __restrict__ mrow, int per_row)
{
    int tok = blockIdx.y;
    int f = blockIdx.x * 256 + threadIdx.x;
    if (f >= F_FEAT) return;
    long i = (long)tok * F_FEAT + f;
    float m = per_row ? mrow[tok] : mrow[tok >> 5];
    xd[i] = RATIO * (expf(xd[i] - diag[tok] - m) + 1e-4f);
}

// ============================================================
__launch_bounds__(256)
__global__ void k_attn(const float* __restrict__ qp, const float* __restrict__ kp,
                       const float* __restrict__ va, float* __restrict__ rep_in)
{
    const int tt = blockIdx.x;  // 0..15
    const int h  = blockIdx.y;  // 0..7
    const long row0 = ((long)h * 16 + tt) * 32;

    __shared__ float s_q[32][68];
    __shared__ float s_k[32][68];
    __shared__ float s_A[32][33];
    __shared__ float s_di[32];
    __shared__ float s_v[32 * 256];

    const int t = threadIdx.x;
    const int n = t >> 3;          // 0..31
    const int mq = (t & 7) * 4;    // A column group

    float acc[4] = {0, 0, 0, 0};
    for (int fc = 0; fc < F_FEAT; fc += 64) {
        for (int i = t; i < 2048; i += 256) {
            int rr = i >> 6, ff = i & 63;
            int fg = fc + ff;
            s_q[rr][ff] = (fg < F_FEAT) ? qp[(row0 + rr) * F_FEAT + fg] : 0.f;
            s_k[rr][ff] = (fg < F_FEAT) ? kp[(row0 + rr) * F_FEAT + fg] : 0.f;
        }
        __syncthreads();
        #pragma unroll 8
        for (int ff = 0; ff < 64; ff++) {
            float a = s_q[n][ff];
            #pragma unroll
            for (int j = 0; j < 4; j++) acc[j] += a * s_k[mq + j][ff];
        }
        __syncthreads();
    }

    float rsum = acc[0] + acc[1] + acc[2] + acc[3];
    rsum += __shfl_xor(rsum, 1);
    rsum += __shfl_xor(rsum, 2);
    rsum += __shfl_xor(rsum, 4);
    #pragma unroll
    for (int j = 0; j < 4; j++) s_A[n][mq + j] = acc[j];
    if ((t & 7) == 0) s_di[n] = 1.f / rsum;
    for (int i = t; i < 8192; i += 256) s_v[i] = va[row0 * 256 + i];
    __syncthreads();

    const int e0 = t & 7;
    float out[32];
    #pragma unroll
    for (int j = 0; j < 32; j++) out[j] = 0.f;
    for (int m = 0; m < 32; m++) {
        float a = s_A[n][m];
        #pragma unroll
        for (int j = 0; j < 32; j++) out[j] += a * s_v[m * 256 + e0 + 8 * j];
    }
    float di = s_di[n];
    float* dst = rep_in + ((long)tt * 32 + n) * 2048;
    #pragma unroll
    for (int j = 0; j < 32; j++) {
        int e = e0 + 8 * j;
        dst[e * 8 + h] = out[j] * di;
    }
}

__global__ void k_xzcopy(const float* __restrict__ xq, float* __restrict__ xz)
{
    int idx = blockIdx.x * 256 + threadIdx.x;
    if (idx >= 512 * 256) return;
    int r = idx >> 8, c = idx & 255;
    xz[r * 384 + c] = xq[idx];
}

__global__ void k_fin(float* __restrict__ out) { if (threadIdx.x == 0) out[1024] = 0.f; }

// ============================================================
extern "C" void kernel_launch(void* const* d_in, const int* in_sizes, int n_in,
                              void* d_out, int out_size, void* d_ws, size_t ws_size,
                              hipStream_t stream)
{
    const float* train  = (const float*)d_in[0];
    const float* label  = (const float*)d_in[1];
    const float* test   = (const float*)d_in[2];
    const float* c1w = (const float*)d_in[3];  const float* c1b = (const float*)d_in[4];
    const float* c2w = (const float*)d_in[5];  const float* c2b = (const float*)d_in[6];
    const float* c3w = (const float*)d_in[7];  const float* c3b = (const float*)d_in[8];
    const float* elw = (const float*)d_in[9];  const float* elb = (const float*)d_in[10];
    const float* tyw = (const float*)d_in[11]; const float* tyb = (const float*)d_in[12];
    const float* ew1 = (const float*)d_in[13]; const float* eb1 = (const float*)d_in[14];
    const float* ew2 = (const float*)d_in[15]; const float* eb2 = (const float*)d_in[16];
    const float* ew3 = (const float*)d_in[17]; const float* eb3 = (const float*)d_in[18];
    const float* wq  = (const float*)d_in[19]; const float* wqb = (const float*)d_in[20];
    const float* wk  = (const float*)d_in[21]; const float* wkb = (const float*)d_in[22];
    const float* wv  = (const float*)d_in[23]; const float* wvb = (const float*)d_in[24];
    const float* wow = (const float*)d_in[25]; const float* wob = (const float*)d_in[26];
    const float* rzw = (const float*)d_in[27]; const float* rzb = (const float*)d_in[28];
    const float* dw1 = (const float*)d_in[29]; const float* db1 = (const float*)d_in[30];
    const float* dw2 = (const float*)d_in[31]; const float* db2 = (const float*)d_in[32];
    const float* dw3 = (const float*)d_in[33]; const float* db3 = (const float*)d_in[34];
    const float* proj= (const float*)d_in[35];

    float* wsf = (float*)d_ws;
    float* out = (float*)d_out;

    float* A_pool = wsf + OFF_POOL;
    float* A_c3   = wsf + OFF_C3;
    float* x_ctx  = wsf + OFF_XCTX;
    float* x_qry  = wsf + OFF_XQRY;
    float* xcat   = wsf + OFF_XCAT;
    float* h1     = wsf + OFF_H1;
    float* h2     = wsf + OFF_H2;
    float* rs     = wsf + OFF_RS;
    float* q_all  = wsf + OFF_QA;
    float* k_all  = wsf + OFF_KA;
    float* v_all  = wsf + OFF_VA;
    float* dq     = wsf + OFF_DQ;
    float* dk     = wsf + OFF_DK;
    float* m_q    = wsf + OFF_MQ;
    float* m_k    = wsf + OFF_MK;
    float* rep_in = wsf + OFF_REPIN;
    float* rep    = wsf + OFF_REP;
    float* xz     = wsf + OFF_XZ;
    float* dh1    = wsf + OFF_DH1;
    float* dh2    = wsf + OFF_DH2;
    float* xd_q   = wsf + OFF_XDQ;
    float* xd_k   = wsf + OFF_XDK;
    unsigned short* Aw = (unsigned short*)(wsf + OFF_AW);

    // ---- encoder ----
    k_wprep<<<54, 256, 0, stream>>>(c2w, Aw);
    k_conv12m<<<dim3(8, 1024), 256, 0, stream>>>(train, test, c1w, c1b, Aw, c2b, A_pool);
    k_conv3<<<dim3(8, 1024), 256, 0, stream>>>(A_pool, c3w, c3b, A_c3);

    hipMemsetAsync(x_ctx, 0, 1024 * 256 * sizeof(float), stream);   // x_ctx + x_qry
    gemm_k<64,64,16,4,4,0,true><<<dim3(4, 16, 8), 256, 0, stream>>>(
        A_c3, elw, elb, x_ctx, 1024, 256, 4096, 256, 1.f, 0, 0, 0, 0, 512);

    // ---- xcat + er MLP -> rs ----
    k_xcat<<<640, 256, 0, stream>>>(x_ctx, label, tyw, tyb, xcat);
    gemm_k<32,32,32,2,2,1,false><<<dim3(8, 16, 1), 256, 0, stream>>>(
        xcat, ew1, eb1, h1, 512, 256, 320, 256, 1.f, 0, 0, 0, 0, 0);
    gemm_k<32,32,32,2,2,1,false><<<dim3(8, 16, 1), 256, 0, stream>>>(
        h1, ew2, eb2, h2, 512, 256, 256, 256, 1.f, 0, 0, 0, 0, 0);
    gemm_k<32,32,32,2,2,0,false><<<dim3(8, 16, 1), 256, 0, stream>>>(
        h2, ew3, eb3, rs, 512, 256, 256, 256, 1.f, 0, 0, 0, 0, 0);

    // ---- q/k/v per-head projections ----
    gemm_k<64,64,16,4,4,0,false><<<dim3(4, 8, 8), 256, 0, stream>>>(
        x_qry, wq, wqb, q_all, 512, 256, 256, 256, 1.f, 0, 65536, 256, 131072, 0);
    gemm_k<64,64,16,4,4,0,false><<<dim3(4, 8, 8), 256, 0, stream>>>(
        x_ctx, wk, wkb, k_all, 512, 256, 256, 256, 1.f, 0, 65536, 256, 131072, 0);
    gemm_k<64,64,16,4,4,0,false><<<dim3(4, 8, 8), 256, 0, stream>>>(
        rs, wv, wvb, v_all, 512, 256, 256, 256, 1.f, 0, 65536, 256, 131072, 0);

    // ---- performer features: xd = dn * (x @ proj^T) ----
    gemm_k<64,64,16,4,4,0,false><<<dim3(23, 64, 1), 256, 0, stream>>>(
        q_all, proj, nullptr, xd_q, 4096, F_FEAT, 256, F_FEAT, DN, 0, 0, 0, 0, 0);
    gemm_k<64,64,16,4,4,0,false><<<dim3(23, 64, 1), 256, 0, stream>>>(
        k_all, proj, nullptr, xd_k, 4096, F_FEAT, 256, F_FEAT, DN, 0, 0, 0, 0, 0);

    k_diag<<<2048, 256, 0, stream>>>(q_all, k_all, dq, dk);
    k_rowmax<<<4096, 256, 0, stream>>>(xd_q, m_q);
    k_blkmax<<<128, 256, 0, stream>>>(xd_k, m_k);
    k_exp<<<dim3(6, 4096), 256, 0, stream>>>(xd_q, dq, m_q, 1);
    k_exp<<<dim3(6, 4096), 256, 0, stream>>>(xd_k, dk, m_k, 0);

    // ---- attention + permuted concat ----
    k_attn<<<dim3(16, 8), 256, 0, stream>>>(xd_q, xd_k, v_all, rep_in);

    // ---- rep = rep_in @ wo^T + b (split-K) ----
    hipMemsetAsync(rep, 0, 512 * 256 * sizeof(float), stream);
    gemm_k<64,64,16,4,4,0,true><<<dim3(4, 8, 8), 256, 0, stream>>>(
        rep_in, wow, wob, rep, 512, 256, 2048, 256, 1.f, 0, 0, 0, 0, 256);

    // ---- xz = [x_qry | rep @ rz^T + b] ----
    k_xzcopy<<<512, 256, 0, stream>>>(x_qry, xz);
    gemm_k<32,32,32,2,2,0,false><<<dim3(4, 16, 1), 256, 0, stream>>>(
        rep, rzw, rzb, xz + 256, 512, 128, 256, 384, 1.f, 0, 0, 0, 0, 0);

    // ---- decoder ----
    gemm_k<32,32,32,2,2,1,false><<<dim3(4, 16, 1), 256, 0, stream>>>(
        xz, dw1, db1, dh1, 512, 100, 384, 100, 1.f, 0, 0, 0, 0, 0);
    gemm_k<32,32,32,2,2,1,false><<<dim3(4, 16, 1), 256, 0, stream>>>(
        dh1, dw2, db2, dh2, 512, 100, 100, 100, 1.f, 0, 0, 0, 0, 0);
    gemm_k<32,32,32,2,2,2,false><<<dim3(1, 16, 1), 256, 0, stream>>>(
        dh2, dw3, db3, out, 512, 2, 100, 2, 1.f, 0, 0, 0, 0, 0);

    k_fin<<<1, 64, 0, stream>>>(out);
}

// Round 3
// 1165.014 us; speedup vs baseline: 3.6748x; 2.4244x over previous
//
#include <hip/hip_runtime.h>
#include <math.h>

// ---------------- problem constants ----------------
// T=16, NC=NQ=32, DW=256, DR=256, DZ=128, NH=8, F=1419
#define F_FEAT 1419
static constexpr float RATIO = 0.026546563287556634f; // 1419^-0.5
static constexpr float DN    = 0.25f;                 // 256^-0.25

typedef short short8 __attribute__((ext_vector_type(8)));
typedef float f32x4  __attribute__((ext_vector_type(4)));

// ---------------- workspace layout (float offsets) ----------------
static constexpr long OFF_POOL = 0;                  // [1024][256 pix][96] bf16 (= 12,582,912 floats region)
static constexpr long OFF_XDQ  = 0;                  // alias (stage B): [4096][1419]
static constexpr long OFF_XDK  = 5812224;            // [4096][1419]
static constexpr long OFF_C3   = 12582912;           // [1024][4096]
static constexpr long BASE     = 16777216;
static constexpr long OFF_XCTX = BASE + 0;           // [512][256]
static constexpr long OFF_XQRY = BASE + 131072;      // [512][256]
static constexpr long OFF_XCAT = BASE + 262144;      // [512][320]
static constexpr long OFF_H1   = BASE + 425984;      // [512][256]
static constexpr long OFF_H2   = BASE + 557056;      // [512][256]
static constexpr long OFF_RS   = BASE + 688128;      // [512][256]
static constexpr long OFF_QA   = BASE + 819200;      // [8][512][256]
static constexpr long OFF_KA   = BASE + 1867776;     // [8][512][256]
static constexpr long OFF_VA   = BASE + 2916352;     // [8][512][256]
static constexpr long OFF_DQ   = BASE + 3964928;     // [4096]
static constexpr long OFF_DK   = BASE + 3969024;     // [4096]
static constexpr long OFF_MQ   = BASE + 3973120;     // [4096]
static constexpr long OFF_MK   = BASE + 3977216;     // [128]
static constexpr long OFF_REPIN= BASE + 3977344;     // [512][2048]
static constexpr long OFF_REP  = BASE + 5025920;     // [512][256]
static constexpr long OFF_XZ   = BASE + 5156992;     // [512][384]
static constexpr long OFF_DH1  = BASE + 5353600;     // [512][100]
static constexpr long OFF_DH2  = BASE + 5404800;     // [512][100]
static constexpr long OFF_AW   = 22233216;           // conv2 A-weights [9][3][16][32] bf16 (13824 ushort)
static constexpr long OFF_AW3  = 22240128;           // conv3 A-weights [9][4][2][16][64] bf16 (73728 ushort)

__device__ inline unsigned short f2bf(float f) {
    unsigned int x = __float_as_uint(f);
    unsigned int r = x + 0x7fffu + ((x >> 16) & 1u);
    return (unsigned short)(r >> 16);
}
__device__ inline float bf2f(unsigned short h) {
    return __uint_as_float((unsigned int)h << 16);
}

// ============================================================
// w2 [48][32][3][3] fp32 -> Aw [tap e=dy*3+dx][mt 3][m 16][ic 32] bf16
// ============================================================
__global__ void k_wprep(const float* __restrict__ w2, unsigned short* __restrict__ Aw)
{
    int i = blockIdx.x * 256 + threadIdx.x;   // 13824 total
    if (i >= 13824) return;
    int ic  = i & 31;
    int m16 = (i >> 5) & 15;
    int emt = i >> 9;          // e*3 + mt
    int mt  = emt % 3;
    int e   = emt / 3;
    int oc  = mt * 16 + m16;
    Aw[i] = f2bf(w2[(oc * 32 + ic) * 9 + e]);
}

// ============================================================
// w3 [64][48][3][3] fp32 -> Aw3 [tap 9][mt 4][hl 2][m 16][k 64] bf16
// hi/lo split; k 48..63 zero-padded.
// ============================================================
__global__ void k_wprep3(const float* __restrict__ w3, unsigned short* __restrict__ Aw3)
{
    int i = blockIdx.x * 256 + threadIdx.x;   // 73728 total
    if (i >= 73728) return;
    int k  = i & 63;
    int m  = (i >> 6) & 15;
    int hl = (i >> 10) & 1;
    int mt = (i >> 11) & 3;
    int e  = i >> 13;
    unsigned short v = 0;
    if (k < 48) {
        int oc = mt * 16 + m;
        float w = w3[(oc * 48 + k) * 9 + e];
        unsigned short hi = f2bf(w);
        v = hl == 0 ? hi : f2bf(w - bf2f(hi));
    }
    Aw3[i] = v;
}

// ============================================================
// Fused conv1(fp32 VALU) -> bf16 ring -> conv2 via MFMA (9 shifted GEMMs,
// 16x16x32 bf16) -> +bias, relu, 2x2 maxpool -> bf16 hi/lo pool
// [img][pixel 256][hi 48 | lo 48] layout for conv3m's coalesced staging.
// ============================================================
__launch_bounds__(256)
__global__ void k_conv12m(const float* __restrict__ train, const float* __restrict__ test,
                          const float* __restrict__ w1, const float* __restrict__ b1,
                          const unsigned short* __restrict__ Aw, const float* __restrict__ b2,
                          unsigned short* __restrict__ pool_out)
{
    const int g   = blockIdx.x;    // 0..7 (conv2 rows 4g..4g+3)
    const int img = blockIdx.y;
    const float* in = (img < 512) ? (train + (long)img * 16384)
                                  : (test  + (long)(img - 512) * 16384);

    __shared__ unsigned short ring[9 * 66 * 40];   // 47520 B
    float* scratch = (float*)ring;                 // alias after MFMA: [(row*32+x)*52 + oc]

    const int t = threadIdx.x;

    // zero pad column c=0 of every slot
    for (int i = t; i < 9 * 40; i += 256) {
        int s = i / 40, icp = i % 40;
        ring[(s * 66 + 0) * 40 + icp] = 0;
    }
    if (g == 0)
        for (int i = t; i < 66 * 40; i += 256) ring[i] = 0;

    // ---- conv1 phase ----
    const int col = t & 63;
    const int icq = t >> 6;
    float wr[8][9], bb[8];
    #pragma unroll
    for (int j = 0; j < 8; j++) {
        int ic = icq * 8 + j;
        bb[j] = b1[ic];
        #pragma unroll
        for (int q = 0; q < 9; q++) wr[j][q] = w1[ic * 9 + q];
    }

    for (int s = (g == 0 ? 1 : 0); s < 9; s++) {
        int row = 8 * g - 1 + s;
        float v[3][3];
        #pragma unroll
        for (int dyy = 0; dyy < 3; dyy++) {
            int r2 = 2 * row - 1 + dyy;
            #pragma unroll
            for (int dxx = 0; dxx < 3; dxx++) {
                int c2 = 2 * col - 1 + dxx;
                v[dyy][dxx] = (r2 >= 0 && c2 >= 0) ? in[r2 * 128 + c2] : 0.f;
            }
        }
        unsigned short o[8];
        #pragma unroll
        for (int j = 0; j < 8; j++) {
            float a = bb[j];
            #pragma unroll
            for (int q = 0; q < 9; q++) a += v[q / 3][q % 3] * wr[j][q];
            o[j] = f2bf(fmaxf(a, 0.f));
        }
        *(uint4*)&ring[(s * 66 + col + 1) * 40 + icq * 8] = *(const uint4*)o;
    }
    __syncthreads();

    // ---- MFMA phase ----
    const int w    = t >> 6;
    const int lane = t & 63;
    const int n    = lane & 15;
    const int quad = lane >> 4;

    f32x4 acc[3][2];
    #pragma unroll
    for (int mt = 0; mt < 3; mt++)
        #pragma unroll
        for (int xh = 0; xh < 2; xh++) acc[mt][xh] = (f32x4){0.f, 0.f, 0.f, 0.f};

    for (int e = 0; e < 9; e++) {
        int dy = e / 3, dx = e - 3 * dy;
        short8 a0 = *(const short8*)&Aw[((e * 3 + 0) * 16 + n) * 32 + quad * 8];
        short8 a1 = *(const short8*)&Aw[((e * 3 + 1) * 16 + n) * 32 + quad * 8];
        short8 a2 = *(const short8*)&Aw[((e * 3 + 2) * 16 + n) * 32 + quad * 8];
        int s = 2 * w + dy;
        #pragma unroll
        for (int xh = 0; xh < 2; xh++) {
            int c = 2 * (xh * 16 + n) + dx;
            short8 bfr = *(const short8*)&ring[(s * 66 + c) * 40 + quad * 8];
            acc[0][xh] = __builtin_amdgcn_mfma_f32_16x16x32_bf16(a0, bfr, acc[0][xh], 0, 0, 0);
            acc[1][xh] = __builtin_amdgcn_mfma_f32_16x16x32_bf16(a1, bfr, acc[1][xh], 0, 0, 0);
            acc[2][xh] = __builtin_amdgcn_mfma_f32_16x16x32_bf16(a2, bfr, acc[2][xh], 0, 0, 0);
        }
    }
    __syncthreads();   // all ring reads done before scratch overwrite

    // C/D: col = lane&15 (=x), row = quad*4+reg (=oc in mtile)
    // scratch layout: [(row*32+x)*52 + oc] -- pad 52 avoids bank conflicts both ways
    #pragma unroll
    for (int mt = 0; mt < 3; mt++) {
        #pragma unroll
        for (int reg = 0; reg < 4; reg++) {
            int oc = mt * 16 + quad * 4 + reg;
            float bias = b2[oc];
            #pragma unroll
            for (int xh = 0; xh < 2; xh++) {
                int x = xh * 16 + n;
                scratch[(w * 32 + x) * 52 + oc] = fmaxf(acc[mt][xh][reg] + bias, 0.f);
            }
        }
    }
    __syncthreads();

    // 2x2 maxpool -> bf16 hi/lo pool, pixel rows 2g, 2g+1
    for (int i = t; i < 1536; i += 256) {
        int oc = i % 48; int pp = i / 48; int px = pp & 15, pr = pp >> 4;
        const float* b0 = &scratch[((2 * pr) * 32 + 2 * px) * 52 + oc];
        float m = fmaxf(fmaxf(b0[0], b0[52]), fmaxf(b0[32 * 52], b0[33 * 52]));
        unsigned short hi = f2bf(m);
        unsigned short lo = f2bf(m - bf2f(hi));
        long base = ((long)img * 256 + (2 * g + pr) * 16 + px) * 96;
        pool_out[base + oc] = hi;
        pool_out[base + 48 + oc] = lo;
    }
}

// ============================================================
// conv3 (48->64, s2) via MFMA, bf16 hi/lo split (~fp32 accuracy).
// Block = image, 512 threads = 8 waves; wave -> (mt = w>>1, nt pair = w&1).
// LDS: s_in[(row+1)*17 + (col+1)][104]: hi k 0..47, lo k 48..95, pad 96..103.
// K=48 padded to 64 on the A side with zeros (B over-reads stay finite).
// ============================================================
#define C3PITCH 104
__launch_bounds__(512)
__global__ void k_conv3m(const unsigned short* __restrict__ pool,
                         const unsigned short* __restrict__ Aw3,
                         const float* __restrict__ b3, float* __restrict__ c3out)
{
    const int img = blockIdx.x;
    __shared__ unsigned short s_in[30120];   // 17*17*104 + 64 pad = 60240 B
    const int t = threadIdx.x;

    uint4* s4 = (uint4*)s_in;
    const uint4 zz = make_uint4(0, 0, 0, 0);
    for (int i = t; i < 3765; i += 512) s4[i] = zz;     // zero halo + pads (NaN-safe)
    __syncthreads();
    {
        int p = t >> 1, half = t & 1;
        const uint4* src = (const uint4*)(pool + ((long)img * 256 + p) * 96 + half * 48);
        int r = p >> 4, c = p & 15;
        uint4* dst = (uint4*)(s_in + ((r + 1) * 17 + (c + 1)) * C3PITCH + half * 48);
        #pragma unroll
        for (int j = 0; j < 6; j++) dst[j] = src[j];
    }
    __syncthreads();

    const int w = t >> 6, lane = t & 63;
    const int n = lane & 15, quad = lane >> 4;
    const int mt = w >> 1, ntb = (w & 1) * 2;

    f32x4 acc[2];
    acc[0] = (f32x4){0.f, 0.f, 0.f, 0.f};
    acc[1] = (f32x4){0.f, 0.f, 0.f, 0.f};

    for (int e = 0; e < 9; e++) {
        int dy = e / 3, dx = e - 3 * dy;
        const unsigned short* A0 = Aw3 + (long)(((e * 4 + mt) * 2 + 0) * 16 + n) * 64 + quad * 8;
        const unsigned short* A1 = Aw3 + (long)(((e * 4 + mt) * 2 + 1) * 16 + n) * 64 + quad * 8;
        short8 ah0 = *(const short8*)(A0);
        short8 ah1 = *(const short8*)(A0 + 32);   // k 32..63 (48.. are zeros)
        short8 al0 = *(const short8*)(A1);
        short8 al1 = *(const short8*)(A1 + 32);
        #pragma unroll
        for (int j = 0; j < 2; j++) {
            int p = (ntb + j) * 16 + n;
            int y = p >> 3, x = p & 7;
            int row = 2 * y + dy;        // (2y-1+dy)+1  halo shift
            int colc = 2 * x + dx;       // (2x-1+dx)+1
            const unsigned short* Bp = s_in + (row * 17 + colc) * C3PITCH + quad * 8;
            short8 bh0 = *(const short8*)(Bp);
            short8 bh1 = *(const short8*)(Bp + 32);
            short8 bl0 = *(const short8*)(Bp + 48);
            short8 bl1 = *(const short8*)(Bp + 48 + 32);
            acc[j] = __builtin_amdgcn_mfma_f32_16x16x32_bf16(ah0, bh0, acc[j], 0, 0, 0);
            acc[j] = __builtin_amdgcn_mfma_f32_16x16x32_bf16(ah1, bh1, acc[j], 0, 0, 0);
            acc[j] = __builtin_amdgcn_mfma_f32_16x16x32_bf16(ah0, bl0, acc[j], 0, 0, 0);
            acc[j] = __builtin_amdgcn_mfma_f32_16x16x32_bf16(ah1, bl1, acc[j], 0, 0, 0);
            acc[j] = __builtin_amdgcn_mfma_f32_16x16x32_bf16(al0, bh0, acc[j], 0, 0, 0);
            acc[j] = __builtin_amdgcn_mfma_f32_16x16x32_bf16(al1, bh1, acc[j], 0, 0, 0);
        }
    }

    float* outp = c3out + (long)img * 4096;
    #pragma unroll
    for (int reg = 0; reg < 4; reg++) {
        int oc = mt * 16 + quad * 4 + reg;
        float bias = b3[oc];
        #pragma unroll
        for (int j = 0; j < 2; j++) {
            int p = (ntb + j) * 16 + n;
            outp[oc * 64 + p] = fmaxf(acc[j][reg] + bias, 0.f);
        }
    }
}

// ============================================================
// Generic fp32 GEMM: Y = act(scale*(X @ W^T) + bias)
// ============================================================
template<int BM, int BN, int BK, int TM, int TN, int ACT, bool SPLITK>
__launch_bounds__(256)
__global__ void gemm_k(const float* __restrict__ Xb, const float* __restrict__ Wb,
                       const float* __restrict__ Bb, float* __restrict__ Yb,
                       int M, int N, int K, int ldY, float scale,
                       long sX, long sW, long sB, long sY, int kChunk)
{
    const int z = blockIdx.z;
    const float* X = Xb + (SPLITK ? 0 : (long)z * sX);
    const float* W = Wb + (SPLITK ? 0 : (long)z * sW);
    const float* B = Bb ? (Bb + (SPLITK ? 0 : (long)z * sB)) : nullptr;
    float* Y = Yb + (SPLITK ? 0 : (long)z * sY);
    int k0 = 0, k1 = K;
    if (SPLITK) { k0 = z * kChunk; k1 = min(K, k0 + kChunk); }

    __shared__ float As[BK][BM + 4];
    __shared__ float Bs[BK][BN + 4];
    const int t = threadIdx.x;
    const int tx = t & 15, ty = t >> 4;
    const int m0 = blockIdx.y * BM, n0 = blockIdx.x * BN;
    float acc[TM][TN];
    #pragma unroll
    for (int i = 0; i < TM; i++)
        #pragma unroll
        for (int j = 0; j < TN; j++) acc[i][j] = 0.f;

    for (int kb = k0; kb < k1; kb += BK) {
        for (int i = t; i < BM * BK; i += 256) {
            int r = i / BK, c = i % BK;
            int mm = m0 + r, kk = kb + c;
            As[c][r] = (mm < M && kk < k1) ? X[(long)mm * K + kk] : 0.f;
        }
        for (int i = t; i < BN * BK; i += 256) {
            int r = i / BK, c = i % BK;
            int nn = n0 + r, kk = kb + c;
            Bs[c][r] = (nn < N && kk < k1) ? W[(long)nn * K + kk] : 0.f;
        }
        __syncthreads();
        #pragma unroll
        for (int kk = 0; kk < BK; kk++) {
            float a[TM], b[TN];
            #pragma unroll
            for (int i = 0; i < TM; i++) a[i] = As[kk][ty * TM + i];
            #pragma unroll
            for (int j = 0; j < TN; j++) b[j] = Bs[kk][tx * TN + j];
            #pragma unroll
            for (int i = 0; i < TM; i++)
                #pragma unroll
                for (int j = 0; j < TN; j++) acc[i][j] += a[i] * b[j];
        }
        __syncthreads();
    }

    #pragma unroll
    for (int i = 0; i < TM; i++) {
        int mm = m0 + ty * TM + i;
        if (mm >= M) continue;
        #pragma unroll
        for (int j = 0; j < TN; j++) {
            int nn = n0 + tx * TN + j;
            if (nn >= N) continue;
            float v = acc[i][j] * scale;
            if (SPLITK) {
                if (z == 0 && B) v += B[nn];
                atomicAdd(&Y[(long)mm * ldY + nn], v);
            } else {
                if (B) v += B[nn];
                if (ACT == 1) v = fmaxf(v, 0.f);
                if (ACT == 2) v = tanhf(v);
                Y[(long)mm * ldY + nn] = v;
            }
        }
    }
}

// ============================================================
__global__ void k_xcat(const float* __restrict__ x_ctx, const float* __restrict__ label,
                       const float* __restrict__ tyw, const float* __restrict__ tyb,
                       float* __restrict__ xcat)
{
    int idx = blockIdx.x * 256 + threadIdx.x;
    if (idx >= 512 * 320) return;
    int r = idx / 320, c = idx % 320;
    float v;
    if (c < 256) v = x_ctx[r * 256 + c];
    else {
        int e = c - 256;
        v = tyb[e] + label[r * 2] * tyw[e * 2] + label[r * 2 + 1] * tyw[e * 2 + 1];
    }
    xcat[idx] = v;
}

__global__ void k_diag(const float* __restrict__ qa, const float* __restrict__ ka,
                       float* __restrict__ dq, float* __restrict__ dk)
{
    int tok = blockIdx.x * 4 + (threadIdx.x >> 6);
    int l = threadIdx.x & 63;
    const float* src = (tok < 4096) ? qa + (long)tok * 256 : ka + (long)(tok - 4096) * 256;
    float4 f = *(const float4*)(src + l * 4);
    float s = f.x * f.x + f.y * f.y + f.z * f.z + f.w * f.w;
    for (int d = 1; d < 64; d <<= 1) s += __shfl_xor(s, d);
    if (l == 0) {
        float v = s * (1.f / 32.f);
        if (tok < 4096) dq[tok] = v; else dk[tok - 4096] = v;
    }
}

__global__ void k_rowmax(const float* __restrict__ xd, float* __restrict__ mq)
{
    int tok = blockIdx.x;
    const float* row = xd + (long)tok * F_FEAT;
    int t = threadIdx.x;
    float m = -1e30f;
    for (int f = t; f < F_FEAT; f += 256) m = fmaxf(m, row[f]);
    for (int d = 1; d < 64; d <<= 1) m = fmaxf(m, __shfl_xor(m, d));
    __shared__ float sm[4];
    if ((t & 63) == 0) sm[t >> 6] = m;
    __syncthreads();
    if (t == 0) mq[tok] = fmaxf(fmaxf(sm[0], sm[1]), fmaxf(sm[2], sm[3]));
}

__global__ void k_blkmax(const float* __restrict__ xd, float* __restrict__ mk)
{
    int b = blockIdx.x;
    const float* base = xd + (long)b * 32 * F_FEAT;
    int t = threadIdx.x;
    float m = -1e30f;
    for (int i = t; i < 32 * F_FEAT; i += 256) m = fmaxf(m, base[i]);
    for (int d = 1; d < 64; d <<= 1) m = fmaxf(m, __shfl_xor(m, d));
    __shared__ float sm[4];
    if ((t & 63) == 0) sm[t >> 6] = m;
    __syncthreads();
    if (t == 0) mk[b] = fmaxf(fmaxf(sm[0], sm[1]), fmaxf(sm[2], sm[3]));
}

__global__ void k_exp(float* __restrict__ xd, const float* __restrict__ diag,
                      const float* __restrict__ mrow, int per_row)
{
    int tok = blockIdx.y;
    int f = blockIdx.x * 256 + threadIdx.x;
    if (f >= F_FEAT) return;
    long i = (long)tok * F_FEAT + f;
    float m = per_row ? mrow[tok] : mrow[tok >> 5];
    xd[i] = RATIO * (expf(xd[i] - diag[tok] - m) + 1e-4f);
}

// ============================================================
__launch_bounds__(256)
__global__ void k_attn(const float* __restrict__ qp, const float* __restrict__ kp,
                       const float* __restrict__ va, float* __restrict__ rep_in)
{
    const int tt = blockIdx.x;  // 0..15
    const int h  = blockIdx.y;  // 0..7
    const long row0 = ((long)h * 16 + tt) * 32;

    __shared__ float s_q[32][68];
    __shared__ float s_k[32][68];
    __shared__ float s_A[32][33];
    __shared__ float s_di[32];
    __shared__ float s_v[32 * 256];

    const int t = threadIdx.x;
    const int n = t >> 3;          // 0..31
    const int mq = (t & 7) * 4;    // A column group

    float acc[4] = {0, 0, 0, 0};
    for (int fc = 0; fc < F_FEAT; fc += 64) {
        for (int i = t; i < 2048; i += 256) {
            int rr = i >> 6, ff = i & 63;
            int fg = fc + ff;
            s_q[rr][ff] = (fg < F_FEAT) ? qp[(row0 + rr) * F_FEAT + fg] : 0.f;
            s_k[rr][ff] = (fg < F_FEAT) ? kp[(row0 + rr) * F_FEAT + fg] : 0.f;
        }
        __syncthreads();
        #pragma unroll 8
        for (int ff = 0; ff < 64; ff++) {
            float a = s_q[n][ff];
            #pragma unroll
            for (int j = 0; j < 4; j++) acc[j] += a * s_k[mq + j][ff];
        }
        __syncthreads();
    }

    float rsum = acc[0] + acc[1] + acc[2] + acc[3];
    rsum += __shfl_xor(rsum, 1);
    rsum += __shfl_xor(rsum, 2);
    rsum += __shfl_xor(rsum, 4);
    #pragma unroll
    for (int j = 0; j < 4; j++) s_A[n][mq + j] = acc[j];
    if ((t & 7) == 0) s_di[n] = 1.f / rsum;
    for (int i = t; i < 8192; i += 256) s_v[i] = va[row0 * 256 + i];
    __syncthreads();

    const int e0 = t & 7;
    float out[32];
    #pragma unroll
    for (int j = 0; j < 32; j++) out[j] = 0.f;
    for (int m = 0; m < 32; m++) {
        float a = s_A[n][m];
        #pragma unroll
        for (int j = 0; j < 32; j++) out[j] += a * s_v[m * 256 + e0 + 8 * j];
    }
    float di = s_di[n];
    float* dst = rep_in + ((long)tt * 32 + n) * 2048;
    #pragma unroll
    for (int j = 0; j < 32; j++) {
        int e = e0 + 8 * j;
        dst[e * 8 + h] = out[j] * di;
    }
}

__global__ void k_xzcopy(const float* __restrict__ xq, float* __restrict__ xz)
{
    int idx = blockIdx.x * 256 + threadIdx.x;
    if (idx >= 512 * 256) return;
    int r = idx >> 8, c = idx & 255;
    xz[r * 384 + c] = xq[idx];
}

__global__ void k_fin(float* __restrict__ out) { if (threadIdx.x == 0) out[1024] = 0.f; }

// ============================================================
extern "C" void kernel_launch(void* const* d_in, const int* in_sizes, int n_in,
                              void* d_out, int out_size, void* d_ws, size_t ws_size,
                              hipStream_t stream)
{
    const float* train  = (const float*)d_in[0];
    const float* label  = (const float*)d_in[1];
    const float* test   = (const float*)d_in[2];
    const float* c1w = (const float*)d_in[3];  const float* c1b = (const float*)d_in[4];
    const float* c2w = (const float*)d_in[5];  const float* c2b = (const float*)d_in[6];
    const float* c3w = (const float*)d_in[7];  const float* c3b = (const float*)d_in[8];
    const float* elw = (const float*)d_in[9];  const float* elb = (const float*)d_in[10];
    const float* tyw = (const float*)d_in[11]; const float* tyb = (const float*)d_in[12];
    const float* ew1 = (const float*)d_in[13]; const float* eb1 = (const float*)d_in[14];
    const float* ew2 = (const float*)d_in[15]; const float* eb2 = (const float*)d_in[16];
    const float* ew3 = (const float*)d_in[17]; const float* eb3 = (const float*)d_in[18];
    const float* wq  = (const float*)d_in[19]; const float* wqb = (const float*)d_in[20];
    const float* wk  = (const float*)d_in[21]; const float* wkb = (const float*)d_in[22];
    const float* wv  = (const float*)d_in[23]; const float* wvb = (const float*)d_in[24];
    const float* wow = (const float*)d_in[25]; const float* wob = (const float*)d_in[26];
    const float* rzw = (const float*)d_in[27]; const float* rzb = (const float*)d_in[28];
    const float* dw1 = (const float*)d_in[29]; const float* db1 = (const float*)d_in[30];
    const float* dw2 = (const float*)d_in[31]; const float* db2 = (const float*)d_in[32];
    const float* dw3 = (const float*)d_in[33]; const float* db3 = (const float*)d_in[34];
    const float* proj= (const float*)d_in[35];

    float* wsf = (float*)d_ws;
    float* out = (float*)d_out;

    unsigned short* A_pool = (unsigned short*)(wsf + OFF_POOL);
    float* A_c3   = wsf + OFF_C3;
    float* x_ctx  = wsf + OFF_XCTX;
    float* x_qry  = wsf + OFF_XQRY;
    float* xcat   = wsf + OFF_XCAT;
    float* h1     = wsf + OFF_H1;
    float* h2     = wsf + OFF_H2;
    float* rs     = wsf + OFF_RS;
    float* q_all  = wsf + OFF_QA;
    float* k_all  = wsf + OFF_KA;
    float* v_all  = wsf + OFF_VA;
    float* dq     = wsf + OFF_DQ;
    float* dk     = wsf + OFF_DK;
    float* m_q    = wsf + OFF_MQ;
    float* m_k    = wsf + OFF_MK;
    float* rep_in = wsf + OFF_REPIN;
    float* rep    = wsf + OFF_REP;
    float* xz     = wsf + OFF_XZ;
    float* dh1    = wsf + OFF_DH1;
    float* dh2    = wsf + OFF_DH2;
    float* xd_q   = wsf + OFF_XDQ;
    float* xd_k   = wsf + OFF_XDK;
    unsigned short* Aw  = (unsigned short*)(wsf + OFF_AW);
    unsigned short* Aw3 = (unsigned short*)(wsf + OFF_AW3);

    // ---- encoder ----
    k_wprep<<<54, 256, 0, stream>>>(c2w, Aw);
    k_wprep3<<<288, 256, 0, stream>>>(c3w, Aw3);
    k_conv12m<<<dim3(8, 1024), 256, 0, stream>>>(train, test, c1w, c1b, Aw, c2b, A_pool);
    k_conv3m<<<1024, 512, 0, stream>>>(A_pool, Aw3, c3b, A_c3);

    hipMemsetAsync(x_ctx, 0, 1024 * 256 * sizeof(float), stream);   // x_ctx + x_qry
    gemm_k<64,64,16,4,4,0,true><<<dim3(4, 16, 8), 256, 0, stream>>>(
        A_c3, elw, elb, x_ctx, 1024, 256, 4096, 256, 1.f, 0, 0, 0, 0, 512);

    // ---- xcat + er MLP -> rs ----
    k_xcat<<<640, 256, 0, stream>>>(x_ctx, label, tyw, tyb, xcat);
    gemm_k<32,32,32,2,2,1,false><<<dim3(8, 16, 1), 256, 0, stream>>>(
        xcat, ew1, eb1, h1, 512, 256, 320, 256, 1.f, 0, 0, 0, 0, 0);
    gemm_k<32,32,32,2,2,1,false><<<dim3(8, 16, 1), 256, 0, stream>>>(
        h1, ew2, eb2, h2, 512, 256, 256, 256, 1.f, 0, 0, 0, 0, 0);
    gemm_k<32,32,32,2,2,0,false><<<dim3(8, 16, 1), 256, 0, stream>>>(
        h2, ew3, eb3, rs, 512, 256, 256, 256, 1.f, 0, 0, 0, 0, 0);

    // ---- q/k/v per-head projections ----
    gemm_k<64,64,16,4,4,0,false><<<dim3(4, 8, 8), 256, 0, stream>>>(
        x_qry, wq, wqb, q_all, 512, 256, 256, 256, 1.f, 0, 65536, 256, 131072, 0);
    gemm_k<64,64,16,4,4,0,false><<<dim3(4, 8, 8), 256, 0, stream>>>(
        x_ctx, wk, wkb, k_all, 512, 256, 256, 256, 1.f, 0, 65536, 256, 131072, 0);
    gemm_k<64,64,16,4,4,0,false><<<dim3(4, 8, 8), 256, 0, stream>>>(
        rs, wv, wvb, v_all, 512, 256, 256, 256, 1.f, 0, 65536, 256, 131072, 0);

    // ---- performer features: xd = dn * (x @ proj^T) ----
    gemm_k<64,64,16,4,4,0,false><<<dim3(23, 64, 1), 256, 0, stream>>>(
        q_all, proj, nullptr, xd_q, 4096, F_FEAT, 256, F_FEAT, DN, 0, 0, 0, 0, 0);
    gemm_k<64,64,16,4,4,0,false><<<dim3(23, 64, 1), 256, 0, stream>>>(
        k_all, proj, nullptr, xd_k, 4096, F_FEAT, 256, F_FEAT, DN, 0, 0, 0, 0, 0);

    k_diag<<<2048, 256, 0, stream>>>(q_all, k_all, dq, dk);
    k_rowmax<<<4096, 256, 0, stream>>>(xd_q, m_q);
    k_blkmax<<<128, 256, 0, stream>>>(xd_k, m_k);
    k_exp<<<dim3(6, 4096), 256, 0, stream>>>(xd_q, dq, m_q, 1);
    k_exp<<<dim3(6, 4096), 256, 0, stream>>>(xd_k, dk, m_k, 0);

    // ---- attention + permuted concat ----
    k_attn<<<dim3(16, 8), 256, 0, stream>>>(xd_q, xd_k, v_all, rep_in);

    // ---- rep = rep_in @ wo^T + b (split-K) ----
    hipMemsetAsync(rep, 0, 512 * 256 * sizeof(float), stream);
    gemm_k<64,64,16,4,4,0,true><<<dim3(4, 8, 8), 256, 0, stream>>>(
        rep_in, wow, wob, rep, 512, 256, 2048, 256, 1.f, 0, 0, 0, 0, 256);

    // ---- xz = [x_qry | rep @ rz^T + b] ----
    k_xzcopy<<<512, 256, 0, stream>>>(x_qry, xz);
    gemm_k<32,32,32,2,2,0,false><<<dim3(4, 16, 1), 256, 0, stream>>>(
        rep, rzw, rzb, xz + 256, 512, 128, 256, 384, 1.f, 0, 0, 0, 0, 0);

    // ---- decoder ----
    gemm_k<32,32,32,2,2,1,false><<<dim3(4, 16, 1), 256, 0, stream>>>(
        xz, dw1, db1, dh1, 512, 100, 384, 100, 1.f, 0, 0, 0, 0, 0);
    gemm_k<32,32,32,2,2,1,false><<<dim3(4, 16, 1), 256, 0, stream>>>(
        dh1, dw2, db2, dh2, 512, 100, 100, 100, 1.f, 0, 0, 0, 0, 0);
    gemm_k<32,32,32,2,2,2,false><<<dim3(1, 16, 1), 256, 0, stream>>>(
        dh2, dw3, db3, out, 512, 2, 100, 2, 1.f, 0, 0, 0, 0, 0);

    k_fin<<<1, 64, 0, stream>>>(out);
}

// Round 4
// 924.846 us; speedup vs baseline: 4.6291x; 1.2597x over previous
//
#include <hip/hip_runtime.h>
#include <math.h>

// ---------------- problem constants ----------------
// T=16, NC=NQ=32, DW=256, DR=256, DZ=128, NH=8, F=1419
#define F_FEAT 1419
static constexpr float RATIO = 0.026546563287556634f; // 1419^-0.5
static constexpr float DN    = 0.25f;                 // 256^-0.25

typedef short short8 __attribute__((ext_vector_type(8)));
typedef float f32x4  __attribute__((ext_vector_type(4)));
typedef _Float16 h16x4 __attribute__((ext_vector_type(4)));

// ---------------- workspace layout (float offsets) ----------------
// Region [0 .. 12,582,912) floats: pool (stage A) -> W planes + xd (stage B) + tail planes
static constexpr long OFF_POOL = 0;                  // [1024][256 pix][96] bf16
static constexpr long OFF_XDQ  = 0;                  // [4096][1419] f32 (written after W planes consumed)
static constexpr long OFF_XDK  = 5812224;            // [4096][1419] f32
// W planes (ush offsets): live conv3m -> qkv, then overwritten by xd_q
static constexpr long U_WQH = 0;                     // 524288 ush each
static constexpr long U_WQL = 524288;
static constexpr long U_WKH = 1048576;
static constexpr long U_WKL = 1572864;
static constexpr long U_WVH = 2097152;
static constexpr long U_WVL = 2621440;               // ends 3145728 ush = 1572864 floats < xd_q region end
// tail planes (after xd_k end 11,624,448 floats = 23,248,896 ush)
static constexpr long U_PH  = 23248896;              // [1472][256] ush
static constexpr long U_PL  = 23625728;
static constexpr long U_XCH = 24002560;              // [1024][256] ush (x_ctx rows 0..511, x_qry 512..1023)
static constexpr long U_XCL = 24264704;
static constexpr long U_RSH = 24526848;              // [512][256] ush
static constexpr long U_RSL = 24657920;              // ends 24788992 ush < 25165824
static constexpr long OFF_C3   = 12582912;           // C3 planes region (old fp32 c3 slot, same bytes)
static constexpr long U_C3H = 25165824;              // [1024][4096] ush
static constexpr long U_C3L = 29360128;              // ends 33554432 ush = 16777216 floats = BASE
static constexpr long BASE     = 16777216;
static constexpr long OFF_XCTX = BASE + 0;           // [512][256] f32
static constexpr long OFF_XQRY = BASE + 131072;      // [512][256] f32
static constexpr long OFF_XCAT = BASE + 262144;      // [512][320]
static constexpr long OFF_H1   = BASE + 425984;      // [512][256]
static constexpr long OFF_H2   = BASE + 557056;      // [512][256]
static constexpr long OFF_RS   = BASE + 688128;      // [512][256]
static constexpr long OFF_QA   = BASE + 819200;      // Q planes: [8][512][256] ush x2 (hi, lo)
static constexpr long U_QH  = (BASE + 819200) * 2;
static constexpr long U_QL  = U_QH + 1048576;
static constexpr long OFF_KA   = BASE + 1867776;     // K planes likewise
static constexpr long U_KH  = (BASE + 1867776) * 2;
static constexpr long U_KL  = U_KH + 1048576;
static constexpr long OFF_VA   = BASE + 2916352;     // [8][512][256] f32
static constexpr long OFF_DQ   = BASE + 3964928;     // [4096]
static constexpr long OFF_DK   = BASE + 3969024;     // [4096]
static constexpr long OFF_MQ   = BASE + 3973120;     // [4096]
static constexpr long OFF_MK   = BASE + 3977216;     // [128]
static constexpr long OFF_REPIN= BASE + 3977344;     // [512][2048] f32 ; EL planes alias (dead before attn)
static constexpr long U_ELH = (BASE + 3977344) * 2;  // [256][4096] ush
static constexpr long U_ELL = U_ELH + 1048576;
static constexpr long OFF_REP  = BASE + 5025920;     // [512][256]
static constexpr long OFF_XZ   = BASE + 5156992;     // [512][384]
static constexpr long OFF_DH1  = BASE + 5353600;     // [512][100]
static constexpr long OFF_DH2  = BASE + 5404800;     // [512][100]
static constexpr long OFF_AW   = 22233216;           // conv2 A-weights bf16 (13824 ushort)
static constexpr long OFF_AW3  = 22240128;           // conv3 A-weights bf16 (73728 ushort)

__device__ inline unsigned short f2bf(float f) {
    unsigned int x = __float_as_uint(f);
    unsigned int r = x + 0x7fffu + ((x >> 16) & 1u);
    return (unsigned short)(r >> 16);
}
__device__ inline float bf2f(unsigned short h) {
    return __uint_as_float((unsigned int)h << 16);
}

// ============================================================
// fp32 -> bf16 hi/lo planes
// ============================================================
__global__ void k_cvt(const float* __restrict__ s, unsigned short* __restrict__ dh,
                      unsigned short* __restrict__ dl, int n)
{
    int i = blockIdx.x * 256 + threadIdx.x;
    if (i >= n) return;
    float v = s[i];
    unsigned short h = f2bf(v);
    dh[i] = h;
    dl[i] = f2bf(v - bf2f(h));
}
__global__ void k_cvtp(const float* __restrict__ s, unsigned short* __restrict__ dh,
                       unsigned short* __restrict__ dl, int nsrc, int ntot)
{
    int i = blockIdx.x * 256 + threadIdx.x;
    if (i >= ntot) return;
    float v = (i < nsrc) ? s[i] : 0.f;
    unsigned short h = f2bf(v);
    dh[i] = h;
    dl[i] = f2bf(v - bf2f(h));
}

// ============================================================
// w2 -> Aw [tap][mt 3][m 16][ic 32] bf16
// ============================================================
__global__ void k_wprep(const float* __restrict__ w2, unsigned short* __restrict__ Aw)
{
    int i = blockIdx.x * 256 + threadIdx.x;
    if (i >= 13824) return;
    int ic  = i & 31;
    int m16 = (i >> 5) & 15;
    int emt = i >> 9;
    int mt  = emt % 3;
    int e   = emt / 3;
    int oc  = mt * 16 + m16;
    Aw[i] = f2bf(w2[(oc * 32 + ic) * 9 + e]);
}

// ============================================================
// w3 -> Aw3 [tap 9][mt 4][hl 2][m 16][k 64] bf16 (hi/lo, k>=48 zero)
// ============================================================
__global__ void k_wprep3(const float* __restrict__ w3, unsigned short* __restrict__ Aw3)
{
    int i = blockIdx.x * 256 + threadIdx.x;
    if (i >= 73728) return;
    int k  = i & 63;
    int m  = (i >> 6) & 15;
    int hl = (i >> 10) & 1;
    int mt = (i >> 11) & 3;
    int e  = i >> 13;
    unsigned short v = 0;
    if (k < 48) {
        int oc = mt * 16 + m;
        float w = w3[(oc * 48 + k) * 9 + e];
        unsigned short hi = f2bf(w);
        v = hl == 0 ? hi : f2bf(w - bf2f(hi));
    }
    Aw3[i] = v;
}

// ============================================================
// Fused conv1 (fp32 VALU, fp16-LDS-staged input) -> bf16 ring -> conv2 MFMA
// -> bias/relu/maxpool -> bf16 hi/lo pool [img][pix 256][hi48|lo48]
// ============================================================
__launch_bounds__(256)
__global__ void k_conv12m(const float* __restrict__ train, const float* __restrict__ test,
                          const float* __restrict__ w1, const float* __restrict__ b1,
                          const unsigned short* __restrict__ Aw, const float* __restrict__ b2,
                          unsigned short* __restrict__ pool_out)
{
    const int g   = blockIdx.x;
    const int img = blockIdx.y;
    const float* in = (img < 512) ? (train + (long)img * 16384)
                                  : (test  + (long)(img - 512) * 16384);

    __shared__ unsigned short ring[9 * 66 * 40];   // 47520 B
    __shared__ unsigned short s_inp[19 * 132];     // 5016 B (fp16 input rows)
    float* scratch = (float*)ring;

    const int t = threadIdx.x;

    // zero pad column c=0 of every ring slot
    for (int i = t; i < 9 * 40; i += 256) {
        int s = i / 40, icp = i % 40;
        ring[(s * 66 + 0) * 40 + icp] = 0;
    }
    if (g == 0)
        for (int i = t; i < 66 * 40; i += 256) ring[i] = 0;

    // ---- stage 19 input rows as fp16 ----
    const int rlo = 16 * g - 3;
    for (int q = t; q < 608; q += 256) {
        int rr = q >> 5;
        int cq = (q & 31) * 4;
        int r = rlo + rr;
        float4 f = (r >= 0) ? *(const float4*)&in[r * 128 + cq] : make_float4(0.f, 0.f, 0.f, 0.f);
        h16x4 hv = { (_Float16)f.x, (_Float16)f.y, (_Float16)f.z, (_Float16)f.w };
        *(h16x4*)&s_inp[rr * 132 + cq] = hv;
    }
    __syncthreads();

    // ---- conv1 phase: thread = (col 0..63, icq 0..3 -> ics icq*8..+8) ----
    const int col = t & 63;
    const int icq = t >> 6;
    float wr[8][9], bb[8];
    #pragma unroll
    for (int j = 0; j < 8; j++) {
        int ic = icq * 8 + j;
        bb[j] = b1[ic];
        #pragma unroll
        for (int q = 0; q < 9; q++) wr[j][q] = w1[ic * 9 + q];
    }

    for (int s = (g == 0 ? 1 : 0); s < 9; s++) {
        float v[3][3];
        #pragma unroll
        for (int dyy = 0; dyy < 3; dyy++) {
            int base = (2 * s + dyy) * 132;
            #pragma unroll
            for (int dxx = 0; dxx < 3; dxx++) {
                int xx = 2 * col - 1 + dxx;
                int xi = xx < 0 ? 0 : xx;
                float raw = (float)(*(const _Float16*)&s_inp[base + xi]);
                v[dyy][dxx] = (xx >= 0) ? raw : 0.f;
            }
        }
        unsigned short o[8];
        #pragma unroll
        for (int j = 0; j < 8; j++) {
            float a = bb[j];
            #pragma unroll
            for (int q = 0; q < 9; q++) a += v[q / 3][q % 3] * wr[j][q];
            o[j] = f2bf(fmaxf(a, 0.f));
        }
        *(uint4*)&ring[(s * 66 + col + 1) * 40 + icq * 8] = *(const uint4*)o;
    }
    __syncthreads();

    // ---- MFMA phase ----
    const int w    = t >> 6;
    const int lane = t & 63;
    const int n    = lane & 15;
    const int quad = lane >> 4;

    f32x4 acc[3][2];
    #pragma unroll
    for (int mt = 0; mt < 3; mt++)
        #pragma unroll
        for (int xh = 0; xh < 2; xh++) acc[mt][xh] = (f32x4){0.f, 0.f, 0.f, 0.f};

    for (int e = 0; e < 9; e++) {
        int dy = e / 3, dx = e - 3 * dy;
        short8 a0 = *(const short8*)&Aw[((e * 3 + 0) * 16 + n) * 32 + quad * 8];
        short8 a1 = *(const short8*)&Aw[((e * 3 + 1) * 16 + n) * 32 + quad * 8];
        short8 a2 = *(const short8*)&Aw[((e * 3 + 2) * 16 + n) * 32 + quad * 8];
        int s = 2 * w + dy;
        #pragma unroll
        for (int xh = 0; xh < 2; xh++) {
            int c = 2 * (xh * 16 + n) + dx;
            short8 bfr = *(const short8*)&ring[(s * 66 + c) * 40 + quad * 8];
            acc[0][xh] = __builtin_amdgcn_mfma_f32_16x16x32_bf16(a0, bfr, acc[0][xh], 0, 0, 0);
            acc[1][xh] = __builtin_amdgcn_mfma_f32_16x16x32_bf16(a1, bfr, acc[1][xh], 0, 0, 0);
            acc[2][xh] = __builtin_amdgcn_mfma_f32_16x16x32_bf16(a2, bfr, acc[2][xh], 0, 0, 0);
        }
    }
    __syncthreads();

    #pragma unroll
    for (int mt = 0; mt < 3; mt++) {
        #pragma unroll
        for (int reg = 0; reg < 4; reg++) {
            int oc = mt * 16 + quad * 4 + reg;
            float bias = b2[oc];
            #pragma unroll
            for (int xh = 0; xh < 2; xh++) {
                int x = xh * 16 + n;
                scratch[(w * 32 + x) * 52 + oc] = fmaxf(acc[mt][xh][reg] + bias, 0.f);
            }
        }
    }
    __syncthreads();

    for (int i = t; i < 1536; i += 256) {
        int oc = i % 48; int pp = i / 48; int px = pp & 15, pr = pp >> 4;
        const float* b0 = &scratch[((2 * pr) * 32 + 2 * px) * 52 + oc];
        float m = fmaxf(fmaxf(b0[0], b0[52]), fmaxf(b0[32 * 52], b0[33 * 52]));
        unsigned short hi = f2bf(m);
        unsigned short lo = f2bf(m - bf2f(hi));
        long base = ((long)img * 256 + (2 * g + pr) * 16 + px) * 96;
        pool_out[base + oc] = hi;
        pool_out[base + 48 + oc] = lo;
    }
}

// ============================================================
// conv3 via MFMA hi/lo; output -> bf16 hi/lo planes [1024][4096]
// ============================================================
#define C3PITCH 104
__launch_bounds__(512)
__global__ void k_conv3m(const unsigned short* __restrict__ pool,
                         const unsigned short* __restrict__ Aw3,
                         const float* __restrict__ b3,
                         unsigned short* __restrict__ C3h, unsigned short* __restrict__ C3l)
{
    const int img = blockIdx.x;
    __shared__ unsigned short s_in[30120];
    const int t = threadIdx.x;

    uint4* s4 = (uint4*)s_in;
    const uint4 zz = make_uint4(0, 0, 0, 0);
    for (int i = t; i < 3765; i += 512) s4[i] = zz;
    __syncthreads();
    {
        int p = t >> 1, half = t & 1;
        const uint4* src = (const uint4*)(pool + ((long)img * 256 + p) * 96 + half * 48);
        int r = p >> 4, c = p & 15;
        uint4* dst = (uint4*)(s_in + ((r + 1) * 17 + (c + 1)) * C3PITCH + half * 48);
        #pragma unroll
        for (int j = 0; j < 6; j++) dst[j] = src[j];
    }
    __syncthreads();

    const int w = t >> 6, lane = t & 63;
    const int n = lane & 15, quad = lane >> 4;
    const int mt = w >> 1, ntb = (w & 1) * 2;

    f32x4 acc[2];
    acc[0] = (f32x4){0.f, 0.f, 0.f, 0.f};
    acc[1] = (f32x4){0.f, 0.f, 0.f, 0.f};

    for (int e = 0; e < 9; e++) {
        int dy = e / 3, dx = e - 3 * dy;
        const unsigned short* A0 = Aw3 + (long)(((e * 4 + mt) * 2 + 0) * 16 + n) * 64 + quad * 8;
        const unsigned short* A1 = Aw3 + (long)(((e * 4 + mt) * 2 + 1) * 16 + n) * 64 + quad * 8;
        short8 ah0 = *(const short8*)(A0);
        short8 ah1 = *(const short8*)(A0 + 32);
        short8 al0 = *(const short8*)(A1);
        short8 al1 = *(const short8*)(A1 + 32);
        #pragma unroll
        for (int j = 0; j < 2; j++) {
            int p = (ntb + j) * 16 + n;
            int y = p >> 3, x = p & 7;
            int row = 2 * y + dy;
            int colc = 2 * x + dx;
            const unsigned short* Bp = s_in + (row * 17 + colc) * C3PITCH + quad * 8;
            short8 bh0 = *(const short8*)(Bp);
            short8 bh1 = *(const short8*)(Bp + 32);
            short8 bl0 = *(const short8*)(Bp + 48);
            short8 bl1 = *(const short8*)(Bp + 48 + 32);
            acc[j] = __builtin_amdgcn_mfma_f32_16x16x32_bf16(ah0, bh0, acc[j], 0, 0, 0);
            acc[j] = __builtin_amdgcn_mfma_f32_16x16x32_bf16(ah1, bh1, acc[j], 0, 0, 0);
            acc[j] = __builtin_amdgcn_mfma_f32_16x16x32_bf16(ah0, bl0, acc[j], 0, 0, 0);
            acc[j] = __builtin_amdgcn_mfma_f32_16x16x32_bf16(ah1, bl1, acc[j], 0, 0, 0);
            acc[j] = __builtin_amdgcn_mfma_f32_16x16x32_bf16(al0, bh0, acc[j], 0, 0, 0);
            acc[j] = __builtin_amdgcn_mfma_f32_16x16x32_bf16(al1, bh1, acc[j], 0, 0, 0);
        }
    }

    unsigned short* oh = C3h + (long)img * 4096;
    unsigned short* ol = C3l + (long)img * 4096;
    #pragma unroll
    for (int reg = 0; reg < 4; reg++) {
        int oc = mt * 16 + quad * 4 + reg;
        float bias = b3[oc];
        #pragma unroll
        for (int j = 0; j < 2; j++) {
            int p = (ntb + j) * 16 + n;
            float v = fmaxf(acc[j][reg] + bias, 0.f);
            unsigned short h = f2bf(v);
            oh[oc * 64 + p] = h;
            ol[oc * 64 + p] = f2bf(v - bf2f(h));
        }
    }
}

// ============================================================
// bf16 hi/lo MFMA GEMM: Y = scale*(X @ W^T) + bias   (3-term, ~fp32 acc)
// X planes [M][K], W planes [N][K]. BM=BN=64, BK=32, 256 thr = 4 waves.
// OUTMODE 0: f32 out (z-batched) ; 1: hi/lo planes out (z-batched) ;
// 2: f32 split-K atomic (z = k-chunk).
// ============================================================
template<int OUTMODE>
__launch_bounds__(256)
__global__ void mgemm(const unsigned short* __restrict__ Xh, const unsigned short* __restrict__ Xl,
                      const unsigned short* __restrict__ Wph, const unsigned short* __restrict__ Wpl,
                      const float* __restrict__ Bb, float* __restrict__ Yf,
                      unsigned short* __restrict__ Yh, unsigned short* __restrict__ Yl,
                      int M, int N, int K, int ldY, float scale,
                      long sW, long sB, long sY, int kChunk)
{
    const int z = blockIdx.z;
    const unsigned short* Wh = Wph + (OUTMODE == 2 ? 0 : (long)z * sW);
    const unsigned short* Wl = Wpl + (OUTMODE == 2 ? 0 : (long)z * sW);
    const float* B = Bb ? (Bb + (OUTMODE == 2 ? 0 : (long)z * sB)) : nullptr;
    int k0 = 0, k1 = K;
    if (OUTMODE == 2) { k0 = z * kChunk; k1 = min(K, k0 + kChunk); }

    __shared__ unsigned short sAh[64 * 40], sAl[64 * 40], sBh[64 * 40], sBl[64 * 40];

    const int t = threadIdx.x;
    const int m0 = blockIdx.y * 64, n0 = blockIdx.x * 64;
    const int r = t >> 2, kq = (t & 3) * 8;

    const int w = t >> 6, lane = t & 63;
    const int wm = (w & 1) * 32, wn = (w >> 1) * 32;
    const int cn = lane & 15, quad = lane >> 4;

    f32x4 acc[2][2];
    acc[0][0] = acc[0][1] = acc[1][0] = acc[1][1] = (f32x4){0.f, 0.f, 0.f, 0.f};

    for (int kb = k0; kb < k1; kb += 32) {
        *(uint4*)&sAh[r * 40 + kq] = *(const uint4*)&Xh[(long)(m0 + r) * K + kb + kq];
        *(uint4*)&sAl[r * 40 + kq] = *(const uint4*)&Xl[(long)(m0 + r) * K + kb + kq];
        *(uint4*)&sBh[r * 40 + kq] = *(const uint4*)&Wh[(long)(n0 + r) * K + kb + kq];
        *(uint4*)&sBl[r * 40 + kq] = *(const uint4*)&Wl[(long)(n0 + r) * K + kb + kq];
        __syncthreads();
        short8 axh[2], axl[2], bxh[2], bxl[2];
        #pragma unroll
        for (int i = 0; i < 2; i++) {
            axh[i] = *(const short8*)&sAh[(wm + i * 16 + cn) * 40 + quad * 8];
            axl[i] = *(const short8*)&sAl[(wm + i * 16 + cn) * 40 + quad * 8];
            bxh[i] = *(const short8*)&sBh[(wn + i * 16 + cn) * 40 + quad * 8];
            bxl[i] = *(const short8*)&sBl[(wn + i * 16 + cn) * 40 + quad * 8];
        }
        #pragma unroll
        for (int i = 0; i < 2; i++)
            #pragma unroll
            for (int j = 0; j < 2; j++) {
                acc[i][j] = __builtin_amdgcn_mfma_f32_16x16x32_bf16(axh[i], bxh[j], acc[i][j], 0, 0, 0);
                acc[i][j] = __builtin_amdgcn_mfma_f32_16x16x32_bf16(axh[i], bxl[j], acc[i][j], 0, 0, 0);
                acc[i][j] = __builtin_amdgcn_mfma_f32_16x16x32_bf16(axl[i], bxh[j], acc[i][j], 0, 0, 0);
            }
        __syncthreads();
    }

    #pragma unroll
    for (int i = 0; i < 2; i++) {
        #pragma unroll
        for (int reg = 0; reg < 4; reg++) {
            int row = m0 + wm + i * 16 + quad * 4 + reg;
            #pragma unroll
            for (int j = 0; j < 2; j++) {
                int col = n0 + wn + j * 16 + cn;
                if (col >= N) continue;
                float v = acc[i][j][reg] * scale;
                if (OUTMODE == 2) {
                    if (z == 0 && B) v += B[col];
                    atomicAdd(&Yf[(long)row * ldY + col], v);
                } else if (OUTMODE == 0) {
                    if (B) v += B[col];
                    (Yf + (long)z * sY)[(long)row * ldY + col] = v;
                } else {
                    if (B) v += B[col];
                    unsigned short h = f2bf(v);
                    (Yh + (long)z * sY)[(long)row * ldY + col] = h;
                    (Yl + (long)z * sY)[(long)row * ldY + col] = f2bf(v - bf2f(h));
                }
            }
        }
    }
}

// ============================================================
// Generic fp32 GEMM (small layers): Y = act(scale*(X @ W^T) + bias)
// ============================================================
template<int BM, int BN, int BK, int TM, int TN, int ACT, bool SPLITK>
__launch_bounds__(256)
__global__ void gemm_k(const float* __restrict__ Xb, const float* __restrict__ Wb,
                       const float* __restrict__ Bb, float* __restrict__ Yb,
                       int M, int N, int K, int ldY, float scale,
                       long sX, long sW, long sB, long sY, int kChunk)
{
    const int z = blockIdx.z;
    const float* X = Xb + (SPLITK ? 0 : (long)z * sX);
    const float* W = Wb + (SPLITK ? 0 : (long)z * sW);
    const float* B = Bb ? (Bb + (SPLITK ? 0 : (long)z * sB)) : nullptr;
    float* Y = Yb + (SPLITK ? 0 : (long)z * sY);
    int k0 = 0, k1 = K;
    if (SPLITK) { k0 = z * kChunk; k1 = min(K, k0 + kChunk); }

    __shared__ float As[BK][BM + 4];
    __shared__ float Bs[BK][BN + 4];
    const int t = threadIdx.x;
    const int tx = t & 15, ty = t >> 4;
    const int m0 = blockIdx.y * BM, n0 = blockIdx.x * BN;
    float acc[TM][TN];
    #pragma unroll
    for (int i = 0; i < TM; i++)
        #pragma unroll
        for (int j = 0; j < TN; j++) acc[i][j] = 0.f;

    for (int kb = k0; kb < k1; kb += BK) {
        for (int i = t; i < BM * BK; i += 256) {
            int rr = i / BK, c = i % BK;
            int mm = m0 + rr, kk = kb + c;
            As[c][rr] = (mm < M && kk < k1) ? X[(long)mm * K + kk] : 0.f;
        }
        for (int i = t; i < BN * BK; i += 256) {
            int rr = i / BK, c = i % BK;
            int nn = n0 + rr, kk = kb + c;
            Bs[c][rr] = (nn < N && kk < k1) ? W[(long)nn * K + kk] : 0.f;
        }
        __syncthreads();
        #pragma unroll
        for (int kk = 0; kk < BK; kk++) {
            float a[TM], b[TN];
            #pragma unroll
            for (int i = 0; i < TM; i++) a[i] = As[kk][ty * TM + i];
            #pragma unroll
            for (int j = 0; j < TN; j++) b[j] = Bs[kk][tx * TN + j];
            #pragma unroll
            for (int i = 0; i < TM; i++)
                #pragma unroll
                for (int j = 0; j < TN; j++) acc[i][j] += a[i] * b[j];
        }
        __syncthreads();
    }

    #pragma unroll
    for (int i = 0; i < TM; i++) {
        int mm = m0 + ty * TM + i;
        if (mm >= M) continue;
        #pragma unroll
        for (int j = 0; j < TN; j++) {
            int nn = n0 + tx * TN + j;
            if (nn >= N) continue;
            float v = acc[i][j] * scale;
            if (SPLITK) {
                if (z == 0 && B) v += B[nn];
                atomicAdd(&Y[(long)mm * ldY + nn], v);
            } else {
                if (B) v += B[nn];
                if (ACT == 1) v = fmaxf(v, 0.f);
                if (ACT == 2) v = tanhf(v);
                Y[(long)mm * ldY + nn] = v;
            }
        }
    }
}

// ============================================================
__global__ void k_xcat(const float* __restrict__ x_ctx, const float* __restrict__ label,
                       const float* __restrict__ tyw, const float* __restrict__ tyb,
                       float* __restrict__ xcat)
{
    int idx = blockIdx.x * 256 + threadIdx.x;
    if (idx >= 512 * 320) return;
    int r = idx / 320, c = idx % 320;
    float v;
    if (c < 256) v = x_ctx[r * 256 + c];
    else {
        int e = c - 256;
        v = tyb[e] + label[r * 2] * tyw[e * 2] + label[r * 2 + 1] * tyw[e * 2 + 1];
    }
    xcat[idx] = v;
}

// diag from hi/lo planes (x = hi + lo, exact to 2^-16)
__global__ void k_diag(const unsigned short* __restrict__ Qh, const unsigned short* __restrict__ Ql,
                       const unsigned short* __restrict__ Kh, const unsigned short* __restrict__ Kl,
                       float* __restrict__ dq, float* __restrict__ dk)
{
    int tok = blockIdx.x * 4 + (threadIdx.x >> 6);
    int l = threadIdx.x & 63;
    const unsigned short* ph; const unsigned short* pl; int tt;
    if (tok < 4096) { ph = Qh; pl = Ql; tt = tok; }
    else            { ph = Kh; pl = Kl; tt = tok - 4096; }
    long idx = (long)tt * 256 + l * 4;
    uint2 hh = *(const uint2*)&ph[idx];
    uint2 ll = *(const uint2*)&pl[idx];
    float v0 = bf2f((unsigned short)(hh.x & 0xffff)) + bf2f((unsigned short)(ll.x & 0xffff));
    float v1 = bf2f((unsigned short)(hh.x >> 16))    + bf2f((unsigned short)(ll.x >> 16));
    float v2 = bf2f((unsigned short)(hh.y & 0xffff)) + bf2f((unsigned short)(ll.y & 0xffff));
    float v3 = bf2f((unsigned short)(hh.y >> 16))    + bf2f((unsigned short)(ll.y >> 16));
    float s = v0 * v0 + v1 * v1 + v2 * v2 + v3 * v3;
    for (int d = 1; d < 64; d <<= 1) s += __shfl_xor(s, d);
    if (l == 0) {
        float v = s * (1.f / 32.f);
        if (tok < 4096) dq[tok] = v; else dk[tok - 4096] = v;
    }
}

__global__ void k_rowmax(const float* __restrict__ xd, float* __restrict__ mq)
{
    int tok = blockIdx.x;
    const float* row = xd + (long)tok * F_FEAT;
    int t = threadIdx.x;
    float m = -1e30f;
    for (int f = t; f < F_FEAT; f += 256) m = fmaxf(m, row[f]);
    for (int d = 1; d < 64; d <<= 1) m = fmaxf(m, __shfl_xor(m, d));
    __shared__ float sm[4];
    if ((t & 63) == 0) sm[t >> 6] = m;
    __syncthreads();
    if (t == 0) mq[tok] = fmaxf(fmaxf(sm[0], sm[1]), fmaxf(sm[2], sm[3]));
}

__global__ void k_blkmax(const float* __restrict__ xd, float* __restrict__ mk)
{
    int b = blockIdx.x;
    const float* base = xd + (long)b * 32 * F_FEAT;
    int t = threadIdx.x;
    float m = -1e30f;
    for (int i = t; i < 32 * F_FEAT; i += 256) m = fmaxf(m, base[i]);
    for (int d = 1; d < 64; d <<= 1) m = fmaxf(m, __shfl_xor(m, d));
    __shared__ float sm[4];
    if ((t & 63) == 0) sm[t >> 6] = m;
    __syncthreads();
    if (t == 0) mk[b] = fmaxf(fmaxf(sm[0], sm[1]), fmaxf(sm[2], sm[3]));
}

__global__ void k_exp(float* __restrict__ xd, const float* __restrict__ diag,
                      const float* __restrict__ mrow, int per_row)
{
    int tok = blockIdx.y;
    int f = blockIdx.x * 256 + threadIdx.x;
    if (f >= F_FEAT) return;
    long i = (long)tok * F_FEAT + f;
    float m = per_row ? mrow[tok] : mrow[tok >> 5];
    xd[i] = RATIO * (expf(xd[i] - diag[tok] - m) + 1e-4f);
}

// ============================================================
__launch_bounds__(256)
__global__ void k_attn(const float* __restrict__ qp, const float* __restrict__ kp,
                       const float* __restrict__ va, float* __restrict__ rep_in)
{
    const int tt = blockIdx.x;
    const int h  = blockIdx.y;
    const long row0 = ((long)h * 16 + tt) * 32;

    __shared__ float s_q[32][68];
    __shared__ float s_k[32][68];
    __shared__ float s_A[32][33];
    __shared__ float s_di[32];
    __shared__ float s_v[32 * 256];

    const int t = threadIdx.x;
    const int n = t >> 3;
    const int mq = (t & 7) * 4;

    float acc[4] = {0, 0, 0, 0};
    for (int fc = 0; fc < F_FEAT; fc += 64) {
        for (int i = t; i < 2048; i += 256) {
            int rr = i >> 6, ff = i & 63;
            int fg = fc + ff;
            s_q[rr][ff] = (fg < F_FEAT) ? qp[(row0 + rr) * F_FEAT + fg] : 0.f;
            s_k[rr][ff] = (fg < F_FEAT) ? kp[(row0 + rr) * F_FEAT + fg] : 0.f;
        }
        __syncthreads();
        #pragma unroll 8
        for (int ff = 0; ff < 64; ff++) {
            float a = s_q[n][ff];
            #pragma unroll
            for (int j = 0; j < 4; j++) acc[j] += a * s_k[mq + j][ff];
        }
        __syncthreads();
    }

    float rsum = acc[0] + acc[1] + acc[2] + acc[3];
    rsum += __shfl_xor(rsum, 1);
    rsum += __shfl_xor(rsum, 2);
    rsum += __shfl_xor(rsum, 4);
    #pragma unroll
    for (int j = 0; j < 4; j++) s_A[n][mq + j] = acc[j];
    if ((t & 7) == 0) s_di[n] = 1.f / rsum;
    for (int i = t; i < 8192; i += 256) s_v[i] = va[row0 * 256 + i];
    __syncthreads();

    const int e0 = t & 7;
    float out[32];
    #pragma unroll
    for (int j = 0; j < 32; j++) out[j] = 0.f;
    for (int m = 0; m < 32; m++) {
        float a = s_A[n][m];
        #pragma unroll
        for (int j = 0; j < 32; j++) out[j] += a * s_v[m * 256 + e0 + 8 * j];
    }
    float di = s_di[n];
    float* dst = rep_in + ((long)tt * 32 + n) * 2048;
    #pragma unroll
    for (int j = 0; j < 32; j++) {
        int e = e0 + 8 * j;
        dst[e * 8 + h] = out[j] * di;
    }
}

__global__ void k_xzcopy(const float* __restrict__ xq, float* __restrict__ xz)
{
    int idx = blockIdx.x * 256 + threadIdx.x;
    if (idx >= 512 * 256) return;
    int r = idx >> 8, c = idx & 255;
    xz[r * 384 + c] = xq[idx];
}

__global__ void k_fin(float* __restrict__ out) { if (threadIdx.x == 0) out[1024] = 0.f; }

// ============================================================
extern "C" void kernel_launch(void* const* d_in, const int* in_sizes, int n_in,
                              void* d_out, int out_size, void* d_ws, size_t ws_size,
                              hipStream_t stream)
{
    const float* train  = (const float*)d_in[0];
    const float* label  = (const float*)d_in[1];
    const float* test   = (const float*)d_in[2];
    const float* c1w = (const float*)d_in[3];  const float* c1b = (const float*)d_in[4];
    const float* c2w = (const float*)d_in[5];  const float* c2b = (const float*)d_in[6];
    const float* c3w = (const float*)d_in[7];  const float* c3b = (const float*)d_in[8];
    const float* elw = (const float*)d_in[9];  const float* elb = (const float*)d_in[10];
    const float* tyw = (const float*)d_in[11]; const float* tyb = (const float*)d_in[12];
    const float* ew1 = (const float*)d_in[13]; const float* eb1 = (const float*)d_in[14];
    const float* ew2 = (const float*)d_in[15]; const float* eb2 = (const float*)d_in[16];
    const float* ew3 = (const float*)d_in[17]; const float* eb3 = (const float*)d_in[18];
    const float* wq  = (const float*)d_in[19]; const float* wqb = (const float*)d_in[20];
    const float* wk  = (const float*)d_in[21]; const float* wkb = (const float*)d_in[22];
    const float* wv  = (const float*)d_in[23]; const float* wvb = (const float*)d_in[24];
    const float* wow = (const float*)d_in[25]; const float* wob = (const float*)d_in[26];
    const float* rzw = (const float*)d_in[27]; const float* rzb = (const float*)d_in[28];
    const float* dw1 = (const float*)d_in[29]; const float* db1 = (const float*)d_in[30];
    const float* dw2 = (const float*)d_in[31]; const float* db2 = (const float*)d_in[32];
    const float* dw3 = (const float*)d_in[33]; const float* db3 = (const float*)d_in[34];
    const float* proj= (const float*)d_in[35];

    float* wsf = (float*)d_ws;
    unsigned short* usw = (unsigned short*)d_ws;
    float* out = (float*)d_out;

    unsigned short* A_pool = usw;                    // pool ush at offset 0
    float* x_ctx  = wsf + OFF_XCTX;
    float* x_qry  = wsf + OFF_XQRY;
    float* xcat   = wsf + OFF_XCAT;
    float* h1     = wsf + OFF_H1;
    float* h2     = wsf + OFF_H2;
    float* rs     = wsf + OFF_RS;
    float* v_all  = wsf + OFF_VA;
    float* dq     = wsf + OFF_DQ;
    float* dk     = wsf + OFF_DK;
    float* m_q    = wsf + OFF_MQ;
    float* m_k    = wsf + OFF_MK;
    float* rep_in = wsf + OFF_REPIN;
    float* rep    = wsf + OFF_REP;
    float* xz     = wsf + OFF_XZ;
    float* dh1    = wsf + OFF_DH1;
    float* dh2    = wsf + OFF_DH2;
    float* xd_q   = wsf + OFF_XDQ;
    float* xd_k   = wsf + OFF_XDK;
    unsigned short* Aw  = (unsigned short*)(wsf + OFF_AW);
    unsigned short* Aw3 = (unsigned short*)(wsf + OFF_AW3);

    unsigned short* WQh = usw + U_WQH; unsigned short* WQl = usw + U_WQL;
    unsigned short* WKh = usw + U_WKH; unsigned short* WKl = usw + U_WKL;
    unsigned short* WVh = usw + U_WVH; unsigned short* WVl = usw + U_WVL;
    unsigned short* Ph  = usw + U_PH;  unsigned short* Pl  = usw + U_PL;
    unsigned short* XCh = usw + U_XCH; unsigned short* XCl = usw + U_XCL;
    unsigned short* RSh = usw + U_RSH; unsigned short* RSl = usw + U_RSL;
    unsigned short* C3h = usw + U_C3H; unsigned short* C3l = usw + U_C3L;
    unsigned short* Qh  = usw + U_QH;  unsigned short* Ql  = usw + U_QL;
    unsigned short* Kh  = usw + U_KH;  unsigned short* Kl  = usw + U_KL;
    unsigned short* ELh = usw + U_ELH; unsigned short* ELl = usw + U_ELL;

    // ---- weight preps (independent of heavy kernels) ----
    k_wprep<<<54, 256, 0, stream>>>(c2w, Aw);
    k_wprep3<<<288, 256, 0, stream>>>(c3w, Aw3);
    k_cvt<<<4096, 256, 0, stream>>>(elw, ELh, ELl, 1048576);

    // ---- encoder convs ----
    k_conv12m<<<dim3(8, 1024), 256, 0, stream>>>(train, test, c1w, c1b, Aw, c2b, A_pool);
    k_conv3m<<<1024, 512, 0, stream>>>(A_pool, Aw3, c3b, C3h, C3l);

    // ---- plane preps that reuse the (now dead) pool region ----
    k_cvtp<<<1472, 256, 0, stream>>>(proj, Ph, Pl, 363264, 376832);
    k_cvt<<<2048, 256, 0, stream>>>(wq, WQh, WQl, 524288);
    k_cvt<<<2048, 256, 0, stream>>>(wk, WKh, WKl, 524288);
    k_cvt<<<2048, 256, 0, stream>>>(wv, WVh, WVl, 524288);

    // ---- enc linear: [1024][4096] @ elw^T -> x_ctx/x_qry (split-K=4) ----
    hipMemsetAsync(x_ctx, 0, 1024 * 256 * sizeof(float), stream);
    mgemm<2><<<dim3(4, 16, 4), 256, 0, stream>>>(
        C3h, C3l, ELh, ELl, elb, x_ctx, nullptr, nullptr,
        1024, 256, 4096, 256, 1.f, 0, 0, 0, 1024);
    k_cvt<<<1024, 256, 0, stream>>>(x_ctx, XCh, XCl, 262144);

    // ---- xcat + er MLP -> rs (fp32, small) ----
    k_xcat<<<640, 256, 0, stream>>>(x_ctx, label, tyw, tyb, xcat);
    gemm_k<32,32,32,2,2,1,false><<<dim3(8, 16, 1), 256, 0, stream>>>(
        xcat, ew1, eb1, h1, 512, 256, 320, 256, 1.f, 0, 0, 0, 0, 0);
    gemm_k<32,32,32,2,2,1,false><<<dim3(8, 16, 1), 256, 0, stream>>>(
        h1, ew2, eb2, h2, 512, 256, 256, 256, 1.f, 0, 0, 0, 0, 0);
    gemm_k<32,32,32,2,2,0,false><<<dim3(8, 16, 1), 256, 0, stream>>>(
        h2, ew3, eb3, rs, 512, 256, 256, 256, 1.f, 0, 0, 0, 0, 0);
    k_cvt<<<512, 256, 0, stream>>>(rs, RSh, RSl, 131072);

    // ---- q/k/v projections (z = 8 heads) ----
    mgemm<1><<<dim3(4, 8, 8), 256, 0, stream>>>(
        XCh + 512 * 256, XCl + 512 * 256, WQh, WQl, wqb, nullptr, Qh, Ql,
        512, 256, 256, 256, 1.f, 65536, 256, 131072, 0);
    mgemm<1><<<dim3(4, 8, 8), 256, 0, stream>>>(
        XCh, XCl, WKh, WKl, wkb, nullptr, Kh, Kl,
        512, 256, 256, 256, 1.f, 65536, 256, 131072, 0);
    mgemm<0><<<dim3(4, 8, 8), 256, 0, stream>>>(
        RSh, RSl, WVh, WVl, wvb, v_all, nullptr, nullptr,
        512, 256, 256, 256, 1.f, 65536, 256, 131072, 0);

    // ---- performer features: xd = dn * (x @ proj^T) ----
    mgemm<0><<<dim3(23, 64, 1), 256, 0, stream>>>(
        Qh, Ql, Ph, Pl, nullptr, xd_q, nullptr, nullptr,
        4096, F_FEAT, 256, F_FEAT, DN, 0, 0, 0, 0);
    mgemm<0><<<dim3(23, 64, 1), 256, 0, stream>>>(
        Kh, Kl, Ph, Pl, nullptr, xd_k, nullptr, nullptr,
        4096, F_FEAT, 256, F_FEAT, DN, 0, 0, 0, 0);

    k_diag<<<2048, 256, 0, stream>>>(Qh, Ql, Kh, Kl, dq, dk);
    k_rowmax<<<4096, 256, 0, stream>>>(xd_q, m_q);
    k_blkmax<<<128, 256, 0, stream>>>(xd_k, m_k);
    k_exp<<<dim3(6, 4096), 256, 0, stream>>>(xd_q, dq, m_q, 1);
    k_exp<<<dim3(6, 4096), 256, 0, stream>>>(xd_k, dk, m_k, 0);

    // ---- attention + permuted concat ----
    k_attn<<<dim3(16, 8), 256, 0, stream>>>(xd_q, xd_k, v_all, rep_in);

    // ---- rep = rep_in @ wo^T + b (fp32 split-K) ----
    hipMemsetAsync(rep, 0, 512 * 256 * sizeof(float), stream);
    gemm_k<64,64,16,4,4,0,true><<<dim3(4, 8, 8), 256, 0, stream>>>(
        rep_in, wow, wob, rep, 512, 256, 2048, 256, 1.f, 0, 0, 0, 0, 256);

    // ---- xz = [x_qry | rep @ rz^T + b] ----
    k_xzcopy<<<512, 256, 0, stream>>>(x_qry, xz);
    gemm_k<32,32,32,2,2,0,false><<<dim3(4, 16, 1), 256, 0, stream>>>(
        rep, rzw, rzb, xz + 256, 512, 128, 256, 384, 1.f, 0, 0, 0, 0, 0);

    // ---- decoder ----
    gemm_k<32,32,32,2,2,1,false><<<dim3(4, 16, 1), 256, 0, stream>>>(
        xz, dw1, db1, dh1, 512, 100, 384, 100, 1.f, 0, 0, 0, 0, 0);
    gemm_k<32,32,32,2,2,1,false><<<dim3(4, 16, 1), 256, 0, stream>>>(
        dh1, dw2, db2, dh2, 512, 100, 100, 100, 1.f, 0, 0, 0, 0, 0);
    gemm_k<32,32,32,2,2,2,false><<<dim3(1, 16, 1), 256, 0, stream>>>(
        dh2, dw3, db3, out, 512, 2, 100, 2, 1.f, 0, 0, 0, 0, 0);

    k_fin<<<1, 64, 0, stream>>>(out);
}

// Round 5
// 869.472 us; speedup vs baseline: 4.9239x; 1.0637x over previous
//
#include <hip/hip_runtime.h>
#include <math.h>

// ---------------- problem constants ----------------
// T=16, NC=NQ=32, DW=256, DR=256, DZ=128, NH=8, F=1419
#define F_FEAT 1419
static constexpr float RATIO = 0.026546563287556634f; // 1419^-0.5
static constexpr float DN    = 0.25f;                 // 256^-0.25

typedef short short8 __attribute__((ext_vector_type(8)));
typedef float f32x4  __attribute__((ext_vector_type(4)));

// ---------------- workspace layout (float offsets) ----------------
static constexpr long OFF_POOL = 0;                  // [1024][256 pix][96] bf16
static constexpr long OFF_XDQ  = 0;                  // [4096][1419] f32 (after W planes consumed)
static constexpr long OFF_XDK  = 5812224;            // [4096][1419] f32
static constexpr long U_WQH = 0;                     // 524288 ush each (dead once qkv mgemms done)
static constexpr long U_WQL = 524288;
static constexpr long U_WKH = 1048576;
static constexpr long U_WKL = 1572864;
static constexpr long U_WVH = 2097152;
static constexpr long U_WVL = 2621440;
static constexpr long U_PH  = 23248896;              // [1472][256] ush
static constexpr long U_PL  = 23625728;
static constexpr long U_XCH = 24002560;              // [1024][256] ush
static constexpr long U_XCL = 24264704;
static constexpr long U_RSH = 24526848;              // [512][256] ush
static constexpr long U_RSL = 24657920;
static constexpr long U_C3H = 25165824;              // [1024][4096] ush
static constexpr long U_C3L = 29360128;
static constexpr long BASE     = 16777216;
static constexpr long OFF_XCTX = BASE + 0;           // [512][256] f32
static constexpr long OFF_XQRY = BASE + 131072;      // [512][256] f32
static constexpr long OFF_XCAT = BASE + 262144;      // [512][320]
static constexpr long OFF_H1   = BASE + 425984;      // [512][256]
static constexpr long OFF_H2   = BASE + 557056;      // [512][256]
static constexpr long OFF_RS   = BASE + 688128;      // [512][256]
static constexpr long OFF_QA   = BASE + 819200;      // Q planes
static constexpr long U_QH  = (BASE + 819200) * 2;
static constexpr long U_QL  = U_QH + 1048576;
static constexpr long U_WOH = U_QH;                  // wo planes reuse Q planes (dead after k_expq)
static constexpr long U_WOL = U_QL;
static constexpr long OFF_KA   = BASE + 1867776;
static constexpr long U_KH  = (BASE + 1867776) * 2;
static constexpr long U_KL  = U_KH + 1048576;
static constexpr long OFF_VA   = BASE + 2916352;     // [8][512][256] f32
static constexpr long OFF_DQ   = BASE + 3964928;     // Aw1 lives here (1024 ush)
static constexpr long OFF_REPIN= BASE + 3977344;     // EL planes, then REP planes (both transient)
static constexpr long U_ELH = (BASE + 3977344) * 2;
static constexpr long U_ELL = U_ELH + 1048576;
static constexpr long U_REPH = U_ELH;                // [512][2048] ush
static constexpr long U_REPL = U_ELL;
static constexpr long OFF_REP  = BASE + 5025920;     // [512][256]
static constexpr long OFF_XZ   = BASE + 5156992;     // [512][384]
static constexpr long OFF_DH1  = BASE + 5353600;     // [512][100]
static constexpr long OFF_DH2  = BASE + 5404800;     // [512][100]
static constexpr long OFF_AW   = 22233216;           // conv2 A-weights bf16 (13824 ushort)
static constexpr long OFF_AW3  = 22240128;           // conv3 A-weights bf16 (73728 ushort)

__device__ inline unsigned short f2bf(float f) {
    unsigned int x = __float_as_uint(f);
    unsigned int r = x + 0x7fffu + ((x >> 16) & 1u);
    return (unsigned short)(r >> 16);
}
__device__ inline float bf2f(unsigned short h) {
    return __uint_as_float((unsigned int)h << 16);
}

// ============================================================
// fp32 -> bf16 hi/lo planes
// ============================================================
__global__ void k_cvt(const float* __restrict__ s, unsigned short* __restrict__ dh,
                      unsigned short* __restrict__ dl, int n)
{
    int i = blockIdx.x * 256 + threadIdx.x;
    if (i >= n) return;
    float v = s[i];
    unsigned short h = f2bf(v);
    dh[i] = h;
    dl[i] = f2bf(v - bf2f(h));
}
__global__ void k_cvtp(const float* __restrict__ s, unsigned short* __restrict__ dh,
                       unsigned short* __restrict__ dl, int nsrc, int ntot)
{
    int i = blockIdx.x * 256 + threadIdx.x;
    if (i >= ntot) return;
    float v = (i < nsrc) ? s[i] : 0.f;
    unsigned short h = f2bf(v);
    dh[i] = h;
    dl[i] = f2bf(v - bf2f(h));
}
// wq/wk/wv in one dispatch (each 524288 elems; planes stride 1048576 from base)
__global__ void k_cvt3(const float* __restrict__ s0, const float* __restrict__ s1,
                       const float* __restrict__ s2, unsigned short* __restrict__ base)
{
    int i = blockIdx.x * 256 + threadIdx.x;
    if (i >= 524288) return;
    int y = blockIdx.y;
    const float* s = (y == 0) ? s0 : (y == 1) ? s1 : s2;
    float v = s[i];
    unsigned short h = f2bf(v);
    base[(long)y * 1048576 + i] = h;
    base[(long)y * 1048576 + 524288 + i] = f2bf(v - bf2f(h));
}

// ============================================================
// w2 -> Aw [tap][mt 3][m 16][ic 32]; w1 -> Aw1 [mt 2][m 16][k 32] (taps 0..8)
// ============================================================
__global__ void k_wprep(const float* __restrict__ w2, const float* __restrict__ w1,
                        unsigned short* __restrict__ Aw, unsigned short* __restrict__ Aw1)
{
    int i = blockIdx.x * 256 + threadIdx.x;   // 14848 total
    if (i < 13824) {
        int ic  = i & 31;
        int m16 = (i >> 5) & 15;
        int emt = i >> 9;
        int mt  = emt % 3;
        int e   = emt / 3;
        int oc  = mt * 16 + m16;
        Aw[i] = f2bf(w2[(oc * 32 + ic) * 9 + e]);
    } else if (i < 14848) {
        int j = i - 13824;
        int k = j & 31;
        int m = (j >> 5) & 15;
        int mt = j >> 9;   // 0..1
        Aw1[j] = (k < 9) ? f2bf(w1[(mt * 16 + m) * 9 + k]) : (unsigned short)0;
    }
}

// ============================================================
// w3 -> Aw3 [tap 9][mt 4][hl 2][m 16][k 64] bf16 (hi/lo, k>=48 zero)
// ============================================================
__global__ void k_wprep3(const float* __restrict__ w3, unsigned short* __restrict__ Aw3)
{
    int i = blockIdx.x * 256 + threadIdx.x;   // 73728 total
    if (i >= 73728) return;
    int k  = i & 63;
    int m  = (i >> 6) & 15;
    int hl = (i >> 10) & 1;
    int mt = (i >> 11) & 3;
    int e  = i >> 13;
    unsigned short v = 0;
    if (k < 48) {
        int oc = mt * 16 + m;
        float w = w3[(oc * 48 + k) * 9 + e];
        unsigned short hi = f2bf(w);
        v = hl == 0 ? hi : f2bf(w - bf2f(hi));
    }
    Aw3[i] = v;
}

// ============================================================
// Fused conv1 (MFMA via wave-private im2col) -> bf16 ring -> conv2 MFMA
// -> bias/relu/maxpool -> bf16 hi/lo pool [img][pix 256][hi48|lo48]
// ============================================================
__launch_bounds__(256)
__global__ void k_conv12m(const float* __restrict__ train, const float* __restrict__ test,
                          const float* __restrict__ b1,
                          const unsigned short* __restrict__ Aw,
                          const unsigned short* __restrict__ Aw1,
                          const float* __restrict__ b2,
                          unsigned short* __restrict__ pool_out)
{
    const int g   = blockIdx.x;    // 0..7 (conv2 rows 4g..4g+3)
    const int img = blockIdx.y;
    const float* in = (img < 512) ? (train + (long)img * 16384)
                                  : (test  + (long)(img - 512) * 16384);

    __shared__ unsigned short ring[9 * 66 * 40];   // 47520 B
    __shared__ unsigned short s_inp[19 * 132];     // 5016 B (bf16 input rows)
    __shared__ unsigned short Bbuf[64 * 40];       // 5120 B (im2col, k 9..31 stay 0)
    float* scratch = (float*)ring;                 // epilogue alias

    const int t = threadIdx.x;

    // zero pad column c=0 of every ring slot; zero Bbuf (k>=9 must be 0)
    for (int i = t; i < 9 * 40; i += 256) {
        int sl = i / 40, icp = i % 40;
        ring[(sl * 66 + 0) * 40 + icp] = 0;
    }
    for (int i = t; i < 1280; i += 256) ((unsigned int*)Bbuf)[i] = 0u;
    if (g == 0)
        for (int i = t; i < 66 * 40; i += 256) ring[i] = 0;

    // ---- stage 19 input rows as bf16 ----
    const int rlo = 16 * g - 3;
    for (int q = t; q < 608; q += 256) {
        int rr = q >> 5;
        int cq = (q & 31) * 4;
        int r = rlo + rr;
        float4 f = (r >= 0) ? *(const float4*)&in[r * 128 + cq] : make_float4(0.f, 0.f, 0.f, 0.f);
        unsigned short o[4] = { f2bf(f.x), f2bf(f.y), f2bf(f.z), f2bf(f.w) };
        *(uint2*)&s_inp[rr * 132 + cq] = *(const uint2*)o;
    }
    __syncthreads();

    const int w    = t >> 6;
    const int lane = t & 63;
    const int cn   = lane & 15;
    const int quad = lane >> 4;

    // conv1 A-frags + per-lane biases
    short8 a1f0 = *(const short8*)&Aw1[(0 * 16 + cn) * 32 + quad * 8];
    short8 a1f1 = *(const short8*)&Aw1[(16 + cn) * 32 + quad * 8];
    float bs[8];
    #pragma unroll
    for (int r = 0; r < 4; r++) { bs[r] = b1[quad * 4 + r]; bs[4 + r] = b1[16 + quad * 4 + r]; }

    // ---- conv1 rows via MFMA (wave-private im2col; no barriers in loop) ----
    for (int sl = (g == 0 ? 1 : 0); sl < 9; sl++) {
        if (lane < 16) {
            const int px = w * 16 + cn;
            unsigned short o[9];
            #pragma unroll
            for (int dy = 0; dy < 3; dy++) {
                const int ib = (2 * sl + dy) * 132;
                #pragma unroll
                for (int dx = 0; dx < 3; dx++) {
                    int xx = 2 * px - 1 + dx;
                    o[dy * 3 + dx] = (xx >= 0) ? s_inp[ib + xx] : (unsigned short)0;
                }
            }
            *(uint4*)&Bbuf[px * 40] = *(const uint4*)o;
            Bbuf[px * 40 + 8] = o[8];
        }
        const int px2 = w * 16 + cn;
        short8 bfr = *(const short8*)&Bbuf[px2 * 40 + quad * 8];
        f32x4 z = (f32x4){0.f, 0.f, 0.f, 0.f};
        f32x4 c0 = __builtin_amdgcn_mfma_f32_16x16x32_bf16(a1f0, bfr, z, 0, 0, 0);
        f32x4 c1 = __builtin_amdgcn_mfma_f32_16x16x32_bf16(a1f1, bfr, z, 0, 0, 0);
        unsigned short p0[4], p1[4];
        #pragma unroll
        for (int r = 0; r < 4; r++) {
            p0[r] = f2bf(fmaxf(c0[r] + bs[r], 0.f));
            p1[r] = f2bf(fmaxf(c1[r] + bs[4 + r], 0.f));
        }
        *(uint2*)&ring[(sl * 66 + px2 + 1) * 40 + quad * 4]      = *(const uint2*)p0;
        *(uint2*)&ring[(sl * 66 + px2 + 1) * 40 + 16 + quad * 4] = *(const uint2*)p1;
    }
    __syncthreads();

    // ---- conv2 MFMA phase ----
    f32x4 acc[3][2];
    #pragma unroll
    for (int mt = 0; mt < 3; mt++)
        #pragma unroll
        for (int xh = 0; xh < 2; xh++) acc[mt][xh] = (f32x4){0.f, 0.f, 0.f, 0.f};

    for (int e = 0; e < 9; e++) {
        int dy = e / 3, dx = e - 3 * dy;
        short8 a0 = *(const short8*)&Aw[((e * 3 + 0) * 16 + cn) * 32 + quad * 8];
        short8 a1 = *(const short8*)&Aw[((e * 3 + 1) * 16 + cn) * 32 + quad * 8];
        short8 a2 = *(const short8*)&Aw[((e * 3 + 2) * 16 + cn) * 32 + quad * 8];
        int sl = 2 * w + dy;
        #pragma unroll
        for (int xh = 0; xh < 2; xh++) {
            int c = 2 * (xh * 16 + cn) + dx;
            short8 bfr = *(const short8*)&ring[(sl * 66 + c) * 40 + quad * 8];
            acc[0][xh] = __builtin_amdgcn_mfma_f32_16x16x32_bf16(a0, bfr, acc[0][xh], 0, 0, 0);
            acc[1][xh] = __builtin_amdgcn_mfma_f32_16x16x32_bf16(a1, bfr, acc[1][xh], 0, 0, 0);
            acc[2][xh] = __builtin_amdgcn_mfma_f32_16x16x32_bf16(a2, bfr, acc[2][xh], 0, 0, 0);
        }
    }
    __syncthreads();   // ring reads done before scratch overwrite

    #pragma unroll
    for (int mt = 0; mt < 3; mt++) {
        #pragma unroll
        for (int reg = 0; reg < 4; reg++) {
            int oc = mt * 16 + quad * 4 + reg;
            float bias = b2[oc];
            #pragma unroll
            for (int xh = 0; xh < 2; xh++) {
                int x = xh * 16 + cn;
                scratch[(w * 32 + x) * 52 + oc] = fmaxf(acc[mt][xh][reg] + bias, 0.f);
            }
        }
    }
    __syncthreads();

    for (int i = t; i < 1536; i += 256) {
        int oc = i % 48; int pp = i / 48; int px = pp & 15, pr = pp >> 4;
        const float* b0 = &scratch[((2 * pr) * 32 + 2 * px) * 52 + oc];
        float m = fmaxf(fmaxf(b0[0], b0[52]), fmaxf(b0[32 * 52], b0[33 * 52]));
        unsigned short hi = f2bf(m);
        unsigned short lo = f2bf(m - bf2f(hi));
        long base = ((long)img * 256 + (2 * g + pr) * 16 + px) * 96;
        pool_out[base + oc] = hi;
        pool_out[base + 48 + oc] = lo;
    }
}

// ============================================================
// conv3 via MFMA hi/lo; output -> bf16 hi/lo planes [1024][4096]
// ============================================================
#define C3PITCH 104
__launch_bounds__(512)
__global__ void k_conv3m(const unsigned short* __restrict__ pool,
                         const unsigned short* __restrict__ Aw3,
                         const float* __restrict__ b3,
                         unsigned short* __restrict__ C3h, unsigned short* __restrict__ C3l)
{
    const int img = blockIdx.x;
    __shared__ unsigned short s_in[30120];
    const int t = threadIdx.x;

    uint4* s4 = (uint4*)s_in;
    const uint4 zz = make_uint4(0, 0, 0, 0);
    for (int i = t; i < 3765; i += 512) s4[i] = zz;
    __syncthreads();
    {
        int p = t >> 1, half = t & 1;
        const uint4* src = (const uint4*)(pool + ((long)img * 256 + p) * 96 + half * 48);
        int r = p >> 4, c = p & 15;
        uint4* dst = (uint4*)(s_in + ((r + 1) * 17 + (c + 1)) * C3PITCH + half * 48);
        #pragma unroll
        for (int j = 0; j < 6; j++) dst[j] = src[j];
    }
    __syncthreads();

    const int w = t >> 6, lane = t & 63;
    const int n = lane & 15, quad = lane >> 4;
    const int mt = w >> 1, ntb = (w & 1) * 2;

    f32x4 acc[2];
    acc[0] = (f32x4){0.f, 0.f, 0.f, 0.f};
    acc[1] = (f32x4){0.f, 0.f, 0.f, 0.f};

    for (int e = 0; e < 9; e++) {
        int dy = e / 3, dx = e - 3 * dy;
        const unsigned short* A0 = Aw3 + (long)(((e * 4 + mt) * 2 + 0) * 16 + n) * 64 + quad * 8;
        const unsigned short* A1 = Aw3 + (long)(((e * 4 + mt) * 2 + 1) * 16 + n) * 64 + quad * 8;
        short8 ah0 = *(const short8*)(A0);
        short8 ah1 = *(const short8*)(A0 + 32);
        short8 al0 = *(const short8*)(A1);
        short8 al1 = *(const short8*)(A1 + 32);
        #pragma unroll
        for (int j = 0; j < 2; j++) {
            int p = (ntb + j) * 16 + n;
            int y = p >> 3, x = p & 7;
            int row = 2 * y + dy;
            int colc = 2 * x + dx;
            const unsigned short* Bp = s_in + (row * 17 + colc) * C3PITCH + quad * 8;
            short8 bh0 = *(const short8*)(Bp);
            short8 bh1 = *(const short8*)(Bp + 32);
            short8 bl0 = *(const short8*)(Bp + 48);
            short8 bl1 = *(const short8*)(Bp + 48 + 32);
            acc[j] = __builtin_amdgcn_mfma_f32_16x16x32_bf16(ah0, bh0, acc[j], 0, 0, 0);
            acc[j] = __builtin_amdgcn_mfma_f32_16x16x32_bf16(ah1, bh1, acc[j], 0, 0, 0);
            acc[j] = __builtin_amdgcn_mfma_f32_16x16x32_bf16(ah0, bl0, acc[j], 0, 0, 0);
            acc[j] = __builtin_amdgcn_mfma_f32_16x16x32_bf16(ah1, bl1, acc[j], 0, 0, 0);
            acc[j] = __builtin_amdgcn_mfma_f32_16x16x32_bf16(al0, bh0, acc[j], 0, 0, 0);
            acc[j] = __builtin_amdgcn_mfma_f32_16x16x32_bf16(al1, bh1, acc[j], 0, 0, 0);
        }
    }

    unsigned short* oh = C3h + (long)img * 4096;
    unsigned short* ol = C3l + (long)img * 4096;
    #pragma unroll
    for (int reg = 0; reg < 4; reg++) {
        int oc = mt * 16 + quad * 4 + reg;
        float bias = b3[oc];
        #pragma unroll
        for (int j = 0; j < 2; j++) {
            int p = (ntb + j) * 16 + n;
            float v = fmaxf(acc[j][reg] + bias, 0.f);
            unsigned short h = f2bf(v);
            oh[oc * 64 + p] = h;
            ol[oc * 64 + p] = f2bf(v - bf2f(h));
        }
    }
}

// ============================================================
// bf16 hi/lo MFMA GEMM (3-term, ~fp32). OUTMODE 0: f32 (z-batch);
// 1: hi/lo planes (z-batch); 2: f32 split-K atomic (z = k-chunk).
// ============================================================
template<int OUTMODE>
__launch_bounds__(256)
__global__ void mgemm(const unsigned short* __restrict__ Xh, const unsigned short* __restrict__ Xl,
                      const unsigned short* __restrict__ Wph, const unsigned short* __restrict__ Wpl,
                      const float* __restrict__ Bb, float* __restrict__ Yf,
                      unsigned short* __restrict__ Yh, unsigned short* __restrict__ Yl,
                      int M, int N, int K, int ldY, float scale,
                      long sW, long sB, long sY, int kChunk)
{
    const int z = blockIdx.z;
    const unsigned short* Wh = Wph + (OUTMODE == 2 ? 0 : (long)z * sW);
    const unsigned short* Wl = Wpl + (OUTMODE == 2 ? 0 : (long)z * sW);
    const float* B = Bb ? (Bb + (OUTMODE == 2 ? 0 : (long)z * sB)) : nullptr;
    int k0 = 0, k1 = K;
    if (OUTMODE == 2) { k0 = z * kChunk; k1 = min(K, k0 + kChunk); }

    __shared__ unsigned short sAh[64 * 40], sAl[64 * 40], sBh[64 * 40], sBl[64 * 40];

    const int t = threadIdx.x;
    const int m0 = blockIdx.y * 64, n0 = blockIdx.x * 64;
    const int r = t >> 2, kq = (t & 3) * 8;

    const int w = t >> 6, lane = t & 63;
    const int wm = (w & 1) * 32, wn = (w >> 1) * 32;
    const int cn = lane & 15, quad = lane >> 4;

    f32x4 acc[2][2];
    acc[0][0] = acc[0][1] = acc[1][0] = acc[1][1] = (f32x4){0.f, 0.f, 0.f, 0.f};

    for (int kb = k0; kb < k1; kb += 32) {
        *(uint4*)&sAh[r * 40 + kq] = *(const uint4*)&Xh[(long)(m0 + r) * K + kb + kq];
        *(uint4*)&sAl[r * 40 + kq] = *(const uint4*)&Xl[(long)(m0 + r) * K + kb + kq];
        *(uint4*)&sBh[r * 40 + kq] = *(const uint4*)&Wh[(long)(n0 + r) * K + kb + kq];
        *(uint4*)&sBl[r * 40 + kq] = *(const uint4*)&Wl[(long)(n0 + r) * K + kb + kq];
        __syncthreads();
        short8 axh[2], axl[2], bxh[2], bxl[2];
        #pragma unroll
        for (int i = 0; i < 2; i++) {
            axh[i] = *(const short8*)&sAh[(wm + i * 16 + cn) * 40 + quad * 8];
            axl[i] = *(const short8*)&sAl[(wm + i * 16 + cn) * 40 + quad * 8];
            bxh[i] = *(const short8*)&sBh[(wn + i * 16 + cn) * 40 + quad * 8];
            bxl[i] = *(const short8*)&sBl[(wn + i * 16 + cn) * 40 + quad * 8];
        }
        #pragma unroll
        for (int i = 0; i < 2; i++)
            #pragma unroll
            for (int j = 0; j < 2; j++) {
                acc[i][j] = __builtin_amdgcn_mfma_f32_16x16x32_bf16(axh[i], bxh[j], acc[i][j], 0, 0, 0);
                acc[i][j] = __builtin_amdgcn_mfma_f32_16x16x32_bf16(axh[i], bxl[j], acc[i][j], 0, 0, 0);
                acc[i][j] = __builtin_amdgcn_mfma_f32_16x16x32_bf16(axl[i], bxh[j], acc[i][j], 0, 0, 0);
            }
        __syncthreads();
    }

    #pragma unroll
    for (int i = 0; i < 2; i++) {
        #pragma unroll
        for (int reg = 0; reg < 4; reg++) {
            int row = m0 + wm + i * 16 + quad * 4 + reg;
            #pragma unroll
            for (int j = 0; j < 2; j++) {
                int col = n0 + wn + j * 16 + cn;
                if (col >= N) continue;
                float v = acc[i][j][reg] * scale;
                if (OUTMODE == 2) {
                    if (z == 0 && B) v += B[col];
                    atomicAdd(&Yf[(long)row * ldY + col], v);
                } else if (OUTMODE == 0) {
                    if (B) v += B[col];
                    (Yf + (long)z * sY)[(long)row * ldY + col] = v;
                } else {
                    if (B) v += B[col];
                    unsigned short h = f2bf(v);
                    (Yh + (long)z * sY)[(long)row * ldY + col] = h;
                    (Yl + (long)z * sY)[(long)row * ldY + col] = f2bf(v - bf2f(h));
                }
            }
        }
    }
}

// ============================================================
// Generic fp32 GEMM (small layers)
// ============================================================
template<int BM, int BN, int BK, int TM, int TN, int ACT, bool SPLITK>
__launch_bounds__(256)
__global__ void gemm_k(const float* __restrict__ Xb, const float* __restrict__ Wb,
                       const float* __restrict__ Bb, float* __restrict__ Yb,
                       int M, int N, int K, int ldY, float scale,
                       long sX, long sW, long sB, long sY, int kChunk)
{
    const int z = blockIdx.z;
    const float* X = Xb + (SPLITK ? 0 : (long)z * sX);
    const float* W = Wb + (SPLITK ? 0 : (long)z * sW);
    const float* B = Bb ? (Bb + (SPLITK ? 0 : (long)z * sB)) : nullptr;
    float* Y = Yb + (SPLITK ? 0 : (long)z * sY);
    int k0 = 0, k1 = K;
    if (SPLITK) { k0 = z * kChunk; k1 = min(K, k0 + kChunk); }

    __shared__ float As[BK][BM + 4];
    __shared__ float Bs[BK][BN + 4];
    const int t = threadIdx.x;
    const int tx = t & 15, ty = t >> 4;
    const int m0 = blockIdx.y * BM, n0 = blockIdx.x * BN;
    float acc[TM][TN];
    #pragma unroll
    for (int i = 0; i < TM; i++)
        #pragma unroll
        for (int j = 0; j < TN; j++) acc[i][j] = 0.f;

    for (int kb = k0; kb < k1; kb += BK) {
        for (int i = t; i < BM * BK; i += 256) {
            int rr = i / BK, c = i % BK;
            int mm = m0 + rr, kk = kb + c;
            As[c][rr] = (mm < M && kk < k1) ? X[(long)mm * K + kk] : 0.f;
        }
        for (int i = t; i < BN * BK; i += 256) {
            int rr = i / BK, c = i % BK;
            int nn = n0 + rr, kk = kb + c;
            Bs[c][rr] = (nn < N && kk < k1) ? W[(long)nn * K + kk] : 0.f;
        }
        __syncthreads();
        #pragma unroll
        for (int kk = 0; kk < BK; kk++) {
            float a[TM], b[TN];
            #pragma unroll
            for (int i = 0; i < TM; i++) a[i] = As[kk][ty * TM + i];
            #pragma unroll
            for (int j = 0; j < TN; j++) b[j] = Bs[kk][tx * TN + j];
            #pragma unroll
            for (int i = 0; i < TM; i++)
                #pragma unroll
                for (int j = 0; j < TN; j++) acc[i][j] += a[i] * b[j];
        }
        __syncthreads();
    }

    #pragma unroll
    for (int i = 0; i < TM; i++) {
        int mm = m0 + ty * TM + i;
        if (mm >= M) continue;
        #pragma unroll
        for (int j = 0; j < TN; j++) {
            int nn = n0 + tx * TN + j;
            if (nn >= N) continue;
            float v = acc[i][j] * scale;
            if (SPLITK) {
                if (z == 0 && B) v += B[nn];
                atomicAdd(&Y[(long)mm * ldY + nn], v);
            } else {
                if (B) v += B[nn];
                if (ACT == 1) v = fmaxf(v, 0.f);
                if (ACT == 2) v = tanhf(v);
                Y[(long)mm * ldY + nn] = v;
            }
        }
    }
}

// ============================================================
__global__ void k_xcat(const float* __restrict__ x_ctx, const float* __restrict__ label,
                       const float* __restrict__ tyw, const float* __restrict__ tyb,
                       float* __restrict__ xcat)
{
    int idx = blockIdx.x * 256 + threadIdx.x;
    if (idx >= 512 * 320) return;
    int r = idx / 320, c = idx % 320;
    float v;
    if (c < 256) v = x_ctx[r * 256 + c];
    else {
        int e = c - 256;
        v = tyb[e] + label[r * 2] * tyw[e * 2] + label[r * 2 + 1] * tyw[e * 2 + 1];
    }
    xcat[idx] = v;
}

// ============================================================
// Fused diag + per-row max + exp for queries. One block per token.
// ============================================================
__launch_bounds__(256)
__global__ void k_expq(float* __restrict__ xd, const unsigned short* __restrict__ Qh,
                       const unsigned short* __restrict__ Ql)
{
    const int tok = blockIdx.x;
    const int t = threadIdx.x;
    __shared__ float red[8];
    float v = bf2f(Qh[(long)tok * 256 + t]) + bf2f(Ql[(long)tok * 256 + t]);
    float s = v * v;
    for (int d = 1; d < 64; d <<= 1) s += __shfl_xor(s, d);
    if ((t & 63) == 0) red[t >> 6] = s;
    __syncthreads();
    float diag = (red[0] + red[1] + red[2] + red[3]) * (1.f / 32.f);

    float vals[6];
    float m = -1e30f;
    #pragma unroll
    for (int j = 0; j < 6; j++) {
        int f = t + j * 256;
        if (f < F_FEAT) { vals[j] = xd[(long)tok * F_FEAT + f]; m = fmaxf(m, vals[j]); }
    }
    for (int d = 1; d < 64; d <<= 1) m = fmaxf(m, __shfl_xor(m, d));
    if ((t & 63) == 0) red[4 + (t >> 6)] = m;
    __syncthreads();
    m = fmaxf(fmaxf(red[4], red[5]), fmaxf(red[6], red[7]));
    #pragma unroll
    for (int j = 0; j < 6; j++) {
        int f = t + j * 256;
        if (f < F_FEAT) xd[(long)tok * F_FEAT + f] = RATIO * (expf(vals[j] - diag - m) + 1e-4f);
    }
}

// ============================================================
// Fused diag + block max + exp for keys. One block per (h,t) = 32 tokens.
// ============================================================
__launch_bounds__(256)
__global__ void k_expk(float* __restrict__ xd, const unsigned short* __restrict__ Kh,
                       const unsigned short* __restrict__ Kl)
{
    const int b = blockIdx.x;       // 0..127
    const int t = threadIdx.x;
    __shared__ float s_dk[32];
    __shared__ float red[4];
    const int row = t >> 3, j = t & 7;
    const long tok0 = (long)b * 32;

    float s = 0.f;
    const unsigned short* ph = Kh + (tok0 + row) * 256 + j * 32;
    const unsigned short* pl = Kl + (tok0 + row) * 256 + j * 32;
    for (int q = 0; q < 32; q++) { float v = bf2f(ph[q]) + bf2f(pl[q]); s += v * v; }
    s += __shfl_xor(s, 1); s += __shfl_xor(s, 2); s += __shfl_xor(s, 4);
    if (j == 0) s_dk[row] = s * (1.f / 32.f);

    float* base = xd + tok0 * F_FEAT;
    float m = -1e30f;
    for (int i = t; i < 32 * F_FEAT; i += 256) m = fmaxf(m, base[i]);
    for (int d = 1; d < 64; d <<= 1) m = fmaxf(m, __shfl_xor(m, d));
    if ((t & 63) == 0) red[t >> 6] = m;
    __syncthreads();
    m = fmaxf(fmaxf(red[0], red[1]), fmaxf(red[2], red[3]));

    for (int r = 0; r < 32; r++) {
        float dg = s_dk[r];
        float* rp = base + (long)r * F_FEAT;
        for (int f = t; f < F_FEAT; f += 256) rp[f] = RATIO * (expf(rp[f] - dg - m) + 1e-4f);
    }
}

// ============================================================
// Attention core -> hi/lo planes of rep_in (permuted concat)
// ============================================================
__launch_bounds__(256)
__global__ void k_attn(const float* __restrict__ qp, const float* __restrict__ kp,
                       const float* __restrict__ va,
                       unsigned short* __restrict__ REPh, unsigned short* __restrict__ REPl)
{
    const int tt = blockIdx.x;
    const int h  = blockIdx.y;
    const long row0 = ((long)h * 16 + tt) * 32;

    __shared__ float s_q[32][68];
    __shared__ float s_k[32][68];
    __shared__ float s_A[32][33];
    __shared__ float s_di[32];
    __shared__ float s_v[32 * 256];

    const int t = threadIdx.x;
    const int n = t >> 3;
    const int mq = (t & 7) * 4;

    float acc[4] = {0, 0, 0, 0};
    for (int fc = 0; fc < F_FEAT; fc += 64) {
        for (int i = t; i < 2048; i += 256) {
            int rr = i >> 6, ff = i & 63;
            int fg = fc + ff;
            s_q[rr][ff] = (fg < F_FEAT) ? qp[(row0 + rr) * F_FEAT + fg] : 0.f;
            s_k[rr][ff] = (fg < F_FEAT) ? kp[(row0 + rr) * F_FEAT + fg] : 0.f;
        }
        __syncthreads();
        #pragma unroll 8
        for (int ff = 0; ff < 64; ff++) {
            float a = s_q[n][ff];
            #pragma unroll
            for (int j = 0; j < 4; j++) acc[j] += a * s_k[mq + j][ff];
        }
        __syncthreads();
    }

    float rsum = acc[0] + acc[1] + acc[2] + acc[3];
    rsum += __shfl_xor(rsum, 1);
    rsum += __shfl_xor(rsum, 2);
    rsum += __shfl_xor(rsum, 4);
    #pragma unroll
    for (int j = 0; j < 4; j++) s_A[n][mq + j] = acc[j];
    if ((t & 7) == 0) s_di[n] = 1.f / rsum;
    for (int i = t; i < 8192; i += 256) s_v[i] = va[row0 * 256 + i];
    __syncthreads();

    const int e0 = t & 7;
    float out[32];
    #pragma unroll
    for (int j = 0; j < 32; j++) out[j] = 0.f;
    for (int m = 0; m < 32; m++) {
        float a = s_A[n][m];
        #pragma unroll
        for (int j = 0; j < 32; j++) out[j] += a * s_v[m * 256 + e0 + 8 * j];
    }
    float di = s_di[n];
    unsigned short* dsth = REPh + ((long)tt * 32 + n) * 2048;
    unsigned short* dstl = REPl + ((long)tt * 32 + n) * 2048;
    #pragma unroll
    for (int j = 0; j < 32; j++) {
        int e = e0 + 8 * j;
        float val = out[j] * di;
        unsigned short hh = f2bf(val);
        dsth[e * 8 + h] = hh;
        dstl[e * 8 + h] = f2bf(val - bf2f(hh));
    }
}

__global__ void k_xzcopy(const float* __restrict__ xq, float* __restrict__ xz)
{
    int idx = blockIdx.x * 256 + threadIdx.x;
    if (idx >= 512 * 256) return;
    int r = idx >> 8, c = idx & 255;
    xz[r * 384 + c] = xq[idx];
}

__global__ void k_fin(float* __restrict__ out) { if (threadIdx.x == 0) out[1024] = 0.f; }

// ============================================================
extern "C" void kernel_launch(void* const* d_in, const int* in_sizes, int n_in,
                              void* d_out, int out_size, void* d_ws, size_t ws_size,
                              hipStream_t stream)
{
    const float* train  = (const float*)d_in[0];
    const float* label  = (const float*)d_in[1];
    const float* test   = (const float*)d_in[2];
    const float* c1w = (const float*)d_in[3];  const float* c1b = (const float*)d_in[4];
    const float* c2w = (const float*)d_in[5];  const float* c2b = (const float*)d_in[6];
    const float* c3w = (const float*)d_in[7];  const float* c3b = (const float*)d_in[8];
    const float* elw = (const float*)d_in[9];  const float* elb = (const float*)d_in[10];
    const float* tyw = (const float*)d_in[11]; const float* tyb = (const float*)d_in[12];
    const float* ew1 = (const float*)d_in[13]; const float* eb1 = (const float*)d_in[14];
    const float* ew2 = (const float*)d_in[15]; const float* eb2 = (const float*)d_in[16];
    const float* ew3 = (const float*)d_in[17]; const float* eb3 = (const float*)d_in[18];
    const float* wq  = (const float*)d_in[19]; const float* wqb = (const float*)d_in[20];
    const float* wk  = (const float*)d_in[21]; const float* wkb = (const float*)d_in[22];
    const float* wv  = (const float*)d_in[23]; const float* wvb = (const float*)d_in[24];
    const float* wow = (const float*)d_in[25]; const float* wob = (const float*)d_in[26];
    const float* rzw = (const float*)d_in[27]; const float* rzb = (const float*)d_in[28];
    const float* dw1 = (const float*)d_in[29]; const float* db1 = (const float*)d_in[30];
    const float* dw2 = (const float*)d_in[31]; const float* db2 = (const float*)d_in[32];
    const float* dw3 = (const float*)d_in[33]; const float* db3 = (const float*)d_in[34];
    const float* proj= (const float*)d_in[35];

    float* wsf = (float*)d_ws;
    unsigned short* usw = (unsigned short*)d_ws;
    float* out = (float*)d_out;

    unsigned short* A_pool = usw;
    float* x_ctx  = wsf + OFF_XCTX;
    float* x_qry  = wsf + OFF_XQRY;
    float* xcat   = wsf + OFF_XCAT;
    float* h1     = wsf + OFF_H1;
    float* h2     = wsf + OFF_H2;
    float* rs     = wsf + OFF_RS;
    float* v_all  = wsf + OFF_VA;
    float* rep    = wsf + OFF_REP;
    float* xz     = wsf + OFF_XZ;
    float* dh1    = wsf + OFF_DH1;
    float* dh2    = wsf + OFF_DH2;
    float* xd_q   = wsf + OFF_XDQ;
    float* xd_k   = wsf + OFF_XDK;
    unsigned short* Aw  = (unsigned short*)(wsf + OFF_AW);
    unsigned short* Aw3 = (unsigned short*)(wsf + OFF_AW3);
    unsigned short* Aw1 = (unsigned short*)(wsf + OFF_DQ);

    unsigned short* WQVbase = usw + U_WQH;           // wq/wk/wv planes base
    unsigned short* WVh = usw + U_WVH; unsigned short* WVl = usw + U_WVL;
    unsigned short* WQh = usw + U_WQH; unsigned short* WQl = usw + U_WQL;
    unsigned short* WKh = usw + U_WKH; unsigned short* WKl = usw + U_WKL;
    unsigned short* Ph  = usw + U_PH;  unsigned short* Pl  = usw + U_PL;
    unsigned short* XCh = usw + U_XCH; unsigned short* XCl = usw + U_XCL;
    unsigned short* RSh = usw + U_RSH; unsigned short* RSl = usw + U_RSL;
    unsigned short* C3h = usw + U_C3H; unsigned short* C3l = usw + U_C3L;
    unsigned short* Qh  = usw + U_QH;  unsigned short* Ql  = usw + U_QL;
    unsigned short* Kh  = usw + U_KH;  unsigned short* Kl  = usw + U_KL;
    unsigned short* ELh = usw + U_ELH; unsigned short* ELl = usw + U_ELL;
    unsigned short* WOh = usw + U_WOH; unsigned short* WOl = usw + U_WOL;
    unsigned short* REPh= usw + U_REPH;unsigned short* REPl= usw + U_REPL;

    // ---- weight preps ----
    k_wprep<<<58, 256, 0, stream>>>(c2w, c1w, Aw, Aw1);
    k_wprep3<<<288, 256, 0, stream>>>(c3w, Aw3);
    k_cvt<<<4096, 256, 0, stream>>>(elw, ELh, ELl, 1048576);

    // ---- encoder convs ----
    k_conv12m<<<dim3(8, 1024), 256, 0, stream>>>(train, test, c1b, Aw, Aw1, c2b, A_pool);
    k_conv3m<<<1024, 512, 0, stream>>>(A_pool, Aw3, c3b, C3h, C3l);

    // ---- plane preps reusing the dead pool region ----
    k_cvtp<<<1472, 256, 0, stream>>>(proj, Ph, Pl, 363264, 376832);
    k_cvt3<<<dim3(2048, 3), 256, 0, stream>>>(wq, wk, wv, WQVbase);

    // ---- enc linear (split-K=4) ----
    hipMemsetAsync(x_ctx, 0, 1024 * 256 * sizeof(float), stream);
    mgemm<2><<<dim3(4, 16, 4), 256, 0, stream>>>(
        C3h, C3l, ELh, ELl, elb, x_ctx, nullptr, nullptr,
        1024, 256, 4096, 256, 1.f, 0, 0, 0, 1024);
    k_cvt<<<1024, 256, 0, stream>>>(x_ctx, XCh, XCl, 262144);

    // ---- xcat + er MLP -> rs ----
    k_xcat<<<640, 256, 0, stream>>>(x_ctx, label, tyw, tyb, xcat);
    gemm_k<32,32,32,2,2,1,false><<<dim3(8, 16, 1), 256, 0, stream>>>(
        xcat, ew1, eb1, h1, 512, 256, 320, 256, 1.f, 0, 0, 0, 0, 0);
    gemm_k<32,32,32,2,2,1,false><<<dim3(8, 16, 1), 256, 0, stream>>>(
        h1, ew2, eb2, h2, 512, 256, 256, 256, 1.f, 0, 0, 0, 0, 0);
    gemm_k<32,32,32,2,2,0,false><<<dim3(8, 16, 1), 256, 0, stream>>>(
        h2, ew3, eb3, rs, 512, 256, 256, 256, 1.f, 0, 0, 0, 0, 0);
    k_cvt<<<512, 256, 0, stream>>>(rs, RSh, RSl, 131072);

    // ---- q/k/v projections (z = 8 heads) ----
    mgemm<1><<<dim3(4, 8, 8), 256, 0, stream>>>(
        XCh + 512 * 256, XCl + 512 * 256, WQh, WQl, wqb, nullptr, Qh, Ql,
        512, 256, 256, 256, 1.f, 65536, 256, 131072, 0);
    mgemm<1><<<dim3(4, 8, 8), 256, 0, stream>>>(
        XCh, XCl, WKh, WKl, wkb, nullptr, Kh, Kl,
        512, 256, 256, 256, 1.f, 65536, 256, 131072, 0);
    mgemm<0><<<dim3(4, 8, 8), 256, 0, stream>>>(
        RSh, RSl, WVh, WVl, wvb, v_all, nullptr, nullptr,
        512, 256, 256, 256, 1.f, 65536, 256, 131072, 0);

    // ---- performer features ----
    mgemm<0><<<dim3(23, 64, 1), 256, 0, stream>>>(
        Qh, Ql, Ph, Pl, nullptr, xd_q, nullptr, nullptr,
        4096, F_FEAT, 256, F_FEAT, DN, 0, 0, 0, 0);
    mgemm<0><<<dim3(23, 64, 1), 256, 0, stream>>>(
        Kh, Kl, Ph, Pl, nullptr, xd_k, nullptr, nullptr,
        4096, F_FEAT, 256, F_FEAT, DN, 0, 0, 0, 0);

    // ---- fused diag+max+exp ----
    k_expq<<<4096, 256, 0, stream>>>(xd_q, Qh, Ql);
    k_expk<<<128, 256, 0, stream>>>(xd_k, Kh, Kl);

    // wo planes into (now dead) Q-plane space
    k_cvt<<<2048, 256, 0, stream>>>(wow, WOh, WOl, 524288);

    // ---- attention -> REP planes ----
    k_attn<<<dim3(16, 8), 256, 0, stream>>>(xd_q, xd_k, v_all, REPh, REPl);

    // ---- rep = rep_in @ wo^T + b (mgemm split-K=4) ----
    hipMemsetAsync(rep, 0, 512 * 256 * sizeof(float), stream);
    mgemm<2><<<dim3(4, 8, 4), 256, 0, stream>>>(
        REPh, REPl, WOh, WOl, wob, rep, nullptr, nullptr,
        512, 256, 2048, 256, 1.f, 0, 0, 0, 512);

    // ---- xz = [x_qry | rep @ rz^T + b] ----
    k_xzcopy<<<512, 256, 0, stream>>>(x_qry, xz);
    gemm_k<32,32,32,2,2,0,false><<<dim3(4, 16, 1), 256, 0, stream>>>(
        rep, rzw, rzb, xz + 256, 512, 128, 256, 384, 1.f, 0, 0, 0, 0, 0);

    // ---- decoder ----
    gemm_k<32,32,32,2,2,1,false><<<dim3(4, 16, 1), 256, 0, stream>>>(
        xz, dw1, db1, dh1, 512, 100, 384, 100, 1.f, 0, 0, 0, 0, 0);
    gemm_k<32,32,32,2,2,1,false><<<dim3(4, 16, 1), 256, 0, stream>>>(
        dh1, dw2, db2, dh2, 512, 100, 100, 100, 1.f, 0, 0, 0, 0, 0);
    gemm_k<32,32,32,2,2,2,false><<<dim3(1, 16, 1), 256, 0, stream>>>(
        dh2, dw3, db3, out, 512, 2, 100, 2, 1.f, 0, 0, 0, 0, 0);

    k_fin<<<1, 64, 0, stream>>>(out);
}

// Round 8
// 845.799 us; speedup vs baseline: 5.0617x; 1.0280x over previous
//
#include <hip/hip_runtime.h>
#include <math.h>

// ---------------- problem constants ----------------
// T=16, NC=NQ=32, DW=256, DR=256, DZ=128, NH=8, F=1419
#define F_FEAT 1419
static constexpr float RATIO = 0.026546563287556634f; // 1419^-0.5
static constexpr float DN    = 0.25f;                 // 256^-0.25

typedef short short8 __attribute__((ext_vector_type(8)));
typedef float f32x4  __attribute__((ext_vector_type(4)));

// ---------------- workspace layout ----------------
// floats offsets unless noted "ush"
static constexpr long OFF_XDQ  = 0;                  // [4096][1419] f32 (performer phase)
static constexpr long OFF_XDK  = 5812224;            // [4096][1419] f32
static constexpr long U_WQH = 0;                     // W planes ush — POOL REGION: write only AFTER conv3m
static constexpr long U_WQL = 524288;
static constexpr long U_WKH = 1048576;
static constexpr long U_WKL = 1572864;
static constexpr long U_WVH = 2097152;
static constexpr long U_WVL = 2621440;               // ends ush 3,145,728
static constexpr long OFF_ENCT = 4000000;            // enc split-K temp: 8 x 262144 f32 (pool dead by then)
static constexpr long OFF_REPT = 6200000;            // rep split-K temp: 4 x 131072 f32 (xd dead by then)
static constexpr long U_PH  = 23248896;              // [1472][256] ush — POOL REGION: after conv3m
static constexpr long U_PL  = 23625728;
static constexpr long U_XCH = 24002560;              // [1024][256] ush — pool region, written step 5
static constexpr long U_XCL = 24264704;
static constexpr long U_RSH = 24526848;              // [512][256] ush
static constexpr long U_RSL = 24657920;
static constexpr long U_C3H = 25165824;              // [1024][4096] ush (starts at pool end)
static constexpr long U_C3L = 29360128;
static constexpr long U_WOH = 25165824;              // wo planes reuse C3 region after enc GEMM
static constexpr long U_WOL = 25690112;
static constexpr long BASE     = 16777216;
static constexpr long OFF_XCTX = BASE + 0;           // [1024][256] f32 (ctx rows 0..511, qry 512..1023)
static constexpr long OFF_XQRY = BASE + 131072;
static constexpr long OFF_XCAT = BASE + 262144;      // [512][320]
static constexpr long OFF_H1   = BASE + 425984;      // [512][256]
static constexpr long OFF_H2   = BASE + 557056;      // [512][256]
static constexpr long OFF_RS   = BASE + 688128;      // [512][256]
static constexpr long U_QH  = (BASE + 819200) * 2;   // Q planes ush
static constexpr long U_QL  = U_QH + 1048576;
static constexpr long U_KH  = (BASE + 1867776) * 2;  // K planes ush (Q->K stride 2,097,152 ush)
static constexpr long U_KL  = U_KH + 1048576;
static constexpr long OFF_VA   = BASE + 2916352;     // [8][512][256] f32
static constexpr long OFF_AW1  = BASE + 3964928;     // Aw1 (1024 ush)
static constexpr long U_ELH = (BASE + 3977344) * 2;  // EL planes ush (REPIN region); REP planes reuse
static constexpr long U_ELL = U_ELH + 1048576;
static constexpr long U_REPH = U_ELH;                // [512][2048] ush
static constexpr long U_REPL = U_ELL;
static constexpr long OFF_REP  = BASE + 5025920;     // [512][256]
static constexpr long OFF_XZ   = BASE + 5156992;     // [512][384]
static constexpr long OFF_DH1  = BASE + 5353600;     // [512][100]
static constexpr long OFF_DH2  = BASE + 5404800;     // [512][100]
static constexpr long OFF_AW   = 22233216;           // conv2 A-weights (13824 ush)
static constexpr long OFF_AW3  = 22240128;           // conv3 A-weights (73728 ush)

__device__ inline unsigned short f2bf(float f) {
    unsigned int x = __float_as_uint(f);
    unsigned int r = x + 0x7fffu + ((x >> 16) & 1u);
    return (unsigned short)(r >> 16);
}
__device__ inline float bf2f(unsigned short h) {
    return __uint_as_float((unsigned int)h << 16);
}

// ============================================================
// Prep A (runs FIRST — only touches non-pool regions):
// Aw(conv2), Aw1(conv1), Aw3(conv3 hi/lo), EL planes.
// ============================================================
static constexpr int NA1 = 13824;                 // Aw
static constexpr int NA2 = NA1 + 1024;            // Aw1
static constexpr int NA3 = NA2 + 73728;           // Aw3
static constexpr int NA4 = NA3 + 1048576;         // EL

__global__ void k_wprepA(const float* __restrict__ w2, const float* __restrict__ w1,
                         const float* __restrict__ w3, const float* __restrict__ elw,
                         unsigned short* __restrict__ Aw, unsigned short* __restrict__ Aw1,
                         unsigned short* __restrict__ Aw3,
                         unsigned short* __restrict__ ELh, unsigned short* __restrict__ ELl)
{
    int i = blockIdx.x * 256 + threadIdx.x;
    if (i < NA1) {
        int ic  = i & 31;
        int m16 = (i >> 5) & 15;
        int emt = i >> 9;
        int mt  = emt % 3, e = emt / 3;
        Aw[i] = f2bf(w2[((mt * 16 + m16) * 32 + ic) * 9 + e]);
    } else if (i < NA2) {
        int j = i - NA1;
        int k = j & 31, m = (j >> 5) & 15, mt = j >> 9;
        Aw1[j] = (k < 9) ? f2bf(w1[(mt * 16 + m) * 9 + k]) : (unsigned short)0;
    } else if (i < NA3) {
        int j = i - NA2;
        int k  = j & 63;
        int m  = (j >> 6) & 15;
        int hl = (j >> 10) & 1;
        int mt = (j >> 11) & 3;
        int e  = j >> 13;
        unsigned short v = 0;
        if (k < 48) {
            float w = w3[((mt * 16 + m) * 48 + k) * 9 + e];
            unsigned short hi = f2bf(w);
            v = hl == 0 ? hi : f2bf(w - bf2f(hi));
        }
        Aw3[j] = v;
    } else if (i < NA4) {
        int j = i - NA3;
        float v = elw[j];
        unsigned short h = f2bf(v);
        ELh[j] = h; ELl[j] = f2bf(v - bf2f(h));
    }
}

// ============================================================
// Prep B (runs AFTER conv3m — targets live in the then-dead pool region):
// P planes (padded to 1472 rows), WQ/WK/WV planes.
// ============================================================
static constexpr int NB1 = 376832;                // P
static constexpr int NB2 = NB1 + 1572864;         // WQ/WK/WV

__global__ void k_wprepB(const float* __restrict__ proj,
                         const float* __restrict__ wq, const float* __restrict__ wk,
                         const float* __restrict__ wv,
                         unsigned short* __restrict__ Ph, unsigned short* __restrict__ Pl,
                         unsigned short* __restrict__ Wqkv)
{
    int i = blockIdx.x * 256 + threadIdx.x;
    if (i < NB1) {
        float v = (i < 363264) ? proj[i] : 0.f;
        unsigned short h = f2bf(v);
        Ph[i] = h; Pl[i] = f2bf(v - bf2f(h));
    } else if (i < NB2) {
        int j = i - NB1;
        int y = j / 524288, jj = j % 524288;
        const float* s = (y == 0) ? wq : (y == 1) ? wk : wv;
        float v = s[jj];
        unsigned short h = f2bf(v);
        Wqkv[(long)y * 1048576 + jj] = h;
        Wqkv[(long)y * 1048576 + 524288 + jj] = f2bf(v - bf2f(h));
    }
}

// ============================================================
// fp32 -> bf16 hi/lo planes (rs, wo)
// ============================================================
__global__ void k_cvt(const float* __restrict__ s, unsigned short* __restrict__ dh,
                      unsigned short* __restrict__ dl, int n)
{
    int i = blockIdx.x * 256 + threadIdx.x;
    if (i >= n) return;
    float v = s[i];
    unsigned short h = f2bf(v);
    dh[i] = h;
    dl[i] = f2bf(v - bf2f(h));
}

// ============================================================
// Fused conv1 (MFMA, direct-global im2col) -> bf16 ring -> conv2 MFMA
// -> bias/relu/maxpool -> bf16 hi/lo pool [img][pix 256][hi48|lo48]
// LDS = ring 47520 + Bbuf 5120 = 52640 B -> 3 blocks/CU.
// ============================================================
__launch_bounds__(256)
__global__ void k_conv12m(const float* __restrict__ train, const float* __restrict__ test,
                          const float* __restrict__ b1,
                          const unsigned short* __restrict__ Aw,
                          const unsigned short* __restrict__ Aw1,
                          const float* __restrict__ b2,
                          unsigned short* __restrict__ pool_out)
{
    const int g   = blockIdx.x;    // 0..7 (conv2 rows 4g..4g+3)
    const int img = blockIdx.y;
    const float* in = (img < 512) ? (train + (long)img * 16384)
                                  : (test  + (long)(img - 512) * 16384);

    __shared__ unsigned short ring[9 * 66 * 40];   // 47520 B
    __shared__ unsigned short Bbuf[64 * 40];       // 5120 B (taps 9..31 stay 0)
    float* scratch = (float*)ring;                 // epilogue alias

    const int t = threadIdx.x;

    for (int i = t; i < 9 * 40; i += 256) {
        int sl = i / 40, icp = i % 40;
        ring[(sl * 66 + 0) * 40 + icp] = 0;
    }
    for (int i = t; i < 1280; i += 256) ((unsigned int*)Bbuf)[i] = 0u;
    if (g == 0)
        for (int i = t; i < 66 * 40; i += 256) ring[i] = 0;
    __syncthreads();

    const int w    = t >> 6;
    const int lane = t & 63;
    const int cn   = lane & 15;
    const int quad = lane >> 4;

    // conv1 A-frags + per-lane biases
    short8 a1f0 = *(const short8*)&Aw1[(0 * 16 + cn) * 32 + quad * 8];
    short8 a1f1 = *(const short8*)&Aw1[(16 + cn) * 32 + quad * 8];
    float bs[8];
    #pragma unroll
    for (int r = 0; r < 4; r++) { bs[r] = b1[quad * 4 + r]; bs[4 + r] = b1[16 + quad * 4 + r]; }

    // ---- conv1 rows via MFMA (wave-private im2col from global) ----
    for (int sl = (g == 0 ? 1 : 0); sl < 9; sl++) {
        if (lane < 16) {
            const int px = w * 16 + cn;
            unsigned short o[9];
            #pragma unroll
            for (int dy = 0; dy < 3; dy++) {
                int r2 = 16 * g + 2 * sl - 3 + dy;
                #pragma unroll
                for (int dx = 0; dx < 3; dx++) {
                    int c2 = 2 * px - 1 + dx;
                    float v = (r2 >= 0 && c2 >= 0) ? in[r2 * 128 + c2] : 0.f;
                    o[dy * 3 + dx] = f2bf(v);
                }
            }
            *(uint4*)&Bbuf[px * 40] = *(const uint4*)o;
            Bbuf[px * 40 + 8] = o[8];
        }
        const int px2 = w * 16 + cn;
        short8 bfr = *(const short8*)&Bbuf[px2 * 40 + quad * 8];
        f32x4 z = (f32x4){0.f, 0.f, 0.f, 0.f};
        f32x4 c0 = __builtin_amdgcn_mfma_f32_16x16x32_bf16(a1f0, bfr, z, 0, 0, 0);
        f32x4 c1 = __builtin_amdgcn_mfma_f32_16x16x32_bf16(a1f1, bfr, z, 0, 0, 0);
        unsigned short p0[4], p1[4];
        #pragma unroll
        for (int r = 0; r < 4; r++) {
            p0[r] = f2bf(fmaxf(c0[r] + bs[r], 0.f));
            p1[r] = f2bf(fmaxf(c1[r] + bs[4 + r], 0.f));
        }
        *(uint2*)&ring[(sl * 66 + px2 + 1) * 40 + quad * 4]      = *(const uint2*)p0;
        *(uint2*)&ring[(sl * 66 + px2 + 1) * 40 + 16 + quad * 4] = *(const uint2*)p1;
    }
    __syncthreads();

    // ---- conv2 MFMA phase ----
    f32x4 acc[3][2];
    #pragma unroll
    for (int mt = 0; mt < 3; mt++)
        #pragma unroll
        for (int xh = 0; xh < 2; xh++) acc[mt][xh] = (f32x4){0.f, 0.f, 0.f, 0.f};

    for (int e = 0; e < 9; e++) {
        int dy = e / 3, dx = e - 3 * dy;
        short8 a0 = *(const short8*)&Aw[((e * 3 + 0) * 16 + cn) * 32 + quad * 8];
        short8 a1 = *(const short8*)&Aw[((e * 3 + 1) * 16 + cn) * 32 + quad * 8];
        short8 a2 = *(const short8*)&Aw[((e * 3 + 2) * 16 + cn) * 32 + quad * 8];
        int sl = 2 * w + dy;
        #pragma unroll
        for (int xh = 0; xh < 2; xh++) {
            int c = 2 * (xh * 16 + cn) + dx;
            short8 bfr = *(const short8*)&ring[(sl * 66 + c) * 40 + quad * 8];
            acc[0][xh] = __builtin_amdgcn_mfma_f32_16x16x32_bf16(a0, bfr, acc[0][xh], 0, 0, 0);
            acc[1][xh] = __builtin_amdgcn_mfma_f32_16x16x32_bf16(a1, bfr, acc[1][xh], 0, 0, 0);
            acc[2][xh] = __builtin_amdgcn_mfma_f32_16x16x32_bf16(a2, bfr, acc[2][xh], 0, 0, 0);
        }
    }
    __syncthreads();

    #pragma unroll
    for (int mt = 0; mt < 3; mt++) {
        #pragma unroll
        for (int reg = 0; reg < 4; reg++) {
            int oc = mt * 16 + quad * 4 + reg;
            float bias = b2[oc];
            #pragma unroll
            for (int xh = 0; xh < 2; xh++) {
                int x = xh * 16 + cn;
                scratch[(w * 32 + x) * 52 + oc] = fmaxf(acc[mt][xh][reg] + bias, 0.f);
            }
        }
    }
    __syncthreads();

    for (int i = t; i < 1536; i += 256) {
        int oc = i % 48; int pp = i / 48; int px = pp & 15, pr = pp >> 4;
        const float* b0 = &scratch[((2 * pr) * 32 + 2 * px) * 52 + oc];
        float m = fmaxf(fmaxf(b0[0], b0[52]), fmaxf(b0[32 * 52], b0[33 * 52]));
        unsigned short hi = f2bf(m);
        unsigned short lo = f2bf(m - bf2f(hi));
        long base = ((long)img * 256 + (2 * g + pr) * 16 + px) * 96;
        pool_out[base + oc] = hi;
        pool_out[base + 48 + oc] = lo;
    }
}

// ============================================================
// conv3 via MFMA hi/lo -> bf16 hi/lo planes [1024][4096]
// ============================================================
#define C3PITCH 104
__launch_bounds__(512)
__global__ void k_conv3m(const unsigned short* __restrict__ pool,
                         const unsigned short* __restrict__ Aw3,
                         const float* __restrict__ b3,
                         unsigned short* __restrict__ C3h, unsigned short* __restrict__ C3l)
{
    const int img = blockIdx.x;
    __shared__ unsigned short s_in[30120];
    const int t = threadIdx.x;

    uint4* s4 = (uint4*)s_in;
    const uint4 zz = make_uint4(0, 0, 0, 0);
    for (int i = t; i < 3765; i += 512) s4[i] = zz;
    __syncthreads();
    {
        int p = t >> 1, half = t & 1;
        const uint4* src = (const uint4*)(pool + ((long)img * 256 + p) * 96 + half * 48);
        int r = p >> 4, c = p & 15;
        uint4* dst = (uint4*)(s_in + ((r + 1) * 17 + (c + 1)) * C3PITCH + half * 48);
        #pragma unroll
        for (int j = 0; j < 6; j++) dst[j] = src[j];
    }
    __syncthreads();

    const int w = t >> 6, lane = t & 63;
    const int n = lane & 15, quad = lane >> 4;
    const int mt = w >> 1, ntb = (w & 1) * 2;

    f32x4 acc[2];
    acc[0] = (f32x4){0.f, 0.f, 0.f, 0.f};
    acc[1] = (f32x4){0.f, 0.f, 0.f, 0.f};

    for (int e = 0; e < 9; e++) {
        int dy = e / 3, dx = e - 3 * dy;
        const unsigned short* A0 = Aw3 + (long)(((e * 4 + mt) * 2 + 0) * 16 + n) * 64 + quad * 8;
        const unsigned short* A1 = Aw3 + (long)(((e * 4 + mt) * 2 + 1) * 16 + n) * 64 + quad * 8;
        short8 ah0 = *(const short8*)(A0);
        short8 ah1 = *(const short8*)(A0 + 32);
        short8 al0 = *(const short8*)(A1);
        short8 al1 = *(const short8*)(A1 + 32);
        #pragma unroll
        for (int j = 0; j < 2; j++) {
            int p = (ntb + j) * 16 + n;
            int y = p >> 3, x = p & 7;
            const unsigned short* Bp = s_in + ((2 * y + dy) * 17 + (2 * x + dx)) * C3PITCH + quad * 8;
            short8 bh0 = *(const short8*)(Bp);
            short8 bh1 = *(const short8*)(Bp + 32);
            short8 bl0 = *(const short8*)(Bp + 48);
            short8 bl1 = *(const short8*)(Bp + 48 + 32);
            acc[j] = __builtin_amdgcn_mfma_f32_16x16x32_bf16(ah0, bh0, acc[j], 0, 0, 0);
            acc[j] = __builtin_amdgcn_mfma_f32_16x16x32_bf16(ah1, bh1, acc[j], 0, 0, 0);
            acc[j] = __builtin_amdgcn_mfma_f32_16x16x32_bf16(ah0, bl0, acc[j], 0, 0, 0);
            acc[j] = __builtin_amdgcn_mfma_f32_16x16x32_bf16(ah1, bl1, acc[j], 0, 0, 0);
            acc[j] = __builtin_amdgcn_mfma_f32_16x16x32_bf16(al0, bh0, acc[j], 0, 0, 0);
            acc[j] = __builtin_amdgcn_mfma_f32_16x16x32_bf16(al1, bh1, acc[j], 0, 0, 0);
        }
    }

    unsigned short* oh = C3h + (long)img * 4096;
    unsigned short* ol = C3l + (long)img * 4096;
    #pragma unroll
    for (int reg = 0; reg < 4; reg++) {
        int oc = mt * 16 + quad * 4 + reg;
        float bias = b3[oc];
        #pragma unroll
        for (int j = 0; j < 2; j++) {
            int p = (ntb + j) * 16 + n;
            float v = fmaxf(acc[j][reg] + bias, 0.f);
            unsigned short h = f2bf(v);
            oh[oc * 64 + p] = h;
            ol[oc * 64 + p] = f2bf(v - bf2f(h));
        }
    }
}

// ============================================================
// bf16 hi/lo MFMA GEMM (3-term, ~fp32). OUTMODE 0: f32 out (z-batch over
// X/W/B/Y strides); 1: hi/lo plane out (z-batch); 3: split-K chunks, z =
// chunk index, plain store to Yf + z*sY (no bias, no atomics).
// ============================================================
template<int OUTMODE>
__launch_bounds__(256)
__global__ void mgemm(const unsigned short* __restrict__ Xh0, const unsigned short* __restrict__ Xl0,
                      const unsigned short* __restrict__ Wph, const unsigned short* __restrict__ Wpl,
                      const float* __restrict__ Bb, float* __restrict__ Yf,
                      unsigned short* __restrict__ Yh, unsigned short* __restrict__ Yl,
                      int M, int N, int K, int ldY, float scale,
                      long sX, long sW, long sB, long sY, int kChunk)
{
    const int z = blockIdx.z;
    const unsigned short* Xh = Xh0 + (OUTMODE == 3 ? 0 : (long)z * sX);
    const unsigned short* Xl = Xl0 + (OUTMODE == 3 ? 0 : (long)z * sX);
    const unsigned short* Wh = Wph + (OUTMODE == 3 ? 0 : (long)z * sW);
    const unsigned short* Wl = Wpl + (OUTMODE == 3 ? 0 : (long)z * sW);
    const float* B = Bb ? (Bb + (OUTMODE == 3 ? 0 : (long)z * sB)) : nullptr;
    int k0 = 0, k1 = K;
    if (OUTMODE == 3) { k0 = z * kChunk; k1 = min(K, k0 + kChunk); }

    __shared__ unsigned short sAh[64 * 40], sAl[64 * 40], sBh[64 * 40], sBl[64 * 40];

    const int t = threadIdx.x;
    const int m0 = blockIdx.y * 64, n0 = blockIdx.x * 64;
    const int r = t >> 2, kq = (t & 3) * 8;

    const int w = t >> 6, lane = t & 63;
    const int wm = (w & 1) * 32, wn = (w >> 1) * 32;
    const int cn = lane & 15, quad = lane >> 4;

    f32x4 acc[2][2];
    acc[0][0] = acc[0][1] = acc[1][0] = acc[1][1] = (f32x4){0.f, 0.f, 0.f, 0.f};

    for (int kb = k0; kb < k1; kb += 32) {
        *(uint4*)&sAh[r * 40 + kq] = *(const uint4*)&Xh[(long)(m0 + r) * K + kb + kq];
        *(uint4*)&sAl[r * 40 + kq] = *(const uint4*)&Xl[(long)(m0 + r) * K + kb + kq];
        *(uint4*)&sBh[r * 40 + kq] = *(const uint4*)&Wh[(long)(n0 + r) * K + kb + kq];
        *(uint4*)&sBl[r * 40 + kq] = *(const uint4*)&Wl[(long)(n0 + r) * K + kb + kq];
        __syncthreads();
        short8 axh[2], axl[2], bxh[2], bxl[2];
        #pragma unroll
        for (int i = 0; i < 2; i++) {
            axh[i] = *(const short8*)&sAh[(wm + i * 16 + cn) * 40 + quad * 8];
            axl[i] = *(const short8*)&sAl[(wm + i * 16 + cn) * 40 + quad * 8];
            bxh[i] = *(const short8*)&sBh[(wn + i * 16 + cn) * 40 + quad * 8];
            bxl[i] = *(const short8*)&sBl[(wn + i * 16 + cn) * 40 + quad * 8];
        }
        #pragma unroll
        for (int i = 0; i < 2; i++)
            #pragma unroll
            for (int j = 0; j < 2; j++) {
                acc[i][j] = __builtin_amdgcn_mfma_f32_16x16x32_bf16(axh[i], bxh[j], acc[i][j], 0, 0, 0);
                acc[i][j] = __builtin_amdgcn_mfma_f32_16x16x32_bf16(axh[i], bxl[j], acc[i][j], 0, 0, 0);
                acc[i][j] = __builtin_amdgcn_mfma_f32_16x16x32_bf16(axl[i], bxh[j], acc[i][j], 0, 0, 0);
            }
        __syncthreads();
    }

    #pragma unroll
    for (int i = 0; i < 2; i++) {
        #pragma unroll
        for (int reg = 0; reg < 4; reg++) {
            int row = m0 + wm + i * 16 + quad * 4 + reg;
            #pragma unroll
            for (int j = 0; j < 2; j++) {
                int col = n0 + wn + j * 16 + cn;
                if (col >= N) continue;
                float v = acc[i][j][reg] * scale;
                if (OUTMODE == 3) {
                    (Yf + (long)z * sY)[(long)row * ldY + col] = v;
                } else if (OUTMODE == 0) {
                    if (B) v += B[col];
                    (Yf + (long)z * sY)[(long)row * ldY + col] = v;
                } else {
                    if (B) v += B[col];
                    unsigned short h = f2bf(v);
                    (Yh + (long)z * sY)[(long)row * ldY + col] = h;
                    (Yl + (long)z * sY)[(long)row * ldY + col] = f2bf(v - bf2f(h));
                }
            }
        }
    }
}

// ============================================================
// reducers for split-K temps
// ============================================================
__global__ void k_red_enc(const float* __restrict__ tmp, const float* __restrict__ elb,
                          float* __restrict__ x_ctx, unsigned short* __restrict__ XCh,
                          unsigned short* __restrict__ XCl, float* __restrict__ xcat)
{
    int i = blockIdx.x * 256 + threadIdx.x;   // 262144
    int r = i >> 8, c = i & 255;
    float v = elb[c];
    #pragma unroll
    for (int z = 0; z < 8; z++) v += tmp[(long)z * 262144 + i];
    x_ctx[i] = v;
    unsigned short h = f2bf(v);
    XCh[i] = h; XCl[i] = f2bf(v - bf2f(h));
    if (r < 512) xcat[r * 320 + c] = v;
}

__global__ void k_red_rep(const float* __restrict__ tmp, const float* __restrict__ wob,
                          float* __restrict__ rep)
{
    int i = blockIdx.x * 256 + threadIdx.x;   // 131072
    int c = i & 255;
    float v = wob[c];
    #pragma unroll
    for (int z = 0; z < 4; z++) v += tmp[(long)z * 131072 + i];
    rep[i] = v;
}

// xcat cols 256..319 = label @ ty_w^T + ty_b
__global__ void k_ly(const float* __restrict__ label, const float* __restrict__ tyw,
                     const float* __restrict__ tyb, float* __restrict__ xcat)
{
    int i = blockIdx.x * 256 + threadIdx.x;   // 32768
    int r = i >> 6, e = i & 63;
    xcat[r * 320 + 256 + e] = tyb[e] + label[r * 2] * tyw[e * 2] + label[r * 2 + 1] * tyw[e * 2 + 1];
}

// ============================================================
// Generic fp32 GEMM (small layers), float2 inner loads, optional FIN write.
// ============================================================
template<int BM, int BN, int BK, int ACT, bool FIN>
__launch_bounds__(256)
__global__ void gemm_k(const float* __restrict__ X, const float* __restrict__ W,
                       const float* __restrict__ B, float* __restrict__ Y,
                       int M, int N, int K, int ldY)
{
    __shared__ float As[BK][BM + 4];
    __shared__ float Bs[BK][BN + 4];
    const int t = threadIdx.x;
    const int tx = t & 15, ty = t >> 4;
    const int m0 = blockIdx.y * BM, n0 = blockIdx.x * BN;
    float acc[2][2] = {{0.f, 0.f}, {0.f, 0.f}};

    for (int kb = 0; kb < K; kb += BK) {
        for (int i = t; i < BM * BK; i += 256) {
            int rr = i / BK, c = i % BK;
            int mm = m0 + rr, kk = kb + c;
            As[c][rr] = (mm < M && kk < K) ? X[(long)mm * K + kk] : 0.f;
        }
        for (int i = t; i < BN * BK; i += 256) {
            int rr = i / BK, c = i % BK;
            int nn = n0 + rr, kk = kb + c;
            Bs[c][rr] = (nn < N && kk < K) ? W[(long)nn * K + kk] : 0.f;
        }
        __syncthreads();
        #pragma unroll
        for (int kk = 0; kk < BK; kk++) {
            float2 a2 = *(const float2*)&As[kk][ty * 2];
            float2 b2 = *(const float2*)&Bs[kk][tx * 2];
            acc[0][0] += a2.x * b2.x; acc[0][1] += a2.x * b2.y;
            acc[1][0] += a2.y * b2.x; acc[1][1] += a2.y * b2.y;
        }
        __syncthreads();
    }

    #pragma unroll
    for (int i = 0; i < 2; i++) {
        int mm = m0 + ty * 2 + i;
        if (mm >= M) continue;
        #pragma unroll
        for (int j = 0; j < 2; j++) {
            int nn = n0 + tx * 2 + j;
            if (nn >= N) continue;
            float v = acc[i][j] + (B ? B[nn] : 0.f);
            if (ACT == 1) v = fmaxf(v, 0.f);
            if (ACT == 2) v = tanhf(v);
            Y[(long)mm * ldY + nn] = v;
        }
    }
    if (FIN && t == 0 && blockIdx.x == 0 && blockIdx.y == 0) Y[1024] = 0.f;
}

// ============================================================
// Fused diag + max + exp.  blocks 0..4095: per-query-token;
// blocks 4096..4223: one block per key (h,t) tile (owns all 32 rows).
// ============================================================
__launch_bounds__(256)
__global__ void k_expqk(float* __restrict__ xdq, float* __restrict__ xdk,
                        const unsigned short* __restrict__ Qh, const unsigned short* __restrict__ Ql,
                        const unsigned short* __restrict__ Kh, const unsigned short* __restrict__ Kl)
{
    __shared__ float red[8];
    __shared__ float s_dk[32];
    const int bx = blockIdx.x;
    const int t = threadIdx.x;

    if (bx < 4096) {
        const int tok = bx;
        float v = bf2f(Qh[(long)tok * 256 + t]) + bf2f(Ql[(long)tok * 256 + t]);
        float s = v * v;
        for (int d = 1; d < 64; d <<= 1) s += __shfl_xor(s, d);
        if ((t & 63) == 0) red[t >> 6] = s;
        __syncthreads();
        float diag = (red[0] + red[1] + red[2] + red[3]) * (1.f / 32.f);

        float vals[6];
        float m = -1e30f;
        #pragma unroll
        for (int j = 0; j < 6; j++) {
            int f = t + j * 256;
            if (f < F_FEAT) { vals[j] = xdq[(long)tok * F_FEAT + f]; m = fmaxf(m, vals[j]); }
        }
        for (int d = 1; d < 64; d <<= 1) m = fmaxf(m, __shfl_xor(m, d));
        if ((t & 63) == 0) red[4 + (t >> 6)] = m;
        __syncthreads();
        m = fmaxf(fmaxf(red[4], red[5]), fmaxf(red[6], red[7]));
        #pragma unroll
        for (int j = 0; j < 6; j++) {
            int f = t + j * 256;
            if (f < F_FEAT) xdq[(long)tok * F_FEAT + f] = RATIO * (expf(vals[j] - diag - m) + 1e-4f);
        }
    } else {
        const int kb = bx - 4096;       // 0..127, owns the whole (h,t) tile
        const long tok0 = (long)kb * 32;
        const int row = t >> 3, j = t & 7;

        float s = 0.f;
        const unsigned short* ph = Kh + (tok0 + row) * 256 + j * 32;
        const unsigned short* pl = Kl + (tok0 + row) * 256 + j * 32;
        for (int q = 0; q < 32; q++) { float v = bf2f(ph[q]) + bf2f(pl[q]); s += v * v; }
        s += __shfl_xor(s, 1); s += __shfl_xor(s, 2); s += __shfl_xor(s, 4);
        if (j == 0) s_dk[row] = s * (1.f / 32.f);

        float* base = xdk + tok0 * F_FEAT;
        float m = -1e30f;
        for (int i = t; i < 32 * F_FEAT; i += 256) m = fmaxf(m, base[i]);
        for (int d = 1; d < 64; d <<= 1) m = fmaxf(m, __shfl_xor(m, d));
        if ((t & 63) == 0) red[t >> 6] = m;
        __syncthreads();
        m = fmaxf(fmaxf(red[0], red[1]), fmaxf(red[2], red[3]));

        for (int r = 0; r < 32; r++) {
            float dg = s_dk[r];
            float* rp = base + (long)r * F_FEAT;
            for (int f = t; f < F_FEAT; f += 256) rp[f] = RATIO * (expf(rp[f] - dg - m) + 1e-4f);
        }
    }
}

// ============================================================
// Attention core -> hi/lo planes of rep_in (permuted concat)
// ============================================================
__launch_bounds__(256)
__global__ void k_attn(const float* __restrict__ qp, const float* __restrict__ kp,
                       const float* __restrict__ va,
                       unsigned short* __restrict__ REPh, unsigned short* __restrict__ REPl)
{
    const int tt = blockIdx.x;
    const int h  = blockIdx.y;
    const long row0 = ((long)h * 16 + tt) * 32;

    __shared__ float s_q[32][68];
    __shared__ float s_k[32][68];
    __shared__ float s_A[32][33];
    __shared__ float s_di[32];
    __shared__ float s_v[32 * 256];

    const int t = threadIdx.x;
    const int n = t >> 3;
    const int mq = (t & 7) * 4;

    float acc[4] = {0, 0, 0, 0};
    for (int fc = 0; fc < F_FEAT; fc += 64) {
        for (int i = t; i < 2048; i += 256) {
            int rr = i >> 6, ff = i & 63;
            int fg = fc + ff;
            s_q[rr][ff] = (fg < F_FEAT) ? qp[(row0 + rr) * F_FEAT + fg] : 0.f;
            s_k[rr][ff] = (fg < F_FEAT) ? kp[(row0 + rr) * F_FEAT + fg] : 0.f;
        }
        __syncthreads();
        #pragma unroll 8
        for (int ff = 0; ff < 64; ff++) {
            float a = s_q[n][ff];
            #pragma unroll
            for (int j = 0; j < 4; j++) acc[j] += a * s_k[mq + j][ff];
        }
        __syncthreads();
    }

    float rsum = acc[0] + acc[1] + acc[2] + acc[3];
    rsum += __shfl_xor(rsum, 1);
    rsum += __shfl_xor(rsum, 2);
    rsum += __shfl_xor(rsum, 4);
    #pragma unroll
    for (int j = 0; j < 4; j++) s_A[n][mq + j] = acc[j];
    if ((t & 7) == 0) s_di[n] = 1.f / rsum;
    for (int i = t; i < 8192; i += 256) s_v[i] = va[row0 * 256 + i];
    __syncthreads();

    const int e0 = t & 7;
    float out[32];
    #pragma unroll
    for (int j = 0; j < 32; j++) out[j] = 0.f;
    for (int m = 0; m < 32; m++) {
        float a = s_A[n][m];
        #pragma unroll
        for (int j = 0; j < 32; j++) out[j] += a * s_v[m * 256 + e0 + 8 * j];
    }
    float di = s_di[n];
    unsigned short* dsth = REPh + ((long)tt * 32 + n) * 2048;
    unsigned short* dstl = REPl + ((long)tt * 32 + n) * 2048;
    #pragma unroll
    for (int j = 0; j < 32; j++) {
        int e = e0 + 8 * j;
        float val = out[j] * di;
        unsigned short hh = f2bf(val);
        dsth[e * 8 + h] = hh;
        dstl[e * 8 + h] = f2bf(val - bf2f(hh));
    }
}

__global__ void k_xzcopy(const float* __restrict__ xq, float* __restrict__ xz)
{
    int idx = blockIdx.x * 256 + threadIdx.x;
    if (idx >= 512 * 256) return;
    int r = idx >> 8, c = idx & 255;
    xz[r * 384 + c] = xq[idx];
}

// ============================================================
extern "C" void kernel_launch(void* const* d_in, const int* in_sizes, int n_in,
                              void* d_out, int out_size, void* d_ws, size_t ws_size,
                              hipStream_t stream)
{
    const float* train  = (const float*)d_in[0];
    const float* label  = (const float*)d_in[1];
    const float* test   = (const float*)d_in[2];
    const float* c1w = (const float*)d_in[3];  const float* c1b = (const float*)d_in[4];
    const float* c2w = (const float*)d_in[5];  const float* c2b = (const float*)d_in[6];
    const float* c3w = (const float*)d_in[7];  const float* c3b = (const float*)d_in[8];
    const float* elw = (const float*)d_in[9];  const float* elb = (const float*)d_in[10];
    const float* tyw = (const float*)d_in[11]; const float* tyb = (const float*)d_in[12];
    const float* ew1 = (const float*)d_in[13]; const float* eb1 = (const float*)d_in[14];
    const float* ew2 = (const float*)d_in[15]; const float* eb2 = (const float*)d_in[16];
    const float* ew3 = (const float*)d_in[17]; const float* eb3 = (const float*)d_in[18];
    const float* wq  = (const float*)d_in[19]; const float* wqb = (const float*)d_in[20];
    const float* wk  = (const float*)d_in[21]; const float* wkb = (const float*)d_in[22];
    const float* wv  = (const float*)d_in[23]; const float* wvb = (const float*)d_in[24];
    const float* wow = (const float*)d_in[25]; const float* wob = (const float*)d_in[26];
    const float* rzw = (const float*)d_in[27]; const float* rzb = (const float*)d_in[28];
    const float* dw1 = (const float*)d_in[29]; const float* db1 = (const float*)d_in[30];
    const float* dw2 = (const float*)d_in[31]; const float* db2 = (const float*)d_in[32];
    const float* dw3 = (const float*)d_in[33]; const float* db3 = (const float*)d_in[34];
    const float* proj= (const float*)d_in[35];

    float* wsf = (float*)d_ws;
    unsigned short* usw = (unsigned short*)d_ws;
    float* out = (float*)d_out;

    unsigned short* A_pool = usw;                 // pool at ush offset 0 (dead after conv3m)
    float* x_ctx  = wsf + OFF_XCTX;
    float* x_qry  = wsf + OFF_XQRY;
    float* xcat   = wsf + OFF_XCAT;
    float* h1     = wsf + OFF_H1;
    float* h2     = wsf + OFF_H2;
    float* rs     = wsf + OFF_RS;
    float* v_all  = wsf + OFF_VA;
    float* rep    = wsf + OFF_REP;
    float* xz     = wsf + OFF_XZ;
    float* dh1    = wsf + OFF_DH1;
    float* dh2    = wsf + OFF_DH2;
    float* xd_q   = wsf + OFF_XDQ;
    float* xd_k   = wsf + OFF_XDK;
    float* enc_t  = wsf + OFF_ENCT;
    float* rep_t  = wsf + OFF_REPT;
    unsigned short* Aw  = (unsigned short*)(wsf + OFF_AW);
    unsigned short* Aw3 = (unsigned short*)(wsf + OFF_AW3);
    unsigned short* Aw1 = (unsigned short*)(wsf + OFF_AW1);

    unsigned short* Wqkv = usw + U_WQH;
    unsigned short* WQh = usw + U_WQH; unsigned short* WQl = usw + U_WQL;
    unsigned short* WKh = usw + U_WKH; unsigned short* WKl = usw + U_WKL;
    unsigned short* WVh = usw + U_WVH; unsigned short* WVl = usw + U_WVL;
    unsigned short* Ph  = usw + U_PH;  unsigned short* Pl  = usw + U_PL;
    unsigned short* XCh = usw + U_XCH; unsigned short* XCl = usw + U_XCL;
    unsigned short* RSh = usw + U_RSH; unsigned short* RSl = usw + U_RSL;
    unsigned short* C3h = usw + U_C3H; unsigned short* C3l = usw + U_C3L;
    unsigned short* Qh  = usw + U_QH;  unsigned short* Ql  = usw + U_QL;
    unsigned short* Kh  = usw + U_KH;  unsigned short* Kl  = usw + U_KL;
    unsigned short* ELh = usw + U_ELH; unsigned short* ELl = usw + U_ELL;
    unsigned short* WOh = usw + U_WOH; unsigned short* WOl = usw + U_WOL;
    unsigned short* REPh= usw + U_REPH;unsigned short* REPl= usw + U_REPL;

    // 1. prep A: Aw/Aw1/Aw3/EL (non-pool regions only)
    k_wprepA<<<4442, 256, 0, stream>>>(c2w, c1w, c3w, elw, Aw, Aw1, Aw3, ELh, ELl);

    // 2-3. encoder convs
    k_conv12m<<<dim3(8, 1024), 256, 0, stream>>>(train, test, c1b, Aw, Aw1, c2b, A_pool);
    k_conv3m<<<1024, 512, 0, stream>>>(A_pool, Aw3, c3b, C3h, C3l);

    // 4. prep B: P + WQKV planes into the now-dead pool region
    k_wprepB<<<7616, 256, 0, stream>>>(proj, wq, wk, wv, Ph, Pl, Wqkv);

    // 5-6. enc linear split-K=8 into temps, then reduce (+bias, planes, xcat copy)
    mgemm<3><<<dim3(4, 16, 8), 256, 0, stream>>>(
        C3h, C3l, ELh, ELl, nullptr, enc_t, nullptr, nullptr,
        1024, 256, 4096, 256, 1.f, 0, 0, 0, 262144, 512);
    k_red_enc<<<1024, 256, 0, stream>>>(enc_t, elb, x_ctx, XCh, XCl, xcat);

    // 7. label embedding part of xcat
    k_ly<<<128, 256, 0, stream>>>(label, tyw, tyb, xcat);

    // 8-10. er MLP -> rs
    gemm_k<32,32,32,1,false><<<dim3(8, 16), 256, 0, stream>>>(xcat, ew1, eb1, h1, 512, 256, 320, 256);
    gemm_k<32,32,32,1,false><<<dim3(8, 16), 256, 0, stream>>>(h1, ew2, eb2, h2, 512, 256, 256, 256);
    gemm_k<32,32,32,0,false><<<dim3(8, 16), 256, 0, stream>>>(h2, ew3, eb3, rs, 512, 256, 256, 256);
    // 11.
    k_cvt<<<512, 256, 0, stream>>>(rs, RSh, RSl, 131072);

    // 12-14. q/k/v projections (z = 8 heads)
    mgemm<1><<<dim3(4, 8, 8), 256, 0, stream>>>(
        XCh + 512 * 256, XCl + 512 * 256, WQh, WQl, wqb, nullptr, Qh, Ql,
        512, 256, 256, 256, 1.f, 0, 65536, 256, 131072, 0);
    mgemm<1><<<dim3(4, 8, 8), 256, 0, stream>>>(
        XCh, XCl, WKh, WKl, wkb, nullptr, Kh, Kl,
        512, 256, 256, 256, 1.f, 0, 65536, 256, 131072, 0);
    mgemm<0><<<dim3(4, 8, 8), 256, 0, stream>>>(
        RSh, RSl, WVh, WVl, wvb, v_all, nullptr, nullptr,
        512, 256, 256, 256, 1.f, 0, 65536, 256, 131072, 0);

    // 15. wo planes into dead C3 region (enc done)
    k_cvt<<<2048, 256, 0, stream>>>(wow, WOh, WOl, 524288);

    // 16. performer features, q and k in one dispatch (z=2; X/Y z-strided)
    mgemm<0><<<dim3(23, 64, 2), 256, 0, stream>>>(
        Qh, Ql, Ph, Pl, nullptr, xd_q, nullptr, nullptr,
        4096, F_FEAT, 256, F_FEAT, DN, 2097152, 0, 0, 5812224, 0);

    // 17. fused diag+max+exp (4096 q blocks + 128 whole-tile k blocks)
    k_expqk<<<4224, 256, 0, stream>>>(xd_q, xd_k, Qh, Ql, Kh, Kl);

    // 18. attention -> REP planes
    k_attn<<<dim3(16, 8), 256, 0, stream>>>(xd_q, xd_k, v_all, REPh, REPl);

    // 19-20. rep = rep_in @ wo^T + b : split-K=4 temps + reduce
    mgemm<3><<<dim3(4, 8, 4), 256, 0, stream>>>(
        REPh, REPl, WOh, WOl, nullptr, rep_t, nullptr, nullptr,
        512, 256, 2048, 256, 1.f, 0, 0, 0, 131072, 512);
    k_red_rep<<<512, 256, 0, stream>>>(rep_t, wob, rep);

    // 21-22. xz = [x_qry | rep @ rz^T + b]
    k_xzcopy<<<512, 256, 0, stream>>>(x_qry, xz);
    gemm_k<32,32,32,0,false><<<dim3(4, 16), 256, 0, stream>>>(rep, rzw, rzb, xz + 256, 512, 128, 256, 384);

    // 23-25. decoder (k_fin folded into the last GEMM)
    gemm_k<32,32,32,1,false><<<dim3(4, 16), 256, 0, stream>>>(xz, dw1, db1, dh1, 512, 100, 384, 100);
    gemm_k<32,32,32,1,false><<<dim3(4, 16), 256, 0, stream>>>(dh1, dw2, db2, dh2, 512, 100, 100, 100);
    gemm_k<32,32,32,2,true><<<dim3(1, 16), 256, 0, stream>>>(dh2, dw3, db3, out, 512, 2, 100, 2);
}